// Round 7
// baseline (491.573 us; speedup 1.0000x reference)
//
#include <hip/hip_runtime.h>

// GraphNN R7 (Plan D): CSR gathers + all-MFMA GEMMs.
//  h0 pass: stats only, 3200 blocks (1 tile/wave).
//  h1 pass: recompute h0 (gather+tanh) -> MFMA -> h1 stats + bf16 h1 C-frag
//           store (12.8MB only).
//  vals pass: light h1 reader (verified in R6 Plan B).

#define N_NODES 50000
#define N_EDGES 400000
#define N_PAIRS 200000
#define N_G     100
#define EPG     4000
#define PPG     2000
#define NCHUNK  3125   // 50000/16

typedef float  f4   __attribute__((ext_vector_type(4)));
typedef short  bf8  __attribute__((ext_vector_type(8)));
typedef unsigned u32x4 __attribute__((ext_vector_type(4)));
typedef unsigned short ushort_t;

__device__ __forceinline__ float tanh_fast(float x) {
    float cx = fminf(15.f, fmaxf(-15.f, x));
    float e = __expf(2.f * cx);
    return (e - 1.f) * __builtin_amdgcn_rcpf(e + 1.f);
}
__device__ __forceinline__ unsigned f2bf(float f) {   // RNE fp32->bf16
    unsigned u = __float_as_uint(f);
    return (u + 0x7FFFu + ((u >> 16) & 1u)) >> 16;
}
__device__ __forceinline__ float bf2f(unsigned h) { return __uint_as_float(h << 16); }

// ---------------- CSR build ---------------------------------------------------
__global__ void k_csr_count(const int* __restrict__ edges, int* __restrict__ cnt) {
    int p = blockIdx.x * 256 + threadIdx.x;
    if (p >= N_PAIRS) return;
    atomicAdd(&cnt[edges[N_EDGES + 2 * p]], 1);
}
__global__ __launch_bounds__(512) void k_csr_scan(const int* __restrict__ cnt,
                                                  int* __restrict__ offs) {
    __shared__ int s[512];
    int g = blockIdx.x, t = threadIdx.x;
    int v = (t < 500) ? cnt[g * 500 + t] : 0;
    s[t] = v; __syncthreads();
    for (int off = 1; off < 512; off <<= 1) {
        int a = (t >= off) ? s[t - off] : 0;
        __syncthreads();
        s[t] += a; __syncthreads();
    }
    if (t < 500) offs[g * 500 + t] = g * PPG + s[t] - v;
}
__global__ void k_csr_fill(const int* __restrict__ edges, const float* __restrict__ ea,
                           const int* __restrict__ offs, int* __restrict__ fillc,
                           int* __restrict__ esrc, float* __restrict__ ew) {
    int p = blockIdx.x * 256 + threadIdx.x;
    if (p >= N_PAIRS) return;
    int d = edges[N_EDGES + 2 * p];
    int pos = offs[d] + atomicAdd(&fillc[d], 1);
    esrc[pos] = edges[2 * p];
    ew[pos] = ea[4 * p] + ea[4 * p + 2];
}

// ---------------- gathers -----------------------------------------------------
__global__ __launch_bounds__(256) void k_gath5(
    const int* __restrict__ cnt, const int* __restrict__ offs,
    const int* __restrict__ esrc, const float* __restrict__ ew,
    const float* __restrict__ x, float* __restrict__ agg) {
    int t = blockIdx.x * 256 + threadIdx.x;
    int n = t >> 3, k = t & 7;
    if (n >= N_NODES || k >= 5) return;
    int o0 = offs[n], c = cnt[n];
    float acc = 0.f;
    for (int i = o0; i < o0 + c; ++i) acc += x[esrc[i] * 5 + k] * ew[i];
    agg[n * 5 + k] = acc;
}
__global__ __launch_bounds__(256) void k_gath32(
    const int* __restrict__ cnt, const int* __restrict__ offs,
    const int* __restrict__ esrc, const float* __restrict__ ew,
    const float* __restrict__ x1, ushort_t* __restrict__ c2h, ushort_t* __restrict__ c2l) {
    int n = blockIdx.x * 8 + (threadIdx.x >> 5), k = threadIdx.x & 31;
    if (n >= N_NODES) return;
    int o0 = offs[n], c = cnt[n];
    float acc = 0.f;
    for (int i = o0; i < o0 + c; ++i) acc += x1[esrc[i] * 32 + k] * ew[i];
    unsigned hi = f2bf(acc);
    size_t o = (size_t)n * 64 + k;
    c2h[o] = (ushort_t)hi;
    c2l[o] = (ushort_t)f2bf(acc - bf2f(hi));
}
__global__ __launch_bounds__(256) void k_gath64(
    const int* __restrict__ cnt, const int* __restrict__ offs,
    const int* __restrict__ esrc, const float* __restrict__ ew,
    const float* __restrict__ x2, ushort_t* __restrict__ ch, ushort_t* __restrict__ cl) {
    int n = blockIdx.x * 4 + (threadIdx.x >> 6), k = threadIdx.x & 63;
    if (n >= N_NODES) return;
    int o0 = offs[n], c = cnt[n];
    float acc = 0.f;
    for (int i = o0; i < o0 + c; ++i) acc += x2[esrc[i] * 64 + k] * ew[i];
    unsigned hi = f2bf(acc);
    size_t o = (size_t)n * 128 + k;
    ch[o] = (ushort_t)hi;
    cl[o] = (ushort_t)f2bf(acc - bf2f(hi));
}

// ---------------- layer1 dense 5->32 ------------------------------------------
__global__ __launch_bounds__(256) void k_dense1(
    const float* __restrict__ x, const float* __restrict__ agg,
    const float* __restrict__ Wrel, const float* __restrict__ brel,
    const float* __restrict__ Wroot, float* __restrict__ x1,
    ushort_t* __restrict__ c2h, ushort_t* __restrict__ c2l) {
    __shared__ float wr[160], wt[160], bb[32];
    __shared__ float sa[8][5], sx[8][5];
    for (int i = threadIdx.x; i < 160; i += 256) { wr[i] = Wrel[i]; wt[i] = Wroot[i]; }
    if (threadIdx.x < 32) bb[threadIdx.x] = brel[threadIdx.x];
    int j = threadIdx.x & 31, nl = threadIdx.x >> 5;
    int nb = blockIdx.x * 8;
    __syncthreads();
    for (int i = threadIdx.x; i < 40; i += 256) {
        int nn = nb + i / 5, kk = i % 5;
        float av = 0.f, xv = 0.f;
        if (nn < N_NODES) { av = agg[nn * 5 + kk]; xv = x[nn * 5 + kk]; }
        sa[i / 5][kk] = av; sx[i / 5][kk] = xv;
    }
    __syncthreads();
    int n = nb + nl;
    if (n < N_NODES) {
        float acc = bb[j];
        #pragma unroll
        for (int k = 0; k < 5; ++k)
            acc += sa[nl][k] * wr[k * 32 + j] + sx[nl][k] * wt[k * 32 + j];
        float v = tanhf(acc);
        x1[n * 32 + j] = v;
        unsigned hi = f2bf(v);
        size_t o = (size_t)n * 64 + 32 + j;
        c2h[o] = (ushort_t)hi;
        c2l[o] = (ushort_t)f2bf(v - bf2f(hi));
    }
}

// ---------------- weight frag packers -----------------------------------------
__global__ void k_packWc(const float* __restrict__ Wrel2, const float* __restrict__ Wroot2,
                         unsigned* __restrict__ dst) {
    int i = blockIdx.x * 256 + threadIdx.x;   // 8192
    int t = i & 3, l = (i >> 2) & 63, kk = (i >> 8) & 3, n = i >> 10;
    int k = kk * 32 + ((l >> 4) << 3) + 2 * t;
    int j = 16 * n + (l & 15);
    float v0 = (k < 64) ? Wrel2[k * 128 + j] : Wroot2[(k - 64) * 128 + j];
    float v1 = (k + 1 < 64) ? Wrel2[(k + 1) * 128 + j] : Wroot2[(k + 1 - 64) * 128 + j];
    dst[i] = f2bf(v0) | (f2bf(v1) << 16);
}
__global__ void k_packWpq(const float* __restrict__ Wd0, unsigned* __restrict__ dst) {
    int i = blockIdx.x * 256 + threadIdx.x;   // 16384
    int t = i & 3, l = (i >> 2) & 63, kk = (i >> 8) & 3, n = i >> 10;
    int k = kk * 32 + ((l >> 4) << 3) + 2 * t;
    int j = 16 * n + (l & 15);
    float v0 = (j < 128) ? Wd0[k * 128 + j] : Wd0[(129 + k) * 128 + (j - 128)];
    float v1 = (j < 128) ? Wd0[(k + 1) * 128 + j] : Wd0[(129 + k + 1) * 128 + (j - 128)];
    dst[i] = f2bf(v0) | (f2bf(v1) << 16);
}
__global__ void k_packW2(const float* __restrict__ Wrel1, const float* __restrict__ Wroot1,
                         unsigned* __restrict__ dst) {
    int i = blockIdx.x * 256 + threadIdx.x;   // 2048
    int t = i & 3, l = (i >> 2) & 63, kk = (i >> 8) & 1, n = i >> 9;
    int k = kk * 32 + ((l >> 4) << 3) + 2 * t;
    int j = 16 * n + (l & 15);
    float v0 = (k < 32) ? Wrel1[k * 64 + j] : Wroot1[(k - 32) * 64 + j];
    float v1 = (k + 1 < 32) ? Wrel1[(k + 1) * 64 + j] : Wroot1[(k + 1 - 32) * 64 + j];
    dst[i] = f2bf(v0) | (f2bf(v1) << 16);
}

// ---------------- G1b: x2 = tanh(cat2 @ W2 + brel1) ---------------------------
__global__ __launch_bounds__(256) void k_g1b(
    const ushort_t* __restrict__ Ah, const ushort_t* __restrict__ Al,
    const unsigned* __restrict__ Wb_, const float* __restrict__ bias,
    float* __restrict__ x2, ushort_t* __restrict__ ch, ushort_t* __restrict__ cl) {
    int wave = threadIdx.x >> 6, lane = threadIdx.x & 63;
    int rl = lane & 15, gp = lane >> 4;
    int cid = blockIdx.x * 4 + wave;
    if (cid >= NCHUNK) return;
    u32x4 B[4][2];
    const u32x4* Wb = (const u32x4*)Wb_;
    #pragma unroll
    for (int n = 0; n < 4; ++n)
        #pragma unroll
        for (int kk = 0; kk < 2; ++kk)
            B[n][kk] = Wb[(n * 2 + kk) * 64 + lane];
    float bs[4];
    #pragma unroll
    for (int n = 0; n < 4; ++n) bs[n] = bias[n * 16 + rl];
    const u32x4* ph = (const u32x4*)(Ah + (size_t)(cid * 16 + rl) * 64 + gp * 8);
    const u32x4* pl = (const u32x4*)(Al + (size_t)(cid * 16 + rl) * 64 + gp * 8);
    bf8 ah[2], al4[2];
    #pragma unroll
    for (int kk = 0; kk < 2; ++kk) {
        ah[kk]  = __builtin_bit_cast(bf8, ph[kk * 4]);
        al4[kk] = __builtin_bit_cast(bf8, pl[kk * 4]);
    }
    f4 acc[4];
    #pragma unroll
    for (int n = 0; n < 4; ++n) acc[n] = (f4)0.f;
    #pragma unroll
    for (int kk = 0; kk < 2; ++kk) {
        #pragma unroll
        for (int n = 0; n < 4; ++n)
            acc[n] = __builtin_amdgcn_mfma_f32_16x16x32_bf16(
                ah[kk], __builtin_bit_cast(bf8, B[n][kk]), acc[n], 0, 0, 0);
        #pragma unroll
        for (int n = 0; n < 4; ++n)
            acc[n] = __builtin_amdgcn_mfma_f32_16x16x32_bf16(
                al4[kk], __builtin_bit_cast(bf8, B[n][kk]), acc[n], 0, 0, 0);
    }
    #pragma unroll
    for (int n = 0; n < 4; ++n)
        #pragma unroll
        for (int t = 0; t < 4; ++t) {
            float v = tanh_fast(acc[n][t] + bs[n]);
            int node = cid * 16 + gp * 4 + t;
            int col = n * 16 + rl;
            x2[(size_t)node * 64 + col] = v;
            unsigned hi = f2bf(v);
            size_t o = (size_t)node * 128 + 64 + col;
            ch[o] = (ushort_t)hi;
            cl[o] = (ushort_t)f2bf(v - bf2f(hi));
        }
}

// ---------------- G1: x3 = tanh(cat @ Wc + brel2) -----------------------------
__global__ __launch_bounds__(256) void k_g1(
    const ushort_t* __restrict__ Ah, const ushort_t* __restrict__ Al,
    const unsigned* __restrict__ Wb_, const float* __restrict__ bias,
    ushort_t* __restrict__ Oh, ushort_t* __restrict__ Ol) {
    int wave = threadIdx.x >> 6, lane = threadIdx.x & 63;
    int cg = wave & 1, mg = wave >> 1;
    int rl = lane & 15, gp = lane >> 4;
    u32x4 B[4][4];
    const u32x4* Wb = (const u32x4*)Wb_;
    #pragma unroll
    for (int n = 0; n < 4; ++n)
        #pragma unroll
        for (int kk = 0; kk < 4; ++kk)
            B[n][kk] = Wb[((cg * 4 + n) * 4 + kk) * 64 + lane];
    float bs[4];
    #pragma unroll
    for (int n = 0; n < 4; ++n) bs[n] = bias[cg * 64 + n * 16 + rl];
    for (int it = 0; it < 2; ++it) {
        int cid = (blockIdx.x * 2 + it) * 2 + mg;
        if (cid >= NCHUNK) continue;
        const u32x4* ph = (const u32x4*)(Ah + (size_t)(cid * 16 + rl) * 128 + gp * 8);
        const u32x4* pl = (const u32x4*)(Al + (size_t)(cid * 16 + rl) * 128 + gp * 8);
        bf8 ah[4], al4[4];
        #pragma unroll
        for (int kk = 0; kk < 4; ++kk) {
            ah[kk]  = __builtin_bit_cast(bf8, ph[kk * 4]);
            al4[kk] = __builtin_bit_cast(bf8, pl[kk * 4]);
        }
        f4 acc[4];
        #pragma unroll
        for (int n = 0; n < 4; ++n) acc[n] = (f4)0.f;
        #pragma unroll
        for (int kk = 0; kk < 4; ++kk) {
            #pragma unroll
            for (int n = 0; n < 4; ++n)
                acc[n] = __builtin_amdgcn_mfma_f32_16x16x32_bf16(
                    ah[kk], __builtin_bit_cast(bf8, B[n][kk]), acc[n], 0, 0, 0);
            #pragma unroll
            for (int n = 0; n < 4; ++n)
                acc[n] = __builtin_amdgcn_mfma_f32_16x16x32_bf16(
                    al4[kk], __builtin_bit_cast(bf8, B[n][kk]), acc[n], 0, 0, 0);
        }
        #pragma unroll
        for (int n = 0; n < 4; ++n)
            #pragma unroll
            for (int t = 0; t < 4; ++t) {
                float v = tanh_fast(acc[n][t] + bs[n]);
                unsigned hi = f2bf(v);
                int node = cid * 16 + gp * 4 + t;
                int col = cg * 64 + n * 16 + rl;
                Oh[(size_t)node * 128 + col] = (ushort_t)hi;
                Ol[(size_t)node * 128 + col] = (ushort_t)f2bf(v - bf2f(hi));
            }
    }
}

// ---------------- G2: [P|Q] = x3 @ Wpq (+bd0) ---------------------------------
__global__ __launch_bounds__(256) void k_g2(
    const ushort_t* __restrict__ Ah, const ushort_t* __restrict__ Al,
    const unsigned* __restrict__ Wb_, const float* __restrict__ bd0,
    float* __restrict__ P, float* __restrict__ Qb) {
    int cg = threadIdx.x >> 6, lane = threadIdx.x & 63;
    int rl = lane & 15, gp = lane >> 4;
    u32x4 B[4][4];
    const u32x4* Wb = (const u32x4*)Wb_;
    #pragma unroll
    for (int n = 0; n < 4; ++n)
        #pragma unroll
        for (int kk = 0; kk < 4; ++kk)
            B[n][kk] = Wb[((cg * 4 + n) * 4 + kk) * 64 + lane];
    float bs[4];
    #pragma unroll
    for (int n = 0; n < 4; ++n) {
        int j = cg * 64 + n * 16 + rl;
        bs[n] = (j < 128) ? bd0[j] : 0.f;
    }
    for (int it = 0; it < 2; ++it) {
        int cid = blockIdx.x * 2 + it;
        if (cid >= NCHUNK) continue;
        const u32x4* ph = (const u32x4*)(Ah + (size_t)(cid * 16 + rl) * 128 + gp * 8);
        const u32x4* pl = (const u32x4*)(Al + (size_t)(cid * 16 + rl) * 128 + gp * 8);
        bf8 ah[4], al4[4];
        #pragma unroll
        for (int kk = 0; kk < 4; ++kk) {
            ah[kk]  = __builtin_bit_cast(bf8, ph[kk * 4]);
            al4[kk] = __builtin_bit_cast(bf8, pl[kk * 4]);
        }
        f4 acc[4];
        #pragma unroll
        for (int n = 0; n < 4; ++n) acc[n] = (f4)0.f;
        #pragma unroll
        for (int kk = 0; kk < 4; ++kk) {
            #pragma unroll
            for (int n = 0; n < 4; ++n)
                acc[n] = __builtin_amdgcn_mfma_f32_16x16x32_bf16(
                    ah[kk], __builtin_bit_cast(bf8, B[n][kk]), acc[n], 0, 0, 0);
            #pragma unroll
            for (int n = 0; n < 4; ++n)
                acc[n] = __builtin_amdgcn_mfma_f32_16x16x32_bf16(
                    al4[kk], __builtin_bit_cast(bf8, B[n][kk]), acc[n], 0, 0, 0);
        }
        #pragma unroll
        for (int n = 0; n < 4; ++n) {
            int j = cg * 64 + n * 16 + rl;
            #pragma unroll
            for (int t = 0; t < 4; ++t) {
                float v = acc[n][t] + bs[n];
                int node = cid * 16 + gp * 4 + t;
                if (j < 128) P[(size_t)node * 128 + j] = v;
                else         Qb[(size_t)node * 128 + (j - 128)] = v;
            }
        }
    }
}

// ---------------- h0 stats only; grid N_G*32, 1 tile/wave ---------------------
__global__ __launch_bounds__(256, 1) void k_h0s(
    const int* __restrict__ edges, const float* __restrict__ ea,
    const float* __restrict__ P, const float* __restrict__ Qb,
    const float* __restrict__ Wd0,
    float* __restrict__ S0, float* __restrict__ Q0s) {
    int g = blockIdx.x >> 5, tb = blockIdx.x & 31;
    int wave = threadIdx.x >> 6, lane = threadIdx.x & 63;
    int row = lane & 15, grp = lane >> 4;
    int tile = tb * 4 + wave;
    f4 wmr[4][2];
    #pragma unroll
    for (int kk = 0; kk < 4; ++kk) {
        const f4* wmp = (const f4*)(Wd0 + 16384 + kk * 32 + grp * 8);
        wmr[kk][0] = wmp[0]; wmr[kk][1] = wmp[1];
    }
    f4 s[4][2], q[4][2];
    #pragma unroll
    for (int kk = 0; kk < 4; ++kk)
        #pragma unroll
        for (int h = 0; h < 2; ++h) { s[kk][h] = (f4)0.f; q[kk][h] = (f4)0.f; }

    if (tile < 125) {
        int eg0 = g * EPG + tile * 32;
        #pragma unroll
        for (int m = 0; m < 2; ++m) {
            int e = eg0 + 16 * m + row;
            int sn = edges[e], dn = edges[N_EDGES + e];
            float w = ea[2 * e];
            const f4* Pr = (const f4*)(P + sn * 128);
            const f4* Qr = (const f4*)(Qb + dn * 128);
            #pragma unroll
            for (int kk = 0; kk < 4; ++kk) {
                int o = kk * 8 + grp * 2;
                f4 p0 = Pr[o], p1 = Pr[o + 1];
                f4 q0 = Qr[o], q1 = Qr[o + 1];
                #pragma unroll
                for (int r = 0; r < 4; ++r) {
                    float h0 = tanh_fast(p0[r] + q0[r] + w * wmr[kk][0][r]);
                    float h1 = tanh_fast(p1[r] + q1[r] + w * wmr[kk][1][r]);
                    s[kk][0][r] += h0; q[kk][0][r] += h0 * h0;
                    s[kk][1][r] += h1; q[kk][1][r] += h1 * h1;
                }
            }
        }
    }
    #pragma unroll
    for (int kk = 0; kk < 4; ++kk)
        #pragma unroll
        for (int h = 0; h < 2; ++h)
            #pragma unroll
            for (int r = 0; r < 4; ++r) {
                float sv = s[kk][h][r], qv = q[kk][h][r];
                sv += __shfl_xor(sv, 1); sv += __shfl_xor(sv, 2);
                sv += __shfl_xor(sv, 4); sv += __shfl_xor(sv, 8);
                qv += __shfl_xor(qv, 1); qv += __shfl_xor(qv, 2);
                qv += __shfl_xor(qv, 4); qv += __shfl_xor(qv, 8);
                if (row == 0 && tile < 125) {
                    int k = kk * 32 + grp * 8 + h * 4 + r;
                    atomicAdd(&S0[g * 128 + k], sv);
                    atomicAdd(&Q0s[g * 128 + k], qv);
                }
            }
}

// ---------------- fold gnorm0 -> W1b + gam ------------------------------------
__global__ __launch_bounds__(256) void k_fin0(
    const float* __restrict__ S0, const float* __restrict__ Q0s,
    const float* __restrict__ gnw, const float* __restrict__ gnb, const float* __restrict__ gnms,
    const float* __restrict__ Wd1, const float* __restrict__ bd1,
    unsigned* __restrict__ W1b, float* __restrict__ gam) {
    int g = blockIdx.x;
    __shared__ float al[128], be[128];
    if (threadIdx.x < 128) {
        int k = threadIdx.x;
        float S = S0[g * 128 + k], Q = Q0s[g * 128 + k];
        float mean = S * (1.f / EPG);
        float t = mean * gnms[k];
        float var = (Q - 2.f * t * S) * (1.f / EPG) + t * t;
        float a = gnw[k] * rsqrtf(var + 1e-5f);
        al[k] = a;
        be[k] = gnb[k] - a * t;
    }
    __syncthreads();
    unsigned* Wb = W1b + (size_t)g * 4096;
    for (int i = threadIdx.x; i < 4096; i += 256) {
        int t = i & 3, l = (i >> 2) & 63, kk = (i >> 8) & 3, n = i >> 10;
        int k = kk * 32 + ((l >> 4) << 3) + 2 * t;
        int j = 16 * n + (l & 15);
        unsigned lo = f2bf(al[k] * Wd1[k * 64 + j]);
        unsigned hi = f2bf(al[k + 1] * Wd1[(k + 1) * 64 + j]);
        Wb[i] = lo | (hi << 16);
    }
    if (threadIdx.x < 64) {
        int j = threadIdx.x;
        float acc = bd1[j];
        #pragma unroll 8
        for (int k = 0; k < 128; ++k) acc += be[k] * Wd1[k * 64 + j];
        gam[g * 64 + j] = acc;
    }
}

// ---------------- h1 pass: recompute h0, MFMA, stats + bf16 h1 store ----------
__global__ __launch_bounds__(256, 1) void k_h1ms(
    const int* __restrict__ edges, const float* __restrict__ ea,
    const float* __restrict__ P, const float* __restrict__ Qb,
    const float* __restrict__ Wd0,
    const unsigned* __restrict__ W1b, const float* __restrict__ gam,
    float* __restrict__ S1, float* __restrict__ Q1s, unsigned* __restrict__ h1ff) {
    int g = blockIdx.x >> 5, tb = blockIdx.x & 31;
    int wave = threadIdx.x >> 6, lane = threadIdx.x & 63;
    int col = lane & 15, grp = lane >> 4;
    int tile = tb * 4 + wave;
    bf8 bfr[4][4];
    {
        const u32x4* Wb = (const u32x4*)(W1b + (size_t)g * 4096);
        #pragma unroll
        for (int n = 0; n < 4; ++n)
            #pragma unroll
            for (int kk = 0; kk < 4; ++kk)
                bfr[n][kk] = __builtin_bit_cast(bf8, Wb[(n * 4 + kk) * 64 + lane]);
    }
    f4 wmr[4][2];
    #pragma unroll
    for (int kk = 0; kk < 4; ++kk) {
        const f4* wmp = (const f4*)(Wd0 + 16384 + kk * 32 + grp * 8);
        wmr[kk][0] = wmp[0]; wmr[kk][1] = wmp[1];
    }
    float gamn[4];
    #pragma unroll
    for (int n = 0; n < 4; ++n) gamn[n] = gam[g * 64 + 16 * n + col];
    float sacc[4] = {0.f, 0.f, 0.f, 0.f}, qacc[4] = {0.f, 0.f, 0.f, 0.f};

    if (tile < 125) {
        int eg0 = g * EPG + tile * 32;
        int tileG = g * 125 + tile;
        bf8 af[2][4];
        #pragma unroll
        for (int m = 0; m < 2; ++m) {
            int e = eg0 + 16 * m + col;
            int sn = edges[e], dn = edges[N_EDGES + e];
            float w = ea[2 * e];
            const f4* Pr = (const f4*)(P + sn * 128);
            const f4* Qr = (const f4*)(Qb + dn * 128);
            #pragma unroll
            for (int kk = 0; kk < 4; ++kk) {
                int o = kk * 8 + grp * 2;
                f4 p0 = Pr[o], p1 = Pr[o + 1];
                f4 q0 = Qr[o], q1 = Qr[o + 1];
                bf8 a;
                #pragma unroll
                for (int r = 0; r < 4; ++r) {
                    float h0 = tanh_fast(p0[r] + q0[r] + w * wmr[kk][0][r]);
                    float h1 = tanh_fast(p1[r] + q1[r] + w * wmr[kk][1][r]);
                    a[r]     = (short)f2bf(h0);
                    a[4 + r] = (short)f2bf(h1);
                }
                af[m][kk] = a;
            }
        }
        f4 acc[2][4];
        #pragma unroll
        for (int m = 0; m < 2; ++m)
            #pragma unroll
            for (int n = 0; n < 4; ++n) acc[m][n] = (f4)0.f;
        #pragma unroll
        for (int kk = 0; kk < 4; ++kk)
            #pragma unroll
            for (int m = 0; m < 2; ++m)
                #pragma unroll
                for (int n = 0; n < 4; ++n)
                    acc[m][n] = __builtin_amdgcn_mfma_f32_16x16x32_bf16(
                        af[m][kk], bfr[n][kk], acc[m][n], 0, 0, 0);
        #pragma unroll
        for (int m = 0; m < 2; ++m)
            #pragma unroll
            for (int n = 0; n < 4; ++n) {
                float h[4];
                #pragma unroll
                for (int t = 0; t < 4; ++t) {
                    h[t] = tanh_fast(acc[m][n][t] + gamn[n]);
                    sacc[n] += h[t]; qacc[n] += h[t] * h[t];
                }
                unsigned w0 = f2bf(h[0]) | (f2bf(h[1]) << 16);
                unsigned w1 = f2bf(h[2]) | (f2bf(h[3]) << 16);
                size_t base = ((size_t)(tileG * 2 + m) * 4 + n) * 2;
                h1ff[(base + 0) * 64 + lane] = w0;
                h1ff[(base + 1) * 64 + lane] = w1;
            }
    }
    #pragma unroll
    for (int n = 0; n < 4; ++n) {
        float s = sacc[n], q = qacc[n];
        s += __shfl_xor(s, 16); s += __shfl_xor(s, 32);
        q += __shfl_xor(q, 16); q += __shfl_xor(q, 32);
        if (lane < 16) {
            atomicAdd(&S1[g * 64 + 16 * n + col], s);
            atomicAdd(&Q1s[g * 64 + 16 * n + col], q);
        }
    }
}

// ---------------- vals pass: read h1ff, dot, pair-min (R6-verified) -----------
__global__ __launch_bounds__(256) void k_vals(
    const int* __restrict__ edges, const unsigned* __restrict__ h1ff,
    const float* __restrict__ ug, const float* __restrict__ cg,
    float* __restrict__ vals, float* __restrict__ outp) {
    int g = blockIdx.x >> 4, tb = blockIdx.x & 15;
    int wave = threadIdx.x >> 6, lane = threadIdx.x & 63;
    int col = lane & 15, grp = lane >> 4;
    int slot = tb * 4 + wave;
    float un[4];
    #pragma unroll
    for (int n = 0; n < 4; ++n) un[n] = ug[g * 64 + 16 * n + col];
    float cgv = cg[g];
    for (int j = 0; j < 2; ++j) {
        int tile = slot + 64 * j;
        if (tile >= 125) break;
        int tileG = g * 125 + tile;
        int eg0 = g * EPG + tile * 32;
        #pragma unroll
        for (int m = 0; m < 2; ++m) {
            float v[4] = {0.f, 0.f, 0.f, 0.f};
            #pragma unroll
            for (int n = 0; n < 4; ++n) {
                size_t base = ((size_t)(tileG * 2 + m) * 4 + n) * 2;
                unsigned w0 = h1ff[(base + 0) * 64 + lane];
                unsigned w1 = h1ff[(base + 1) * 64 + lane];
                v[0] += un[n] * bf2f(w0 & 0xFFFFu);
                v[1] += un[n] * bf2f(w0 >> 16);
                v[2] += un[n] * bf2f(w1 & 0xFFFFu);
                v[3] += un[n] * bf2f(w1 >> 16);
            }
            float rp[4];
            #pragma unroll
            for (int t = 0; t < 4; ++t) {
                float vv = v[t];
                vv += __shfl_xor(vv, 1); vv += __shfl_xor(vv, 2);
                vv += __shfl_xor(vv, 4); vv += __shfl_xor(vv, 8);
                rp[t] = vv + cgv;
            }
            if (col == 0) {
                #pragma unroll
                for (int pr = 0; pr < 2; ++pr) {
                    float va = rp[2 * pr], vb = rp[2 * pr + 1];
                    int p = ((eg0 + 16 * m + grp * 4) >> 1) + pr;
                    vals[p] = fminf(va, vb);
                    outp[600000 + p] = (vb < va) ? 1.f : 0.f;
                    int e = 2 * p;
                    outp[p]          = (float)edges[e];
                    outp[200000 + p] = (float)edges[N_EDGES + e];
                }
            }
        }
    }
}

// ---------------- fold gnorm1 into Wout ---------------------------------------
__global__ void k_fin1(const float* __restrict__ S1, const float* __restrict__ Q1s,
                       const float* __restrict__ gnw, const float* __restrict__ gnb,
                       const float* __restrict__ gnms,
                       const float* __restrict__ Wout, const float* __restrict__ bout,
                       float* __restrict__ ug, float* __restrict__ cg) {
    int g = blockIdx.x; int j = threadIdx.x;  // 64 threads
    float S = S1[g * 64 + j], Q = Q1s[g * 64 + j];
    float mean = S * (1.f / EPG);
    float t = mean * gnms[j];
    float var = (Q - 2.f * t * S) * (1.f / EPG) + t * t;
    float a = gnw[j] * rsqrtf(var + 1e-5f);
    float b = gnb[j] - a * t;
    ug[g * 64 + j] = a * Wout[j];
    float c = b * Wout[j];
    #pragma unroll
    for (int off = 32; off; off >>= 1) c += __shfl_xor(c, off);
    if (j == 0) cg[g] = c + bout[0];
}

// ---------------- per-graph softmax -------------------------------------------
__global__ __launch_bounds__(256) void k_softmax(const float* __restrict__ vals,
                                                 float* __restrict__ outp) {
    int g = blockIdx.x;
    __shared__ float rbuf[4], rbuf2[4];
    int t = threadIdx.x;
    const float* v = vals + g * PPG;
    float mx = -1e30f;
    for (int i = t; i < PPG; i += 256) mx = fmaxf(mx, v[i]);
    #pragma unroll
    for (int off = 32; off; off >>= 1) mx = fmaxf(mx, __shfl_xor(mx, off));
    if ((t & 63) == 0) rbuf[t >> 6] = mx;
    __syncthreads();
    mx = fmaxf(fmaxf(rbuf[0], rbuf[1]), fmaxf(rbuf[2], rbuf[3]));
    float sm = 0.f;
    for (int i = t; i < PPG; i += 256) sm += expf(v[i] - mx);
    #pragma unroll
    for (int off = 32; off; off >>= 1) sm += __shfl_xor(sm, off);
    if ((t & 63) == 0) rbuf2[t >> 6] = sm;
    __syncthreads();
    sm = rbuf2[0] + rbuf2[1] + rbuf2[2] + rbuf2[3];
    for (int i = t; i < PPG; i += 256)
        outp[400000 + g * PPG + i] = expf(v[i] - mx) / (sm + 1e-16f);
}

extern "C" void kernel_launch(void* const* d_in, const int* in_sizes, int n_in,
                              void* d_out, int out_size, void* d_ws, size_t ws_size,
                              hipStream_t stream) {
    const float* x     = (const float*)d_in[0];
    const int*   edges = (const int*)d_in[1];
    const float* ea    = (const float*)d_in[2];
    const float* Wrel0 = (const float*)d_in[6],  *brel0 = (const float*)d_in[7],  *Wroot0 = (const float*)d_in[8];
    const float* Wrel1 = (const float*)d_in[9],  *brel1 = (const float*)d_in[10], *Wroot1 = (const float*)d_in[11];
    const float* Wrel2 = (const float*)d_in[12], *brel2 = (const float*)d_in[13], *Wroot2 = (const float*)d_in[14];
    const float* Wd0 = (const float*)d_in[15],  *bd0 = (const float*)d_in[16];
    const float* gnw0 = (const float*)d_in[17], *gnb0 = (const float*)d_in[18], *gnms0 = (const float*)d_in[19];
    const float* Wd1 = (const float*)d_in[20],  *bd1 = (const float*)d_in[21];
    const float* gnw1 = (const float*)d_in[22], *gnb1 = (const float*)d_in[23], *gnms1 = (const float*)d_in[24];
    const float* Wout = (const float*)d_in[25], *bout = (const float*)d_in[26];
    float* o = (float*)d_out;
    float* w = (float*)d_ws;

    // region A [0, 8.25M): early node tensors -> x3 planes -> h1ff
    float* agg5 = w;
    float* x1   = w + 250000;
    float* x2   = w + 1850000;
    ushort_t* c2h = (ushort_t*)(w + 5050000);
    ushort_t* c2l = (ushort_t*)(w + 6650000);
    ushort_t* x3h = (ushort_t*)(w + 0);
    ushort_t* x3l = (ushort_t*)(w + 3200000);
    unsigned* h1ff = (unsigned*)(w + 0);          // 12.8M u32 (after k_g2; x3 dead)
    // region B [8.25M, 21.05M): cat planes -> P|Qb
    float* P    = w + 8250000;
    float* Qb   = w + 14650000;
    ushort_t* cath = (ushort_t*)(w + 8250000);
    ushort_t* catl = (ushort_t*)(w + 11450000);
    // tail [21.05M, ...)
    float* tail = w + 21050000;
    unsigned* Wcb  = (unsigned*)tail;
    unsigned* Wpqb = Wcb + 8192;
    unsigned* W2b  = Wpqb + 16384;
    int* cnt   = (int*)(W2b + 2048);
    int* fillc = cnt + 50000;
    int* offs  = fillc + 50000;
    int* esrc  = offs + 50000;
    float* ew  = (float*)(esrc + 200000);
    float* S0  = ew + 200000;
    float* Q0s = S0 + 12800;
    unsigned* W1b = (unsigned*)(Q0s + 12800);
    float* gam = (float*)(W1b + 409600);
    float* S1  = gam + 6400;
    float* Q1s = S1 + 6400;
    float* ug  = Q1s + 6400;
    float* cg  = ug + 6400;
    float* vals = cg + 100;

    hipMemsetAsync(cnt, 0, 100000 * sizeof(int), stream);
    hipMemsetAsync(S0, 0, 25600 * sizeof(float), stream);
    hipMemsetAsync(S1, 0, 12800 * sizeof(float), stream);

    k_packWc<<<32, 256, 0, stream>>>(Wrel2, Wroot2, Wcb);
    k_packWpq<<<64, 256, 0, stream>>>(Wd0, Wpqb);
    k_packW2<<<8, 256, 0, stream>>>(Wrel1, Wroot1, W2b);

    k_csr_count<<<782, 256, 0, stream>>>(edges, cnt);
    k_csr_scan<<<N_G, 512, 0, stream>>>(cnt, offs);
    k_csr_fill<<<782, 256, 0, stream>>>(edges, ea, offs, fillc, esrc, ew);

    k_gath5<<<1563, 256, 0, stream>>>(cnt, offs, esrc, ew, x, agg5);
    k_dense1<<<6250, 256, 0, stream>>>(x, agg5, Wrel0, brel0, Wroot0, x1, c2h, c2l);
    k_gath32<<<6250, 256, 0, stream>>>(cnt, offs, esrc, ew, x1, c2h, c2l);
    k_g1b<<<782, 256, 0, stream>>>(c2h, c2l, W2b, brel1, x2, cath, catl);
    k_gath64<<<12500, 256, 0, stream>>>(cnt, offs, esrc, ew, x2, cath, catl);

    k_g1<<<(NCHUNK + 3) / 4, 256, 0, stream>>>(cath, catl, Wcb, brel2, x3h, x3l);
    k_g2<<<(NCHUNK + 1) / 2, 256, 0, stream>>>(x3h, x3l, Wpqb, bd0, P, Qb);

    k_h0s<<<N_G * 32, 256, 0, stream>>>(edges, ea, P, Qb, Wd0, S0, Q0s);
    k_fin0<<<N_G, 256, 0, stream>>>(S0, Q0s, gnw0, gnb0, gnms0, Wd1, bd1, W1b, gam);

    k_h1ms<<<N_G * 32, 256, 0, stream>>>(edges, ea, P, Qb, Wd0, W1b, gam, S1, Q1s, h1ff);
    k_fin1<<<N_G, 64, 0, stream>>>(S1, Q1s, gnw1, gnb1, gnms1, Wout, bout, ug, cg);
    k_vals<<<N_G * 16, 256, 0, stream>>>(edges, h1ff, ug, cg, vals, o);

    k_softmax<<<N_G, 256, 0, stream>>>(vals, o);
}

// Round 8
// 471.001 us; speedup vs baseline: 1.0437x; 1.0437x over previous
//
#include <hip/hip_runtime.h>

// GraphNN R8: R5 pipeline (best-known-good) with two safe deltas:
//  - k_h0s: R6 j-loop template (no spill), grid N_G*16.
//  - k_h1m<0> stores bf16 h1 C-frags (h1ff at w+25.6M, disjoint from P/Qb);
//    vals sweep becomes the light k_vals reader. Fallback = R5 recompute.

#define N_NODES 50000
#define N_EDGES 400000
#define N_PAIRS 200000
#define N_G     100
#define EPG     4000
#define PPG     2000
#define NCHUNK  3125   // 50000/16

typedef float  f4   __attribute__((ext_vector_type(4)));
typedef short  bf8  __attribute__((ext_vector_type(8)));
typedef unsigned u32x4 __attribute__((ext_vector_type(4)));
typedef unsigned short ushort_t;

__device__ __forceinline__ float tanh_fast(float x) {
    float cx = fminf(15.f, fmaxf(-15.f, x));
    float e = __expf(2.f * cx);
    return (e - 1.f) * __builtin_amdgcn_rcpf(e + 1.f);
}
__device__ __forceinline__ unsigned f2bf(float f) {   // RNE fp32->bf16
    unsigned u = __float_as_uint(f);
    return (u + 0x7FFFu + ((u >> 16) & 1u)) >> 16;
}
__device__ __forceinline__ float bf2f(unsigned h) { return __uint_as_float(h << 16); }

// ---------------- CSR build ---------------------------------------------------
__global__ void k_csr_count(const int* __restrict__ edges, int* __restrict__ cnt) {
    int p = blockIdx.x * 256 + threadIdx.x;
    if (p >= N_PAIRS) return;
    atomicAdd(&cnt[edges[N_EDGES + 2 * p]], 1);
}
__global__ __launch_bounds__(512) void k_csr_scan(const int* __restrict__ cnt,
                                                  int* __restrict__ offs) {
    __shared__ int s[512];
    int g = blockIdx.x, t = threadIdx.x;
    int v = (t < 500) ? cnt[g * 500 + t] : 0;
    s[t] = v; __syncthreads();
    for (int off = 1; off < 512; off <<= 1) {
        int a = (t >= off) ? s[t - off] : 0;
        __syncthreads();
        s[t] += a; __syncthreads();
    }
    if (t < 500) offs[g * 500 + t] = g * PPG + s[t] - v;
}
__global__ void k_csr_fill(const int* __restrict__ edges, const float* __restrict__ ea,
                           const int* __restrict__ offs, int* __restrict__ fillc,
                           int* __restrict__ esrc, float* __restrict__ ew) {
    int p = blockIdx.x * 256 + threadIdx.x;
    if (p >= N_PAIRS) return;
    int d = edges[N_EDGES + 2 * p];
    int pos = offs[d] + atomicAdd(&fillc[d], 1);
    esrc[pos] = edges[2 * p];
    ew[pos] = ea[4 * p] + ea[4 * p + 2];
}

// ---------------- gathers -----------------------------------------------------
__global__ __launch_bounds__(256) void k_gath5(
    const int* __restrict__ cnt, const int* __restrict__ offs,
    const int* __restrict__ esrc, const float* __restrict__ ew,
    const float* __restrict__ x, float* __restrict__ agg) {
    int t = blockIdx.x * 256 + threadIdx.x;
    int n = t >> 3, k = t & 7;
    if (n >= N_NODES || k >= 5) return;
    int o0 = offs[n], c = cnt[n];
    float acc = 0.f;
    for (int i = o0; i < o0 + c; ++i) acc += x[esrc[i] * 5 + k] * ew[i];
    agg[n * 5 + k] = acc;
}
__global__ __launch_bounds__(256) void k_gath32(
    const int* __restrict__ cnt, const int* __restrict__ offs,
    const int* __restrict__ esrc, const float* __restrict__ ew,
    const float* __restrict__ x1, ushort_t* __restrict__ c2h, ushort_t* __restrict__ c2l) {
    int n = blockIdx.x * 8 + (threadIdx.x >> 5), k = threadIdx.x & 31;
    if (n >= N_NODES) return;
    int o0 = offs[n], c = cnt[n];
    float acc = 0.f;
    for (int i = o0; i < o0 + c; ++i) acc += x1[esrc[i] * 32 + k] * ew[i];
    unsigned hi = f2bf(acc);
    size_t o = (size_t)n * 64 + k;
    c2h[o] = (ushort_t)hi;
    c2l[o] = (ushort_t)f2bf(acc - bf2f(hi));
}
__global__ __launch_bounds__(256) void k_gath64(
    const int* __restrict__ cnt, const int* __restrict__ offs,
    const int* __restrict__ esrc, const float* __restrict__ ew,
    const float* __restrict__ x2, ushort_t* __restrict__ ch, ushort_t* __restrict__ cl) {
    int n = blockIdx.x * 4 + (threadIdx.x >> 6), k = threadIdx.x & 63;
    if (n >= N_NODES) return;
    int o0 = offs[n], c = cnt[n];
    float acc = 0.f;
    for (int i = o0; i < o0 + c; ++i) acc += x2[esrc[i] * 64 + k] * ew[i];
    unsigned hi = f2bf(acc);
    size_t o = (size_t)n * 128 + k;
    ch[o] = (ushort_t)hi;
    cl[o] = (ushort_t)f2bf(acc - bf2f(hi));
}

// ---------------- layer1 dense 5->32 ------------------------------------------
__global__ __launch_bounds__(256) void k_dense1(
    const float* __restrict__ x, const float* __restrict__ agg,
    const float* __restrict__ Wrel, const float* __restrict__ brel,
    const float* __restrict__ Wroot, float* __restrict__ x1,
    ushort_t* __restrict__ c2h, ushort_t* __restrict__ c2l) {
    __shared__ float wr[160], wt[160], bb[32];
    __shared__ float sa[8][5], sx[8][5];
    for (int i = threadIdx.x; i < 160; i += 256) { wr[i] = Wrel[i]; wt[i] = Wroot[i]; }
    if (threadIdx.x < 32) bb[threadIdx.x] = brel[threadIdx.x];
    int j = threadIdx.x & 31, nl = threadIdx.x >> 5;
    int nb = blockIdx.x * 8;
    __syncthreads();
    for (int i = threadIdx.x; i < 40; i += 256) {
        int nn = nb + i / 5, kk = i % 5;
        float av = 0.f, xv = 0.f;
        if (nn < N_NODES) { av = agg[nn * 5 + kk]; xv = x[nn * 5 + kk]; }
        sa[i / 5][kk] = av; sx[i / 5][kk] = xv;
    }
    __syncthreads();
    int n = nb + nl;
    if (n < N_NODES) {
        float acc = bb[j];
        #pragma unroll
        for (int k = 0; k < 5; ++k)
            acc += sa[nl][k] * wr[k * 32 + j] + sx[nl][k] * wt[k * 32 + j];
        float v = tanhf(acc);
        x1[n * 32 + j] = v;
        unsigned hi = f2bf(v);
        size_t o = (size_t)n * 64 + 32 + j;
        c2h[o] = (ushort_t)hi;
        c2l[o] = (ushort_t)f2bf(v - bf2f(hi));
    }
}

// ---------------- weight frag packers -----------------------------------------
__global__ void k_packWc(const float* __restrict__ Wrel2, const float* __restrict__ Wroot2,
                         unsigned* __restrict__ dst) {
    int i = blockIdx.x * 256 + threadIdx.x;   // 8192
    int t = i & 3, l = (i >> 2) & 63, kk = (i >> 8) & 3, n = i >> 10;
    int k = kk * 32 + ((l >> 4) << 3) + 2 * t;
    int j = 16 * n + (l & 15);
    float v0 = (k < 64) ? Wrel2[k * 128 + j] : Wroot2[(k - 64) * 128 + j];
    float v1 = (k + 1 < 64) ? Wrel2[(k + 1) * 128 + j] : Wroot2[(k + 1 - 64) * 128 + j];
    dst[i] = f2bf(v0) | (f2bf(v1) << 16);
}
__global__ void k_packWpq(const float* __restrict__ Wd0, unsigned* __restrict__ dst) {
    int i = blockIdx.x * 256 + threadIdx.x;   // 16384
    int t = i & 3, l = (i >> 2) & 63, kk = (i >> 8) & 3, n = i >> 10;
    int k = kk * 32 + ((l >> 4) << 3) + 2 * t;
    int j = 16 * n + (l & 15);
    float v0 = (j < 128) ? Wd0[k * 128 + j] : Wd0[(129 + k) * 128 + (j - 128)];
    float v1 = (j < 128) ? Wd0[(k + 1) * 128 + j] : Wd0[(129 + k + 1) * 128 + (j - 128)];
    dst[i] = f2bf(v0) | (f2bf(v1) << 16);
}
__global__ void k_packW2(const float* __restrict__ Wrel1, const float* __restrict__ Wroot1,
                         unsigned* __restrict__ dst) {
    int i = blockIdx.x * 256 + threadIdx.x;   // 2048
    int t = i & 3, l = (i >> 2) & 63, kk = (i >> 8) & 1, n = i >> 9;
    int k = kk * 32 + ((l >> 4) << 3) + 2 * t;
    int j = 16 * n + (l & 15);
    float v0 = (k < 32) ? Wrel1[k * 64 + j] : Wroot1[(k - 32) * 64 + j];
    float v1 = (k + 1 < 32) ? Wrel1[(k + 1) * 64 + j] : Wroot1[(k + 1 - 32) * 64 + j];
    dst[i] = f2bf(v0) | (f2bf(v1) << 16);
}

// ---------------- G1b: x2 = tanh(cat2 @ W2 + brel1) ---------------------------
__global__ __launch_bounds__(256) void k_g1b(
    const ushort_t* __restrict__ Ah, const ushort_t* __restrict__ Al,
    const unsigned* __restrict__ Wb_, const float* __restrict__ bias,
    float* __restrict__ x2, ushort_t* __restrict__ ch, ushort_t* __restrict__ cl) {
    int wave = threadIdx.x >> 6, lane = threadIdx.x & 63;
    int rl = lane & 15, gp = lane >> 4;
    int cid = blockIdx.x * 4 + wave;
    if (cid >= NCHUNK) return;
    u32x4 B[4][2];
    const u32x4* Wb = (const u32x4*)Wb_;
    #pragma unroll
    for (int n = 0; n < 4; ++n)
        #pragma unroll
        for (int kk = 0; kk < 2; ++kk)
            B[n][kk] = Wb[(n * 2 + kk) * 64 + lane];
    float bs[4];
    #pragma unroll
    for (int n = 0; n < 4; ++n) bs[n] = bias[n * 16 + rl];
    const u32x4* ph = (const u32x4*)(Ah + (size_t)(cid * 16 + rl) * 64 + gp * 8);
    const u32x4* pl = (const u32x4*)(Al + (size_t)(cid * 16 + rl) * 64 + gp * 8);
    bf8 ah[2], al4[2];
    #pragma unroll
    for (int kk = 0; kk < 2; ++kk) {
        ah[kk]  = __builtin_bit_cast(bf8, ph[kk * 4]);
        al4[kk] = __builtin_bit_cast(bf8, pl[kk * 4]);
    }
    f4 acc[4];
    #pragma unroll
    for (int n = 0; n < 4; ++n) acc[n] = (f4)0.f;
    #pragma unroll
    for (int kk = 0; kk < 2; ++kk) {
        #pragma unroll
        for (int n = 0; n < 4; ++n)
            acc[n] = __builtin_amdgcn_mfma_f32_16x16x32_bf16(
                ah[kk], __builtin_bit_cast(bf8, B[n][kk]), acc[n], 0, 0, 0);
        #pragma unroll
        for (int n = 0; n < 4; ++n)
            acc[n] = __builtin_amdgcn_mfma_f32_16x16x32_bf16(
                al4[kk], __builtin_bit_cast(bf8, B[n][kk]), acc[n], 0, 0, 0);
    }
    #pragma unroll
    for (int n = 0; n < 4; ++n)
        #pragma unroll
        for (int t = 0; t < 4; ++t) {
            float v = tanh_fast(acc[n][t] + bs[n]);
            int node = cid * 16 + gp * 4 + t;
            int col = n * 16 + rl;
            x2[(size_t)node * 64 + col] = v;
            unsigned hi = f2bf(v);
            size_t o = (size_t)node * 128 + 64 + col;
            ch[o] = (ushort_t)hi;
            cl[o] = (ushort_t)f2bf(v - bf2f(hi));
        }
}

// ---------------- G1: x3 = tanh(cat @ Wc + brel2) -----------------------------
__global__ __launch_bounds__(256) void k_g1(
    const ushort_t* __restrict__ Ah, const ushort_t* __restrict__ Al,
    const unsigned* __restrict__ Wb_, const float* __restrict__ bias,
    ushort_t* __restrict__ Oh, ushort_t* __restrict__ Ol) {
    int wave = threadIdx.x >> 6, lane = threadIdx.x & 63;
    int cg = wave & 1, mg = wave >> 1;
    int rl = lane & 15, gp = lane >> 4;
    u32x4 B[4][4];
    const u32x4* Wb = (const u32x4*)Wb_;
    #pragma unroll
    for (int n = 0; n < 4; ++n)
        #pragma unroll
        for (int kk = 0; kk < 4; ++kk)
            B[n][kk] = Wb[((cg * 4 + n) * 4 + kk) * 64 + lane];
    float bs[4];
    #pragma unroll
    for (int n = 0; n < 4; ++n) bs[n] = bias[cg * 64 + n * 16 + rl];
    for (int it = 0; it < 2; ++it) {
        int cid = (blockIdx.x * 2 + it) * 2 + mg;
        if (cid >= NCHUNK) continue;
        const u32x4* ph = (const u32x4*)(Ah + (size_t)(cid * 16 + rl) * 128 + gp * 8);
        const u32x4* pl = (const u32x4*)(Al + (size_t)(cid * 16 + rl) * 128 + gp * 8);
        bf8 ah[4], al4[4];
        #pragma unroll
        for (int kk = 0; kk < 4; ++kk) {
            ah[kk]  = __builtin_bit_cast(bf8, ph[kk * 4]);
            al4[kk] = __builtin_bit_cast(bf8, pl[kk * 4]);
        }
        f4 acc[4];
        #pragma unroll
        for (int n = 0; n < 4; ++n) acc[n] = (f4)0.f;
        #pragma unroll
        for (int kk = 0; kk < 4; ++kk) {
            #pragma unroll
            for (int n = 0; n < 4; ++n)
                acc[n] = __builtin_amdgcn_mfma_f32_16x16x32_bf16(
                    ah[kk], __builtin_bit_cast(bf8, B[n][kk]), acc[n], 0, 0, 0);
            #pragma unroll
            for (int n = 0; n < 4; ++n)
                acc[n] = __builtin_amdgcn_mfma_f32_16x16x32_bf16(
                    al4[kk], __builtin_bit_cast(bf8, B[n][kk]), acc[n], 0, 0, 0);
        }
        #pragma unroll
        for (int n = 0; n < 4; ++n)
            #pragma unroll
            for (int t = 0; t < 4; ++t) {
                float v = tanh_fast(acc[n][t] + bs[n]);
                unsigned hi = f2bf(v);
                int node = cid * 16 + gp * 4 + t;
                int col = cg * 64 + n * 16 + rl;
                Oh[(size_t)node * 128 + col] = (ushort_t)hi;
                Ol[(size_t)node * 128 + col] = (ushort_t)f2bf(v - bf2f(hi));
            }
    }
}

// ---------------- G2: [P|Q] = x3 @ Wpq (+bd0) ---------------------------------
__global__ __launch_bounds__(256) void k_g2(
    const ushort_t* __restrict__ Ah, const ushort_t* __restrict__ Al,
    const unsigned* __restrict__ Wb_, const float* __restrict__ bd0,
    float* __restrict__ P, float* __restrict__ Qb) {
    int cg = threadIdx.x >> 6, lane = threadIdx.x & 63;
    int rl = lane & 15, gp = lane >> 4;
    u32x4 B[4][4];
    const u32x4* Wb = (const u32x4*)Wb_;
    #pragma unroll
    for (int n = 0; n < 4; ++n)
        #pragma unroll
        for (int kk = 0; kk < 4; ++kk)
            B[n][kk] = Wb[((cg * 4 + n) * 4 + kk) * 64 + lane];
    float bs[4];
    #pragma unroll
    for (int n = 0; n < 4; ++n) {
        int j = cg * 64 + n * 16 + rl;
        bs[n] = (j < 128) ? bd0[j] : 0.f;
    }
    for (int it = 0; it < 2; ++it) {
        int cid = blockIdx.x * 2 + it;
        if (cid >= NCHUNK) continue;
        const u32x4* ph = (const u32x4*)(Ah + (size_t)(cid * 16 + rl) * 128 + gp * 8);
        const u32x4* pl = (const u32x4*)(Al + (size_t)(cid * 16 + rl) * 128 + gp * 8);
        bf8 ah[4], al4[4];
        #pragma unroll
        for (int kk = 0; kk < 4; ++kk) {
            ah[kk]  = __builtin_bit_cast(bf8, ph[kk * 4]);
            al4[kk] = __builtin_bit_cast(bf8, pl[kk * 4]);
        }
        f4 acc[4];
        #pragma unroll
        for (int n = 0; n < 4; ++n) acc[n] = (f4)0.f;
        #pragma unroll
        for (int kk = 0; kk < 4; ++kk) {
            #pragma unroll
            for (int n = 0; n < 4; ++n)
                acc[n] = __builtin_amdgcn_mfma_f32_16x16x32_bf16(
                    ah[kk], __builtin_bit_cast(bf8, B[n][kk]), acc[n], 0, 0, 0);
            #pragma unroll
            for (int n = 0; n < 4; ++n)
                acc[n] = __builtin_amdgcn_mfma_f32_16x16x32_bf16(
                    al4[kk], __builtin_bit_cast(bf8, B[n][kk]), acc[n], 0, 0, 0);
        }
        #pragma unroll
        for (int n = 0; n < 4; ++n) {
            int j = cg * 64 + n * 16 + rl;
            #pragma unroll
            for (int t = 0; t < 4; ++t) {
                float v = acc[n][t] + bs[n];
                int node = cid * 16 + gp * 4 + t;
                if (j < 128) P[(size_t)node * 128 + j] = v;
                else         Qb[(size_t)node * 128 + (j - 128)] = v;
            }
        }
    }
}

// ---------------- h0 stats (R6 j-loop template, STORE=0 path), N_G*16 ---------
__global__ __launch_bounds__(256, 1) void k_h0s(
    const int* __restrict__ edges, const float* __restrict__ ea,
    const float* __restrict__ P, const float* __restrict__ Qb,
    const float* __restrict__ Wd0,
    float* __restrict__ S0, float* __restrict__ Q0s) {
    int g = blockIdx.x >> 4, tb = blockIdx.x & 15;
    int wave = threadIdx.x >> 6, lane = threadIdx.x & 63;
    int row = lane & 15, grp = lane >> 4;
    int slot = tb * 4 + wave;
    f4 wmr[4][2];
    #pragma unroll
    for (int kk = 0; kk < 4; ++kk) {
        const f4* wmp = (const f4*)(Wd0 + 16384 + kk * 32 + grp * 8);
        wmr[kk][0] = wmp[0]; wmr[kk][1] = wmp[1];
    }
    f4 s[4][2], q[4][2];
    #pragma unroll
    for (int kk = 0; kk < 4; ++kk)
        #pragma unroll
        for (int h = 0; h < 2; ++h) { s[kk][h] = (f4)0.f; q[kk][h] = (f4)0.f; }

    for (int j = 0; j < 2; ++j) {
        int tile = slot + 64 * j;
        if (tile >= 125) break;
        int eg0 = g * EPG + tile * 32;
        #pragma unroll
        for (int m = 0; m < 2; ++m) {
            int e = eg0 + 16 * m + row;
            int sn = edges[e], dn = edges[N_EDGES + e];
            float w = ea[2 * e];
            const f4* Pr = (const f4*)(P + sn * 128);
            const f4* Qr = (const f4*)(Qb + dn * 128);
            #pragma unroll
            for (int kk = 0; kk < 4; ++kk) {
                int o = kk * 8 + grp * 2;
                f4 p0 = Pr[o], p1 = Pr[o + 1];
                f4 q0 = Qr[o], q1 = Qr[o + 1];
                #pragma unroll
                for (int r = 0; r < 4; ++r) {
                    float h0 = tanh_fast(p0[r] + q0[r] + w * wmr[kk][0][r]);
                    float h1 = tanh_fast(p1[r] + q1[r] + w * wmr[kk][1][r]);
                    s[kk][0][r] += h0; q[kk][0][r] += h0 * h0;
                    s[kk][1][r] += h1; q[kk][1][r] += h1 * h1;
                }
            }
        }
    }
    #pragma unroll
    for (int kk = 0; kk < 4; ++kk)
        #pragma unroll
        for (int h = 0; h < 2; ++h)
            #pragma unroll
            for (int r = 0; r < 4; ++r) {
                float sv = s[kk][h][r], qv = q[kk][h][r];
                sv += __shfl_xor(sv, 1); sv += __shfl_xor(sv, 2);
                sv += __shfl_xor(sv, 4); sv += __shfl_xor(sv, 8);
                qv += __shfl_xor(qv, 1); qv += __shfl_xor(qv, 2);
                qv += __shfl_xor(qv, 4); qv += __shfl_xor(qv, 8);
                if (row == 0) {
                    int k = kk * 32 + grp * 8 + h * 4 + r;
                    atomicAdd(&S0[g * 128 + k], sv);
                    atomicAdd(&Q0s[g * 128 + k], qv);
                }
            }
}

// ---------------- fold gnorm0 -> W1b + gam ------------------------------------
__global__ __launch_bounds__(256) void k_fin0(
    const float* __restrict__ S0, const float* __restrict__ Q0s,
    const float* __restrict__ gnw, const float* __restrict__ gnb, const float* __restrict__ gnms,
    const float* __restrict__ Wd1, const float* __restrict__ bd1,
    unsigned* __restrict__ W1b, float* __restrict__ gam) {
    int g = blockIdx.x;
    __shared__ float al[128], be[128];
    if (threadIdx.x < 128) {
        int k = threadIdx.x;
        float S = S0[g * 128 + k], Q = Q0s[g * 128 + k];
        float mean = S * (1.f / EPG);
        float t = mean * gnms[k];
        float var = (Q - 2.f * t * S) * (1.f / EPG) + t * t;
        float a = gnw[k] * rsqrtf(var + 1e-5f);
        al[k] = a;
        be[k] = gnb[k] - a * t;
    }
    __syncthreads();
    unsigned* Wb = W1b + (size_t)g * 4096;
    for (int i = threadIdx.x; i < 4096; i += 256) {
        int t = i & 3, l = (i >> 2) & 63, kk = (i >> 8) & 3, n = i >> 10;
        int k = kk * 32 + ((l >> 4) << 3) + 2 * t;
        int j = 16 * n + (l & 15);
        unsigned lo = f2bf(al[k] * Wd1[k * 64 + j]);
        unsigned hi = f2bf(al[k + 1] * Wd1[(k + 1) * 64 + j]);
        Wb[i] = lo | (hi << 16);
    }
    if (threadIdx.x < 64) {
        int j = threadIdx.x;
        float acc = bd1[j];
        #pragma unroll 8
        for (int k = 0; k < 128; ++k) acc += be[k] * Wd1[k * 64 + j];
        gam[g * 64 + j] = acc;
    }
}

// ---------------- h1 pass (R5 structure): stats(+h1 store) or vals ------------
// grid N_G*8, 4 waves, slot in [0,32), tile = slot+32j, j<4.
template<int DO_VALS, int STORE>
__global__ __launch_bounds__(256, 1) void k_h1m(
    const int* __restrict__ edges, const float* __restrict__ ea,
    const float* __restrict__ P, const float* __restrict__ Qb,
    const float* __restrict__ Wd0,
    const unsigned* __restrict__ W1b, const float* __restrict__ gam,
    const float* __restrict__ ug, const float* __restrict__ cg,
    float* __restrict__ S1, float* __restrict__ Q1s,
    float* __restrict__ vals, float* __restrict__ outp, unsigned* __restrict__ h1ff) {
    int g = blockIdx.x >> 3, tb = blockIdx.x & 7;
    int wave = threadIdx.x >> 6, lane = threadIdx.x & 63;
    int col = lane & 15, grp = lane >> 4;
    int slot = tb * 4 + wave;

    bf8 bfr[4][4];
    {
        const u32x4* Wb = (const u32x4*)(W1b + (size_t)g * 4096);
        #pragma unroll
        for (int n = 0; n < 4; ++n)
            #pragma unroll
            for (int kk = 0; kk < 4; ++kk)
                bfr[n][kk] = __builtin_bit_cast(bf8, Wb[(n * 4 + kk) * 64 + lane]);
    }
    f4 wmr[4][2];
    #pragma unroll
    for (int kk = 0; kk < 4; ++kk) {
        const f4* wmp = (const f4*)(Wd0 + 16384 + kk * 32 + grp * 8);
        wmr[kk][0] = wmp[0]; wmr[kk][1] = wmp[1];
    }
    float gamn[4], un[4] = {0.f, 0.f, 0.f, 0.f};
    #pragma unroll
    for (int n = 0; n < 4; ++n) gamn[n] = gam[g * 64 + 16 * n + col];
    float cgv = 0.f;
    if (DO_VALS) {
        #pragma unroll
        for (int n = 0; n < 4; ++n) un[n] = ug[g * 64 + 16 * n + col];
        cgv = cg[g];
    }
    float sacc[4] = {0.f, 0.f, 0.f, 0.f}, qacc[4] = {0.f, 0.f, 0.f, 0.f};

    for (int j = 0; j < 4; ++j) {
        int tile = slot + 32 * j;
        if (tile >= 125) break;
        int eg0 = g * EPG + tile * 32;
        bf8 af[2][4];
        #pragma unroll
        for (int m = 0; m < 2; ++m) {
            int e = eg0 + 16 * m + col;
            int sn = edges[e], dn = edges[N_EDGES + e];
            float w = ea[2 * e];
            const f4* Pr = (const f4*)(P + sn * 128);
            const f4* Qr = (const f4*)(Qb + dn * 128);
            #pragma unroll
            for (int kk = 0; kk < 4; ++kk) {
                int o = kk * 8 + grp * 2;
                f4 p0 = Pr[o], p1 = Pr[o + 1];
                f4 q0 = Qr[o], q1 = Qr[o + 1];
                bf8 a;
                #pragma unroll
                for (int r = 0; r < 4; ++r) {
                    float h0 = tanh_fast(p0[r] + q0[r] + w * wmr[kk][0][r]);
                    float h1 = tanh_fast(p1[r] + q1[r] + w * wmr[kk][1][r]);
                    a[r]     = (short)f2bf(h0);
                    a[4 + r] = (short)f2bf(h1);
                }
                af[m][kk] = a;
            }
        }
        f4 acc[2][4];
        #pragma unroll
        for (int m = 0; m < 2; ++m)
            #pragma unroll
            for (int n = 0; n < 4; ++n) acc[m][n] = (f4)0.f;
        #pragma unroll
        for (int kk = 0; kk < 4; ++kk)
            #pragma unroll
            for (int m = 0; m < 2; ++m)
                #pragma unroll
                for (int n = 0; n < 4; ++n)
                    acc[m][n] = __builtin_amdgcn_mfma_f32_16x16x32_bf16(
                        af[m][kk], bfr[n][kk], acc[m][n], 0, 0, 0);

        if (DO_VALS) {
            float rp[2][4];
            #pragma unroll
            for (int m = 0; m < 2; ++m)
                #pragma unroll
                for (int t = 0; t < 4; ++t) {
                    float v = 0.f;
                    #pragma unroll
                    for (int n = 0; n < 4; ++n)
                        v += un[n] * tanh_fast(acc[m][n][t] + gamn[n]);
                    v += __shfl_xor(v, 1); v += __shfl_xor(v, 2);
                    v += __shfl_xor(v, 4); v += __shfl_xor(v, 8);
                    rp[m][t] = v + cgv;
                }
            if (col == 0) {
                #pragma unroll
                for (int m = 0; m < 2; ++m)
                    #pragma unroll
                    for (int pr = 0; pr < 2; ++pr) {
                        float va = rp[m][2 * pr], vb = rp[m][2 * pr + 1];
                        int p = ((eg0 + 16 * m + grp * 4) >> 1) + pr;
                        vals[p] = fminf(va, vb);
                        outp[600000 + p] = (vb < va) ? 1.f : 0.f;
                        int e = 2 * p;
                        outp[p]          = (float)edges[e];
                        outp[200000 + p] = (float)edges[N_EDGES + e];
                    }
            }
        } else {
            int tileG = g * 125 + tile;
            #pragma unroll
            for (int m = 0; m < 2; ++m)
                #pragma unroll
                for (int n = 0; n < 4; ++n) {
                    float h[4];
                    #pragma unroll
                    for (int t = 0; t < 4; ++t) {
                        h[t] = tanh_fast(acc[m][n][t] + gamn[n]);
                        sacc[n] += h[t]; qacc[n] += h[t] * h[t];
                    }
                    if (STORE) {
                        unsigned w0 = f2bf(h[0]) | (f2bf(h[1]) << 16);
                        unsigned w1 = f2bf(h[2]) | (f2bf(h[3]) << 16);
                        size_t base = ((size_t)(tileG * 2 + m) * 4 + n) * 2;
                        h1ff[(base + 0) * 64 + lane] = w0;
                        h1ff[(base + 1) * 64 + lane] = w1;
                    }
                }
        }
    }
    if (!DO_VALS) {
        #pragma unroll
        for (int n = 0; n < 4; ++n) {
            float s = sacc[n], q = qacc[n];
            s += __shfl_xor(s, 16); s += __shfl_xor(s, 32);
            q += __shfl_xor(q, 16); q += __shfl_xor(q, 32);
            if (lane < 16) {
                atomicAdd(&S1[g * 64 + 16 * n + col], s);
                atomicAdd(&Q1s[g * 64 + 16 * n + col], q);
            }
        }
    }
}

// ---------------- vals pass: read h1ff, dot, pair-min -------------------------
__global__ __launch_bounds__(256) void k_vals(
    const int* __restrict__ edges, const unsigned* __restrict__ h1ff,
    const float* __restrict__ ug, const float* __restrict__ cg,
    float* __restrict__ vals, float* __restrict__ outp) {
    int g = blockIdx.x >> 4, tb = blockIdx.x & 15;
    int wave = threadIdx.x >> 6, lane = threadIdx.x & 63;
    int col = lane & 15, grp = lane >> 4;
    int slot = tb * 4 + wave;
    float un[4];
    #pragma unroll
    for (int n = 0; n < 4; ++n) un[n] = ug[g * 64 + 16 * n + col];
    float cgv = cg[g];
    for (int j = 0; j < 2; ++j) {
        int tile = slot + 64 * j;
        if (tile >= 125) break;
        int tileG = g * 125 + tile;
        int eg0 = g * EPG + tile * 32;
        #pragma unroll
        for (int m = 0; m < 2; ++m) {
            float v[4] = {0.f, 0.f, 0.f, 0.f};
            #pragma unroll
            for (int n = 0; n < 4; ++n) {
                size_t base = ((size_t)(tileG * 2 + m) * 4 + n) * 2;
                unsigned w0 = h1ff[(base + 0) * 64 + lane];
                unsigned w1 = h1ff[(base + 1) * 64 + lane];
                v[0] += un[n] * bf2f(w0 & 0xFFFFu);
                v[1] += un[n] * bf2f(w0 >> 16);
                v[2] += un[n] * bf2f(w1 & 0xFFFFu);
                v[3] += un[n] * bf2f(w1 >> 16);
            }
            float rp[4];
            #pragma unroll
            for (int t = 0; t < 4; ++t) {
                float vv = v[t];
                vv += __shfl_xor(vv, 1); vv += __shfl_xor(vv, 2);
                vv += __shfl_xor(vv, 4); vv += __shfl_xor(vv, 8);
                rp[t] = vv + cgv;
            }
            if (col == 0) {
                #pragma unroll
                for (int pr = 0; pr < 2; ++pr) {
                    float va = rp[2 * pr], vb = rp[2 * pr + 1];
                    int p = ((eg0 + 16 * m + grp * 4) >> 1) + pr;
                    vals[p] = fminf(va, vb);
                    outp[600000 + p] = (vb < va) ? 1.f : 0.f;
                    int e = 2 * p;
                    outp[p]          = (float)edges[e];
                    outp[200000 + p] = (float)edges[N_EDGES + e];
                }
            }
        }
    }
}

// ---------------- fold gnorm1 into Wout ---------------------------------------
__global__ void k_fin1(const float* __restrict__ S1, const float* __restrict__ Q1s,
                       const float* __restrict__ gnw, const float* __restrict__ gnb,
                       const float* __restrict__ gnms,
                       const float* __restrict__ Wout, const float* __restrict__ bout,
                       float* __restrict__ ug, float* __restrict__ cg) {
    int g = blockIdx.x; int j = threadIdx.x;  // 64 threads
    float S = S1[g * 64 + j], Q = Q1s[g * 64 + j];
    float mean = S * (1.f / EPG);
    float t = mean * gnms[j];
    float var = (Q - 2.f * t * S) * (1.f / EPG) + t * t;
    float a = gnw[j] * rsqrtf(var + 1e-5f);
    float b = gnb[j] - a * t;
    ug[g * 64 + j] = a * Wout[j];
    float c = b * Wout[j];
    #pragma unroll
    for (int off = 32; off; off >>= 1) c += __shfl_xor(c, off);
    if (j == 0) cg[g] = c + bout[0];
}

// ---------------- per-graph softmax -------------------------------------------
__global__ __launch_bounds__(256) void k_softmax(const float* __restrict__ vals,
                                                 float* __restrict__ outp) {
    int g = blockIdx.x;
    __shared__ float rbuf[4], rbuf2[4];
    int t = threadIdx.x;
    const float* v = vals + g * PPG;
    float mx = -1e30f;
    for (int i = t; i < PPG; i += 256) mx = fmaxf(mx, v[i]);
    #pragma unroll
    for (int off = 32; off; off >>= 1) mx = fmaxf(mx, __shfl_xor(mx, off));
    if ((t & 63) == 0) rbuf[t >> 6] = mx;
    __syncthreads();
    mx = fmaxf(fmaxf(rbuf[0], rbuf[1]), fmaxf(rbuf[2], rbuf[3]));
    float sm = 0.f;
    for (int i = t; i < PPG; i += 256) sm += expf(v[i] - mx);
    #pragma unroll
    for (int off = 32; off; off >>= 1) sm += __shfl_xor(sm, off);
    if ((t & 63) == 0) rbuf2[t >> 6] = sm;
    __syncthreads();
    sm = rbuf2[0] + rbuf2[1] + rbuf2[2] + rbuf2[3];
    for (int i = t; i < PPG; i += 256)
        outp[400000 + g * PPG + i] = expf(v[i] - mx) / (sm + 1e-16f);
}

extern "C" void kernel_launch(void* const* d_in, const int* in_sizes, int n_in,
                              void* d_out, int out_size, void* d_ws, size_t ws_size,
                              hipStream_t stream) {
    const float* x     = (const float*)d_in[0];
    const int*   edges = (const int*)d_in[1];
    const float* ea    = (const float*)d_in[2];
    const float* Wrel0 = (const float*)d_in[6],  *brel0 = (const float*)d_in[7],  *Wroot0 = (const float*)d_in[8];
    const float* Wrel1 = (const float*)d_in[9],  *brel1 = (const float*)d_in[10], *Wroot1 = (const float*)d_in[11];
    const float* Wrel2 = (const float*)d_in[12], *brel2 = (const float*)d_in[13], *Wroot2 = (const float*)d_in[14];
    const float* Wd0 = (const float*)d_in[15],  *bd0 = (const float*)d_in[16];
    const float* gnw0 = (const float*)d_in[17], *gnb0 = (const float*)d_in[18], *gnms0 = (const float*)d_in[19];
    const float* Wd1 = (const float*)d_in[20],  *bd1 = (const float*)d_in[21];
    const float* gnw1 = (const float*)d_in[22], *gnb1 = (const float*)d_in[23], *gnms1 = (const float*)d_in[24];
    const float* Wout = (const float*)d_in[25], *bout = (const float*)d_in[26];
    float* o = (float*)d_out;
    float* w = (float*)d_ws;

    // region A [0, 8.25M): early node tensors -> x3 planes
    float* agg5 = w;
    float* x1   = w + 250000;
    float* x2   = w + 1850000;
    ushort_t* c2h = (ushort_t*)(w + 5050000);
    ushort_t* c2l = (ushort_t*)(w + 6650000);
    ushort_t* x3h = (ushort_t*)(w + 0);
    ushort_t* x3l = (ushort_t*)(w + 3200000);
    // region B [8.25M, 21.05M): cat planes -> P|Qb
    float* P    = w + 8250000;
    float* Qb   = w + 14650000;
    ushort_t* cath = (ushort_t*)(w + 8250000);
    ushort_t* catl = (ushort_t*)(w + 11450000);
    // tail [21.05M, ~22.4M)
    float* tail = w + 21050000;
    unsigned* Wcb  = (unsigned*)tail;
    unsigned* Wpqb = Wcb + 8192;
    unsigned* W2b  = Wpqb + 16384;
    int* cnt   = (int*)(W2b + 2048);
    int* fillc = cnt + 50000;
    int* offs  = fillc + 50000;
    int* esrc  = offs + 50000;
    float* ew  = (float*)(esrc + 200000);
    float* S0  = ew + 200000;
    float* Q0s = S0 + 12800;
    unsigned* W1b = (unsigned*)(Q0s + 12800);
    float* gam = (float*)(W1b + 409600);
    float* S1  = gam + 6400;
    float* Q1s = S1 + 6400;
    float* ug  = Q1s + 6400;
    float* cg  = ug + 6400;
    float* vals = cg + 100;
    // h1ff: DISJOINT region [25.6M, 38.4M) floats — requires ws >= 153.6MB.
    unsigned* h1ff = (unsigned*)(w + 25600000);
    const bool haveH1 = ws_size >= 155000000ULL;   // proven >=159.2MB in R6

    hipMemsetAsync(cnt, 0, 100000 * sizeof(int), stream);
    hipMemsetAsync(S0, 0, 25600 * sizeof(float), stream);
    hipMemsetAsync(S1, 0, 12800 * sizeof(float), stream);

    k_packWc<<<32, 256, 0, stream>>>(Wrel2, Wroot2, Wcb);
    k_packWpq<<<64, 256, 0, stream>>>(Wd0, Wpqb);
    k_packW2<<<8, 256, 0, stream>>>(Wrel1, Wroot1, W2b);

    k_csr_count<<<782, 256, 0, stream>>>(edges, cnt);
    k_csr_scan<<<N_G, 512, 0, stream>>>(cnt, offs);
    k_csr_fill<<<782, 256, 0, stream>>>(edges, ea, offs, fillc, esrc, ew);

    k_gath5<<<1563, 256, 0, stream>>>(cnt, offs, esrc, ew, x, agg5);
    k_dense1<<<6250, 256, 0, stream>>>(x, agg5, Wrel0, brel0, Wroot0, x1, c2h, c2l);
    k_gath32<<<6250, 256, 0, stream>>>(cnt, offs, esrc, ew, x1, c2h, c2l);
    k_g1b<<<782, 256, 0, stream>>>(c2h, c2l, W2b, brel1, x2, cath, catl);
    k_gath64<<<12500, 256, 0, stream>>>(cnt, offs, esrc, ew, x2, cath, catl);

    k_g1<<<(NCHUNK + 3) / 4, 256, 0, stream>>>(cath, catl, Wcb, brel2, x3h, x3l);
    k_g2<<<(NCHUNK + 1) / 2, 256, 0, stream>>>(x3h, x3l, Wpqb, bd0, P, Qb);

    k_h0s<<<N_G * 16, 256, 0, stream>>>(edges, ea, P, Qb, Wd0, S0, Q0s);
    k_fin0<<<N_G, 256, 0, stream>>>(S0, Q0s, gnw0, gnb0, gnms0, Wd1, bd1, W1b, gam);

    if (haveH1) {
        k_h1m<0, 1><<<N_G * 8, 256, 0, stream>>>(edges, ea, P, Qb, Wd0, W1b, gam,
                                                 ug, cg, S1, Q1s, vals, o, h1ff);
        k_fin1<<<N_G, 64, 0, stream>>>(S1, Q1s, gnw1, gnb1, gnms1, Wout, bout, ug, cg);
        k_vals<<<N_G * 16, 256, 0, stream>>>(edges, h1ff, ug, cg, vals, o);
    } else {
        k_h1m<0, 0><<<N_G * 8, 256, 0, stream>>>(edges, ea, P, Qb, Wd0, W1b, gam,
                                                 ug, cg, S1, Q1s, vals, o, h1ff);
        k_fin1<<<N_G, 64, 0, stream>>>(S1, Q1s, gnw1, gnb1, gnms1, Wout, bout, ug, cg);
        k_h1m<1, 0><<<N_G * 8, 256, 0, stream>>>(edges, ea, P, Qb, Wd0, W1b, gam,
                                                 ug, cg, S1, Q1s, vals, o, h1ff);
    }

    k_softmax<<<N_G, 256, 0, stream>>>(vals, o);
}

// Round 9
// 394.821 us; speedup vs baseline: 1.2451x; 1.1929x over previous
//
#include <hip/hip_runtime.h>

// GraphNN R9: R8 pipeline with ATOMIC-FREE stats reduction:
//  k_h0s / k_h1m stats now do LDS cross-wave reduce + per-block partial store;
//  k_fin0 / k_fin1 sum the 8 partials per graph. No S0/S1 memsets.

#define N_NODES 50000
#define N_EDGES 400000
#define N_PAIRS 200000
#define N_G     100
#define EPG     4000
#define PPG     2000
#define NCHUNK  3125   // 50000/16

typedef float  f4   __attribute__((ext_vector_type(4)));
typedef short  bf8  __attribute__((ext_vector_type(8)));
typedef unsigned u32x4 __attribute__((ext_vector_type(4)));
typedef unsigned short ushort_t;

__device__ __forceinline__ float tanh_fast(float x) {
    float cx = fminf(15.f, fmaxf(-15.f, x));
    float e = __expf(2.f * cx);
    return (e - 1.f) * __builtin_amdgcn_rcpf(e + 1.f);
}
__device__ __forceinline__ unsigned f2bf(float f) {   // RNE fp32->bf16
    unsigned u = __float_as_uint(f);
    return (u + 0x7FFFu + ((u >> 16) & 1u)) >> 16;
}
__device__ __forceinline__ float bf2f(unsigned h) { return __uint_as_float(h << 16); }

// ---------------- CSR build ---------------------------------------------------
__global__ void k_csr_count(const int* __restrict__ edges, int* __restrict__ cnt) {
    int p = blockIdx.x * 256 + threadIdx.x;
    if (p >= N_PAIRS) return;
    atomicAdd(&cnt[edges[N_EDGES + 2 * p]], 1);
}
__global__ __launch_bounds__(512) void k_csr_scan(const int* __restrict__ cnt,
                                                  int* __restrict__ offs) {
    __shared__ int s[512];
    int g = blockIdx.x, t = threadIdx.x;
    int v = (t < 500) ? cnt[g * 500 + t] : 0;
    s[t] = v; __syncthreads();
    for (int off = 1; off < 512; off <<= 1) {
        int a = (t >= off) ? s[t - off] : 0;
        __syncthreads();
        s[t] += a; __syncthreads();
    }
    if (t < 500) offs[g * 500 + t] = g * PPG + s[t] - v;
}
__global__ void k_csr_fill(const int* __restrict__ edges, const float* __restrict__ ea,
                           const int* __restrict__ offs, int* __restrict__ fillc,
                           int* __restrict__ esrc, float* __restrict__ ew) {
    int p = blockIdx.x * 256 + threadIdx.x;
    if (p >= N_PAIRS) return;
    int d = edges[N_EDGES + 2 * p];
    int pos = offs[d] + atomicAdd(&fillc[d], 1);
    esrc[pos] = edges[2 * p];
    ew[pos] = ea[4 * p] + ea[4 * p + 2];
}

// ---------------- gathers -----------------------------------------------------
__global__ __launch_bounds__(256) void k_gath5(
    const int* __restrict__ cnt, const int* __restrict__ offs,
    const int* __restrict__ esrc, const float* __restrict__ ew,
    const float* __restrict__ x, float* __restrict__ agg) {
    int t = blockIdx.x * 256 + threadIdx.x;
    int n = t >> 3, k = t & 7;
    if (n >= N_NODES || k >= 5) return;
    int o0 = offs[n], c = cnt[n];
    float acc = 0.f;
    for (int i = o0; i < o0 + c; ++i) acc += x[esrc[i] * 5 + k] * ew[i];
    agg[n * 5 + k] = acc;
}
__global__ __launch_bounds__(256) void k_gath32(
    const int* __restrict__ cnt, const int* __restrict__ offs,
    const int* __restrict__ esrc, const float* __restrict__ ew,
    const float* __restrict__ x1, ushort_t* __restrict__ c2h, ushort_t* __restrict__ c2l) {
    int n = blockIdx.x * 8 + (threadIdx.x >> 5), k = threadIdx.x & 31;
    if (n >= N_NODES) return;
    int o0 = offs[n], c = cnt[n];
    float acc = 0.f;
    for (int i = o0; i < o0 + c; ++i) acc += x1[esrc[i] * 32 + k] * ew[i];
    unsigned hi = f2bf(acc);
    size_t o = (size_t)n * 64 + k;
    c2h[o] = (ushort_t)hi;
    c2l[o] = (ushort_t)f2bf(acc - bf2f(hi));
}
__global__ __launch_bounds__(256) void k_gath64(
    const int* __restrict__ cnt, const int* __restrict__ offs,
    const int* __restrict__ esrc, const float* __restrict__ ew,
    const float* __restrict__ x2, ushort_t* __restrict__ ch, ushort_t* __restrict__ cl) {
    int n = blockIdx.x * 4 + (threadIdx.x >> 6), k = threadIdx.x & 63;
    if (n >= N_NODES) return;
    int o0 = offs[n], c = cnt[n];
    float acc = 0.f;
    for (int i = o0; i < o0 + c; ++i) acc += x2[esrc[i] * 64 + k] * ew[i];
    unsigned hi = f2bf(acc);
    size_t o = (size_t)n * 128 + k;
    ch[o] = (ushort_t)hi;
    cl[o] = (ushort_t)f2bf(acc - bf2f(hi));
}

// ---------------- layer1 dense 5->32 ------------------------------------------
__global__ __launch_bounds__(256) void k_dense1(
    const float* __restrict__ x, const float* __restrict__ agg,
    const float* __restrict__ Wrel, const float* __restrict__ brel,
    const float* __restrict__ Wroot, float* __restrict__ x1,
    ushort_t* __restrict__ c2h, ushort_t* __restrict__ c2l) {
    __shared__ float wr[160], wt[160], bb[32];
    __shared__ float sa[8][5], sx[8][5];
    for (int i = threadIdx.x; i < 160; i += 256) { wr[i] = Wrel[i]; wt[i] = Wroot[i]; }
    if (threadIdx.x < 32) bb[threadIdx.x] = brel[threadIdx.x];
    int j = threadIdx.x & 31, nl = threadIdx.x >> 5;
    int nb = blockIdx.x * 8;
    __syncthreads();
    for (int i = threadIdx.x; i < 40; i += 256) {
        int nn = nb + i / 5, kk = i % 5;
        float av = 0.f, xv = 0.f;
        if (nn < N_NODES) { av = agg[nn * 5 + kk]; xv = x[nn * 5 + kk]; }
        sa[i / 5][kk] = av; sx[i / 5][kk] = xv;
    }
    __syncthreads();
    int n = nb + nl;
    if (n < N_NODES) {
        float acc = bb[j];
        #pragma unroll
        for (int k = 0; k < 5; ++k)
            acc += sa[nl][k] * wr[k * 32 + j] + sx[nl][k] * wt[k * 32 + j];
        float v = tanhf(acc);
        x1[n * 32 + j] = v;
        unsigned hi = f2bf(v);
        size_t o = (size_t)n * 64 + 32 + j;
        c2h[o] = (ushort_t)hi;
        c2l[o] = (ushort_t)f2bf(v - bf2f(hi));
    }
}

// ---------------- weight frag packers -----------------------------------------
__global__ void k_packWc(const float* __restrict__ Wrel2, const float* __restrict__ Wroot2,
                         unsigned* __restrict__ dst) {
    int i = blockIdx.x * 256 + threadIdx.x;   // 8192
    int t = i & 3, l = (i >> 2) & 63, kk = (i >> 8) & 3, n = i >> 10;
    int k = kk * 32 + ((l >> 4) << 3) + 2 * t;
    int j = 16 * n + (l & 15);
    float v0 = (k < 64) ? Wrel2[k * 128 + j] : Wroot2[(k - 64) * 128 + j];
    float v1 = (k + 1 < 64) ? Wrel2[(k + 1) * 128 + j] : Wroot2[(k + 1 - 64) * 128 + j];
    dst[i] = f2bf(v0) | (f2bf(v1) << 16);
}
__global__ void k_packWpq(const float* __restrict__ Wd0, unsigned* __restrict__ dst) {
    int i = blockIdx.x * 256 + threadIdx.x;   // 16384
    int t = i & 3, l = (i >> 2) & 63, kk = (i >> 8) & 3, n = i >> 10;
    int k = kk * 32 + ((l >> 4) << 3) + 2 * t;
    int j = 16 * n + (l & 15);
    float v0 = (j < 128) ? Wd0[k * 128 + j] : Wd0[(129 + k) * 128 + (j - 128)];
    float v1 = (j < 128) ? Wd0[(k + 1) * 128 + j] : Wd0[(129 + k + 1) * 128 + (j - 128)];
    dst[i] = f2bf(v0) | (f2bf(v1) << 16);
}
__global__ void k_packW2(const float* __restrict__ Wrel1, const float* __restrict__ Wroot1,
                         unsigned* __restrict__ dst) {
    int i = blockIdx.x * 256 + threadIdx.x;   // 2048
    int t = i & 3, l = (i >> 2) & 63, kk = (i >> 8) & 1, n = i >> 9;
    int k = kk * 32 + ((l >> 4) << 3) + 2 * t;
    int j = 16 * n + (l & 15);
    float v0 = (k < 32) ? Wrel1[k * 64 + j] : Wroot1[(k - 32) * 64 + j];
    float v1 = (k + 1 < 32) ? Wrel1[(k + 1) * 64 + j] : Wroot1[(k + 1 - 32) * 64 + j];
    dst[i] = f2bf(v0) | (f2bf(v1) << 16);
}

// ---------------- G1b: x2 = tanh(cat2 @ W2 + brel1) ---------------------------
__global__ __launch_bounds__(256) void k_g1b(
    const ushort_t* __restrict__ Ah, const ushort_t* __restrict__ Al,
    const unsigned* __restrict__ Wb_, const float* __restrict__ bias,
    float* __restrict__ x2, ushort_t* __restrict__ ch, ushort_t* __restrict__ cl) {
    int wave = threadIdx.x >> 6, lane = threadIdx.x & 63;
    int rl = lane & 15, gp = lane >> 4;
    int cid = blockIdx.x * 4 + wave;
    if (cid >= NCHUNK) return;
    u32x4 B[4][2];
    const u32x4* Wb = (const u32x4*)Wb_;
    #pragma unroll
    for (int n = 0; n < 4; ++n)
        #pragma unroll
        for (int kk = 0; kk < 2; ++kk)
            B[n][kk] = Wb[(n * 2 + kk) * 64 + lane];
    float bs[4];
    #pragma unroll
    for (int n = 0; n < 4; ++n) bs[n] = bias[n * 16 + rl];
    const u32x4* ph = (const u32x4*)(Ah + (size_t)(cid * 16 + rl) * 64 + gp * 8);
    const u32x4* pl = (const u32x4*)(Al + (size_t)(cid * 16 + rl) * 64 + gp * 8);
    bf8 ah[2], al4[2];
    #pragma unroll
    for (int kk = 0; kk < 2; ++kk) {
        ah[kk]  = __builtin_bit_cast(bf8, ph[kk * 4]);
        al4[kk] = __builtin_bit_cast(bf8, pl[kk * 4]);
    }
    f4 acc[4];
    #pragma unroll
    for (int n = 0; n < 4; ++n) acc[n] = (f4)0.f;
    #pragma unroll
    for (int kk = 0; kk < 2; ++kk) {
        #pragma unroll
        for (int n = 0; n < 4; ++n)
            acc[n] = __builtin_amdgcn_mfma_f32_16x16x32_bf16(
                ah[kk], __builtin_bit_cast(bf8, B[n][kk]), acc[n], 0, 0, 0);
        #pragma unroll
        for (int n = 0; n < 4; ++n)
            acc[n] = __builtin_amdgcn_mfma_f32_16x16x32_bf16(
                al4[kk], __builtin_bit_cast(bf8, B[n][kk]), acc[n], 0, 0, 0);
    }
    #pragma unroll
    for (int n = 0; n < 4; ++n)
        #pragma unroll
        for (int t = 0; t < 4; ++t) {
            float v = tanh_fast(acc[n][t] + bs[n]);
            int node = cid * 16 + gp * 4 + t;
            int col = n * 16 + rl;
            x2[(size_t)node * 64 + col] = v;
            unsigned hi = f2bf(v);
            size_t o = (size_t)node * 128 + 64 + col;
            ch[o] = (ushort_t)hi;
            cl[o] = (ushort_t)f2bf(v - bf2f(hi));
        }
}

// ---------------- G1: x3 = tanh(cat @ Wc + brel2) -----------------------------
__global__ __launch_bounds__(256) void k_g1(
    const ushort_t* __restrict__ Ah, const ushort_t* __restrict__ Al,
    const unsigned* __restrict__ Wb_, const float* __restrict__ bias,
    ushort_t* __restrict__ Oh, ushort_t* __restrict__ Ol) {
    int wave = threadIdx.x >> 6, lane = threadIdx.x & 63;
    int cg = wave & 1, mg = wave >> 1;
    int rl = lane & 15, gp = lane >> 4;
    u32x4 B[4][4];
    const u32x4* Wb = (const u32x4*)Wb_;
    #pragma unroll
    for (int n = 0; n < 4; ++n)
        #pragma unroll
        for (int kk = 0; kk < 4; ++kk)
            B[n][kk] = Wb[((cg * 4 + n) * 4 + kk) * 64 + lane];
    float bs[4];
    #pragma unroll
    for (int n = 0; n < 4; ++n) bs[n] = bias[cg * 64 + n * 16 + rl];
    for (int it = 0; it < 2; ++it) {
        int cid = (blockIdx.x * 2 + it) * 2 + mg;
        if (cid >= NCHUNK) continue;
        const u32x4* ph = (const u32x4*)(Ah + (size_t)(cid * 16 + rl) * 128 + gp * 8);
        const u32x4* pl = (const u32x4*)(Al + (size_t)(cid * 16 + rl) * 128 + gp * 8);
        bf8 ah[4], al4[4];
        #pragma unroll
        for (int kk = 0; kk < 4; ++kk) {
            ah[kk]  = __builtin_bit_cast(bf8, ph[kk * 4]);
            al4[kk] = __builtin_bit_cast(bf8, pl[kk * 4]);
        }
        f4 acc[4];
        #pragma unroll
        for (int n = 0; n < 4; ++n) acc[n] = (f4)0.f;
        #pragma unroll
        for (int kk = 0; kk < 4; ++kk) {
            #pragma unroll
            for (int n = 0; n < 4; ++n)
                acc[n] = __builtin_amdgcn_mfma_f32_16x16x32_bf16(
                    ah[kk], __builtin_bit_cast(bf8, B[n][kk]), acc[n], 0, 0, 0);
            #pragma unroll
            for (int n = 0; n < 4; ++n)
                acc[n] = __builtin_amdgcn_mfma_f32_16x16x32_bf16(
                    al4[kk], __builtin_bit_cast(bf8, B[n][kk]), acc[n], 0, 0, 0);
        }
        #pragma unroll
        for (int n = 0; n < 4; ++n)
            #pragma unroll
            for (int t = 0; t < 4; ++t) {
                float v = tanh_fast(acc[n][t] + bs[n]);
                unsigned hi = f2bf(v);
                int node = cid * 16 + gp * 4 + t;
                int col = cg * 64 + n * 16 + rl;
                Oh[(size_t)node * 128 + col] = (ushort_t)hi;
                Ol[(size_t)node * 128 + col] = (ushort_t)f2bf(v - bf2f(hi));
            }
    }
}

// ---------------- G2: [P|Q] = x3 @ Wpq (+bd0) ---------------------------------
__global__ __launch_bounds__(256) void k_g2(
    const ushort_t* __restrict__ Ah, const ushort_t* __restrict__ Al,
    const unsigned* __restrict__ Wb_, const float* __restrict__ bd0,
    float* __restrict__ P, float* __restrict__ Qb) {
    int cg = threadIdx.x >> 6, lane = threadIdx.x & 63;
    int rl = lane & 15, gp = lane >> 4;
    u32x4 B[4][4];
    const u32x4* Wb = (const u32x4*)Wb_;
    #pragma unroll
    for (int n = 0; n < 4; ++n)
        #pragma unroll
        for (int kk = 0; kk < 4; ++kk)
            B[n][kk] = Wb[((cg * 4 + n) * 4 + kk) * 64 + lane];
    float bs[4];
    #pragma unroll
    for (int n = 0; n < 4; ++n) {
        int j = cg * 64 + n * 16 + rl;
        bs[n] = (j < 128) ? bd0[j] : 0.f;
    }
    for (int it = 0; it < 2; ++it) {
        int cid = blockIdx.x * 2 + it;
        if (cid >= NCHUNK) continue;
        const u32x4* ph = (const u32x4*)(Ah + (size_t)(cid * 16 + rl) * 128 + gp * 8);
        const u32x4* pl = (const u32x4*)(Al + (size_t)(cid * 16 + rl) * 128 + gp * 8);
        bf8 ah[4], al4[4];
        #pragma unroll
        for (int kk = 0; kk < 4; ++kk) {
            ah[kk]  = __builtin_bit_cast(bf8, ph[kk * 4]);
            al4[kk] = __builtin_bit_cast(bf8, pl[kk * 4]);
        }
        f4 acc[4];
        #pragma unroll
        for (int n = 0; n < 4; ++n) acc[n] = (f4)0.f;
        #pragma unroll
        for (int kk = 0; kk < 4; ++kk) {
            #pragma unroll
            for (int n = 0; n < 4; ++n)
                acc[n] = __builtin_amdgcn_mfma_f32_16x16x32_bf16(
                    ah[kk], __builtin_bit_cast(bf8, B[n][kk]), acc[n], 0, 0, 0);
            #pragma unroll
            for (int n = 0; n < 4; ++n)
                acc[n] = __builtin_amdgcn_mfma_f32_16x16x32_bf16(
                    al4[kk], __builtin_bit_cast(bf8, B[n][kk]), acc[n], 0, 0, 0);
        }
        #pragma unroll
        for (int n = 0; n < 4; ++n) {
            int j = cg * 64 + n * 16 + rl;
            #pragma unroll
            for (int t = 0; t < 4; ++t) {
                float v = acc[n][t] + bs[n];
                int node = cid * 16 + gp * 4 + t;
                if (j < 128) P[(size_t)node * 128 + j] = v;
                else         Qb[(size_t)node * 128 + (j - 128)] = v;
            }
        }
    }
}

// ---------------- h0 stats: N_G*8, j<4, LDS block-reduce, partial store -------
__global__ __launch_bounds__(256, 1) void k_h0s(
    const int* __restrict__ edges, const float* __restrict__ ea,
    const float* __restrict__ P, const float* __restrict__ Qb,
    const float* __restrict__ Wd0, float* __restrict__ part0) {
    __shared__ float ls[2][4][128];
    int g = blockIdx.x >> 3, tb = blockIdx.x & 7;
    int wave = threadIdx.x >> 6, lane = threadIdx.x & 63;
    int row = lane & 15, grp = lane >> 4;
    int slot = tb * 4 + wave;
    f4 wmr[4][2];
    #pragma unroll
    for (int kk = 0; kk < 4; ++kk) {
        const f4* wmp = (const f4*)(Wd0 + 16384 + kk * 32 + grp * 8);
        wmr[kk][0] = wmp[0]; wmr[kk][1] = wmp[1];
    }
    f4 s[4][2], q[4][2];
    #pragma unroll
    for (int kk = 0; kk < 4; ++kk)
        #pragma unroll
        for (int h = 0; h < 2; ++h) { s[kk][h] = (f4)0.f; q[kk][h] = (f4)0.f; }

    for (int j = 0; j < 4; ++j) {
        int tile = slot + 32 * j;
        if (tile >= 125) break;
        int eg0 = g * EPG + tile * 32;
        #pragma unroll
        for (int m = 0; m < 2; ++m) {
            int e = eg0 + 16 * m + row;
            int sn = edges[e], dn = edges[N_EDGES + e];
            float w = ea[2 * e];
            const f4* Pr = (const f4*)(P + sn * 128);
            const f4* Qr = (const f4*)(Qb + dn * 128);
            #pragma unroll
            for (int kk = 0; kk < 4; ++kk) {
                int o = kk * 8 + grp * 2;
                f4 p0 = Pr[o], p1 = Pr[o + 1];
                f4 q0 = Qr[o], q1 = Qr[o + 1];
                #pragma unroll
                for (int r = 0; r < 4; ++r) {
                    float h0 = tanh_fast(p0[r] + q0[r] + w * wmr[kk][0][r]);
                    float h1 = tanh_fast(p1[r] + q1[r] + w * wmr[kk][1][r]);
                    s[kk][0][r] += h0; q[kk][0][r] += h0 * h0;
                    s[kk][1][r] += h1; q[kk][1][r] += h1 * h1;
                }
            }
        }
    }
    #pragma unroll
    for (int kk = 0; kk < 4; ++kk)
        #pragma unroll
        for (int h = 0; h < 2; ++h)
            #pragma unroll
            for (int r = 0; r < 4; ++r) {
                float sv = s[kk][h][r], qv = q[kk][h][r];
                sv += __shfl_xor(sv, 1); sv += __shfl_xor(sv, 2);
                sv += __shfl_xor(sv, 4); sv += __shfl_xor(sv, 8);
                qv += __shfl_xor(qv, 1); qv += __shfl_xor(qv, 2);
                qv += __shfl_xor(qv, 4); qv += __shfl_xor(qv, 8);
                if (row == 0) {
                    int k = kk * 32 + grp * 8 + h * 4 + r;
                    ls[0][wave][k] = sv;
                    ls[1][wave][k] = qv;
                }
            }
    __syncthreads();
    // block reduce: 256 threads cover 2 stats x 128 k
    int st = threadIdx.x >> 7, k = threadIdx.x & 127;
    float v = ls[st][0][k] + ls[st][1][k] + ls[st][2][k] + ls[st][3][k];
    part0[((size_t)(g * 8 + tb) * 2 + st) * 128 + k] = v;
}

// ---------------- fold gnorm0 (sums 8 partials) -> W1b + gam ------------------
__global__ __launch_bounds__(256) void k_fin0(
    const float* __restrict__ part0,
    const float* __restrict__ gnw, const float* __restrict__ gnb, const float* __restrict__ gnms,
    const float* __restrict__ Wd1, const float* __restrict__ bd1,
    unsigned* __restrict__ W1b, float* __restrict__ gam) {
    int g = blockIdx.x;
    __shared__ float al[128], be[128];
    if (threadIdx.x < 128) {
        int k = threadIdx.x;
        float S = 0.f, Q = 0.f;
        #pragma unroll
        for (int tb = 0; tb < 8; ++tb) {
            S += part0[((size_t)(g * 8 + tb) * 2 + 0) * 128 + k];
            Q += part0[((size_t)(g * 8 + tb) * 2 + 1) * 128 + k];
        }
        float mean = S * (1.f / EPG);
        float t = mean * gnms[k];
        float var = (Q - 2.f * t * S) * (1.f / EPG) + t * t;
        float a = gnw[k] * rsqrtf(var + 1e-5f);
        al[k] = a;
        be[k] = gnb[k] - a * t;
    }
    __syncthreads();
    unsigned* Wb = W1b + (size_t)g * 4096;
    for (int i = threadIdx.x; i < 4096; i += 256) {
        int t = i & 3, l = (i >> 2) & 63, kk = (i >> 8) & 3, n = i >> 10;
        int k = kk * 32 + ((l >> 4) << 3) + 2 * t;
        int j = 16 * n + (l & 15);
        unsigned lo = f2bf(al[k] * Wd1[k * 64 + j]);
        unsigned hi = f2bf(al[k + 1] * Wd1[(k + 1) * 64 + j]);
        Wb[i] = lo | (hi << 16);
    }
    if (threadIdx.x < 64) {
        int j = threadIdx.x;
        float acc = bd1[j];
        #pragma unroll 8
        for (int k = 0; k < 128; ++k) acc += be[k] * Wd1[k * 64 + j];
        gam[g * 64 + j] = acc;
    }
}

// ---------------- h1 pass: stats(+h1 store, partials) or vals -----------------
template<int DO_VALS, int STORE>
__global__ __launch_bounds__(256, 1) void k_h1m(
    const int* __restrict__ edges, const float* __restrict__ ea,
    const float* __restrict__ P, const float* __restrict__ Qb,
    const float* __restrict__ Wd0,
    const unsigned* __restrict__ W1b, const float* __restrict__ gam,
    const float* __restrict__ ug, const float* __restrict__ cg,
    float* __restrict__ part1,
    float* __restrict__ vals, float* __restrict__ outp, unsigned* __restrict__ h1ff) {
    __shared__ float ls[2][4][64];
    int g = blockIdx.x >> 3, tb = blockIdx.x & 7;
    int wave = threadIdx.x >> 6, lane = threadIdx.x & 63;
    int col = lane & 15, grp = lane >> 4;
    int slot = tb * 4 + wave;

    bf8 bfr[4][4];
    {
        const u32x4* Wb = (const u32x4*)(W1b + (size_t)g * 4096);
        #pragma unroll
        for (int n = 0; n < 4; ++n)
            #pragma unroll
            for (int kk = 0; kk < 4; ++kk)
                bfr[n][kk] = __builtin_bit_cast(bf8, Wb[(n * 4 + kk) * 64 + lane]);
    }
    f4 wmr[4][2];
    #pragma unroll
    for (int kk = 0; kk < 4; ++kk) {
        const f4* wmp = (const f4*)(Wd0 + 16384 + kk * 32 + grp * 8);
        wmr[kk][0] = wmp[0]; wmr[kk][1] = wmp[1];
    }
    float gamn[4], un[4] = {0.f, 0.f, 0.f, 0.f};
    #pragma unroll
    for (int n = 0; n < 4; ++n) gamn[n] = gam[g * 64 + 16 * n + col];
    float cgv = 0.f;
    if (DO_VALS) {
        #pragma unroll
        for (int n = 0; n < 4; ++n) un[n] = ug[g * 64 + 16 * n + col];
        cgv = cg[g];
    }
    float sacc[4] = {0.f, 0.f, 0.f, 0.f}, qacc[4] = {0.f, 0.f, 0.f, 0.f};

    for (int j = 0; j < 4; ++j) {
        int tile = slot + 32 * j;
        if (tile >= 125) break;
        int eg0 = g * EPG + tile * 32;
        bf8 af[2][4];
        #pragma unroll
        for (int m = 0; m < 2; ++m) {
            int e = eg0 + 16 * m + col;
            int sn = edges[e], dn = edges[N_EDGES + e];
            float w = ea[2 * e];
            const f4* Pr = (const f4*)(P + sn * 128);
            const f4* Qr = (const f4*)(Qb + dn * 128);
            #pragma unroll
            for (int kk = 0; kk < 4; ++kk) {
                int o = kk * 8 + grp * 2;
                f4 p0 = Pr[o], p1 = Pr[o + 1];
                f4 q0 = Qr[o], q1 = Qr[o + 1];
                bf8 a;
                #pragma unroll
                for (int r = 0; r < 4; ++r) {
                    float h0 = tanh_fast(p0[r] + q0[r] + w * wmr[kk][0][r]);
                    float h1 = tanh_fast(p1[r] + q1[r] + w * wmr[kk][1][r]);
                    a[r]     = (short)f2bf(h0);
                    a[4 + r] = (short)f2bf(h1);
                }
                af[m][kk] = a;
            }
        }
        f4 acc[2][4];
        #pragma unroll
        for (int m = 0; m < 2; ++m)
            #pragma unroll
            for (int n = 0; n < 4; ++n) acc[m][n] = (f4)0.f;
        #pragma unroll
        for (int kk = 0; kk < 4; ++kk)
            #pragma unroll
            for (int m = 0; m < 2; ++m)
                #pragma unroll
                for (int n = 0; n < 4; ++n)
                    acc[m][n] = __builtin_amdgcn_mfma_f32_16x16x32_bf16(
                        af[m][kk], bfr[n][kk], acc[m][n], 0, 0, 0);

        if (DO_VALS) {
            float rp[2][4];
            #pragma unroll
            for (int m = 0; m < 2; ++m)
                #pragma unroll
                for (int t = 0; t < 4; ++t) {
                    float v = 0.f;
                    #pragma unroll
                    for (int n = 0; n < 4; ++n)
                        v += un[n] * tanh_fast(acc[m][n][t] + gamn[n]);
                    v += __shfl_xor(v, 1); v += __shfl_xor(v, 2);
                    v += __shfl_xor(v, 4); v += __shfl_xor(v, 8);
                    rp[m][t] = v + cgv;
                }
            if (col == 0) {
                #pragma unroll
                for (int m = 0; m < 2; ++m)
                    #pragma unroll
                    for (int pr = 0; pr < 2; ++pr) {
                        float va = rp[m][2 * pr], vb = rp[m][2 * pr + 1];
                        int p = ((eg0 + 16 * m + grp * 4) >> 1) + pr;
                        vals[p] = fminf(va, vb);
                        outp[600000 + p] = (vb < va) ? 1.f : 0.f;
                        int e = 2 * p;
                        outp[p]          = (float)edges[e];
                        outp[200000 + p] = (float)edges[N_EDGES + e];
                    }
            }
        } else {
            int tileG = g * 125 + tile;
            #pragma unroll
            for (int m = 0; m < 2; ++m)
                #pragma unroll
                for (int n = 0; n < 4; ++n) {
                    float h[4];
                    #pragma unroll
                    for (int t = 0; t < 4; ++t) {
                        h[t] = tanh_fast(acc[m][n][t] + gamn[n]);
                        sacc[n] += h[t]; qacc[n] += h[t] * h[t];
                    }
                    if (STORE) {
                        unsigned w0 = f2bf(h[0]) | (f2bf(h[1]) << 16);
                        unsigned w1 = f2bf(h[2]) | (f2bf(h[3]) << 16);
                        size_t base = ((size_t)(tileG * 2 + m) * 4 + n) * 2;
                        h1ff[(base + 0) * 64 + lane] = w0;
                        h1ff[(base + 1) * 64 + lane] = w1;
                    }
                }
        }
    }
    if (!DO_VALS) {
        #pragma unroll
        for (int n = 0; n < 4; ++n) {
            float s = sacc[n], q = qacc[n];
            s += __shfl_xor(s, 16); s += __shfl_xor(s, 32);
            q += __shfl_xor(q, 16); q += __shfl_xor(q, 32);
            if (lane < 16) {
                ls[0][wave][n * 16 + col] = s;
                ls[1][wave][n * 16 + col] = q;
            }
        }
        __syncthreads();
        if (threadIdx.x < 128) {
            int st = threadIdx.x >> 6, k = threadIdx.x & 63;
            float v = ls[st][0][k] + ls[st][1][k] + ls[st][2][k] + ls[st][3][k];
            part1[((size_t)(g * 8 + tb) * 2 + st) * 64 + k] = v;
        }
    }
}

// ---------------- vals pass: read h1ff, dot, pair-min -------------------------
__global__ __launch_bounds__(256) void k_vals(
    const int* __restrict__ edges, const unsigned* __restrict__ h1ff,
    const float* __restrict__ ug, const float* __restrict__ cg,
    float* __restrict__ vals, float* __restrict__ outp) {
    int g = blockIdx.x >> 4, tb = blockIdx.x & 15;
    int wave = threadIdx.x >> 6, lane = threadIdx.x & 63;
    int col = lane & 15, grp = lane >> 4;
    int slot = tb * 4 + wave;
    float un[4];
    #pragma unroll
    for (int n = 0; n < 4; ++n) un[n] = ug[g * 64 + 16 * n + col];
    float cgv = cg[g];
    for (int j = 0; j < 2; ++j) {
        int tile = slot + 64 * j;
        if (tile >= 125) break;
        int tileG = g * 125 + tile;
        int eg0 = g * EPG + tile * 32;
        #pragma unroll
        for (int m = 0; m < 2; ++m) {
            float v[4] = {0.f, 0.f, 0.f, 0.f};
            #pragma unroll
            for (int n = 0; n < 4; ++n) {
                size_t base = ((size_t)(tileG * 2 + m) * 4 + n) * 2;
                unsigned w0 = h1ff[(base + 0) * 64 + lane];
                unsigned w1 = h1ff[(base + 1) * 64 + lane];
                v[0] += un[n] * bf2f(w0 & 0xFFFFu);
                v[1] += un[n] * bf2f(w0 >> 16);
                v[2] += un[n] * bf2f(w1 & 0xFFFFu);
                v[3] += un[n] * bf2f(w1 >> 16);
            }
            float rp[4];
            #pragma unroll
            for (int t = 0; t < 4; ++t) {
                float vv = v[t];
                vv += __shfl_xor(vv, 1); vv += __shfl_xor(vv, 2);
                vv += __shfl_xor(vv, 4); vv += __shfl_xor(vv, 8);
                rp[t] = vv + cgv;
            }
            if (col == 0) {
                #pragma unroll
                for (int pr = 0; pr < 2; ++pr) {
                    float va = rp[2 * pr], vb = rp[2 * pr + 1];
                    int p = ((eg0 + 16 * m + grp * 4) >> 1) + pr;
                    vals[p] = fminf(va, vb);
                    outp[600000 + p] = (vb < va) ? 1.f : 0.f;
                    int e = 2 * p;
                    outp[p]          = (float)edges[e];
                    outp[200000 + p] = (float)edges[N_EDGES + e];
                }
            }
        }
    }
}

// ---------------- fold gnorm1 (sums 8 partials) into Wout ---------------------
__global__ void k_fin1(const float* __restrict__ part1,
                       const float* __restrict__ gnw, const float* __restrict__ gnb,
                       const float* __restrict__ gnms,
                       const float* __restrict__ Wout, const float* __restrict__ bout,
                       float* __restrict__ ug, float* __restrict__ cg) {
    int g = blockIdx.x; int j = threadIdx.x;  // 64 threads
    float S = 0.f, Q = 0.f;
    #pragma unroll
    for (int tb = 0; tb < 8; ++tb) {
        S += part1[((size_t)(g * 8 + tb) * 2 + 0) * 64 + j];
        Q += part1[((size_t)(g * 8 + tb) * 2 + 1) * 64 + j];
    }
    float mean = S * (1.f / EPG);
    float t = mean * gnms[j];
    float var = (Q - 2.f * t * S) * (1.f / EPG) + t * t;
    float a = gnw[j] * rsqrtf(var + 1e-5f);
    float b = gnb[j] - a * t;
    ug[g * 64 + j] = a * Wout[j];
    float c = b * Wout[j];
    #pragma unroll
    for (int off = 32; off; off >>= 1) c += __shfl_xor(c, off);
    if (j == 0) cg[g] = c + bout[0];
}

// ---------------- per-graph softmax -------------------------------------------
__global__ __launch_bounds__(256) void k_softmax(const float* __restrict__ vals,
                                                 float* __restrict__ outp) {
    int g = blockIdx.x;
    __shared__ float rbuf[4], rbuf2[4];
    int t = threadIdx.x;
    const float* v = vals + g * PPG;
    float mx = -1e30f;
    for (int i = t; i < PPG; i += 256) mx = fmaxf(mx, v[i]);
    #pragma unroll
    for (int off = 32; off; off >>= 1) mx = fmaxf(mx, __shfl_xor(mx, off));
    if ((t & 63) == 0) rbuf[t >> 6] = mx;
    __syncthreads();
    mx = fmaxf(fmaxf(rbuf[0], rbuf[1]), fmaxf(rbuf[2], rbuf[3]));
    float sm = 0.f;
    for (int i = t; i < PPG; i += 256) sm += expf(v[i] - mx);
    #pragma unroll
    for (int off = 32; off; off >>= 1) sm += __shfl_xor(sm, off);
    if ((t & 63) == 0) rbuf2[t >> 6] = sm;
    __syncthreads();
    sm = rbuf2[0] + rbuf2[1] + rbuf2[2] + rbuf2[3];
    for (int i = t; i < PPG; i += 256)
        outp[400000 + g * PPG + i] = expf(v[i] - mx) / (sm + 1e-16f);
}

extern "C" void kernel_launch(void* const* d_in, const int* in_sizes, int n_in,
                              void* d_out, int out_size, void* d_ws, size_t ws_size,
                              hipStream_t stream) {
    const float* x     = (const float*)d_in[0];
    const int*   edges = (const int*)d_in[1];
    const float* ea    = (const float*)d_in[2];
    const float* Wrel0 = (const float*)d_in[6],  *brel0 = (const float*)d_in[7],  *Wroot0 = (const float*)d_in[8];
    const float* Wrel1 = (const float*)d_in[9],  *brel1 = (const float*)d_in[10], *Wroot1 = (const float*)d_in[11];
    const float* Wrel2 = (const float*)d_in[12], *brel2 = (const float*)d_in[13], *Wroot2 = (const float*)d_in[14];
    const float* Wd0 = (const float*)d_in[15],  *bd0 = (const float*)d_in[16];
    const float* gnw0 = (const float*)d_in[17], *gnb0 = (const float*)d_in[18], *gnms0 = (const float*)d_in[19];
    const float* Wd1 = (const float*)d_in[20],  *bd1 = (const float*)d_in[21];
    const float* gnw1 = (const float*)d_in[22], *gnb1 = (const float*)d_in[23], *gnms1 = (const float*)d_in[24];
    const float* Wout = (const float*)d_in[25], *bout = (const float*)d_in[26];
    float* o = (float*)d_out;
    float* w = (float*)d_ws;

    // region A [0, 8.25M): early node tensors -> x3 planes
    float* agg5 = w;
    float* x1   = w + 250000;
    float* x2   = w + 1850000;
    ushort_t* c2h = (ushort_t*)(w + 5050000);
    ushort_t* c2l = (ushort_t*)(w + 6650000);
    ushort_t* x3h = (ushort_t*)(w + 0);
    ushort_t* x3l = (ushort_t*)(w + 3200000);
    // region B [8.25M, 21.05M): cat planes -> P|Qb
    float* P    = w + 8250000;
    float* Qb   = w + 14650000;
    ushort_t* cath = (ushort_t*)(w + 8250000);
    ushort_t* catl = (ushort_t*)(w + 11450000);
    // tail [21.05M, ~22.6M)
    float* tail = w + 21050000;
    unsigned* Wcb  = (unsigned*)tail;
    unsigned* Wpqb = Wcb + 8192;
    unsigned* W2b  = Wpqb + 16384;
    int* cnt   = (int*)(W2b + 2048);
    int* fillc = cnt + 50000;
    int* offs  = fillc + 50000;
    int* esrc  = offs + 50000;
    float* ew  = (float*)(esrc + 200000);
    unsigned* W1b = (unsigned*)(ew + 200000);      // 409600
    float* gam = (float*)(W1b + 409600);           // 6400
    float* ug  = gam + 6400;                       // 6400
    float* cg  = ug + 6400;                        // 100
    float* vals = cg + 100;                        // 200000
    float* part0 = vals + 200000;                  // 204800
    float* part1 = part0 + 204800;                 // 102400
    // h1ff: DISJOINT region [25.6M, 38.4M) floats — requires ws >= 153.6MB.
    unsigned* h1ff = (unsigned*)(w + 25600000);
    const bool haveH1 = ws_size >= 155000000ULL;   // proven >=159.2MB in R6

    hipMemsetAsync(cnt, 0, 100000 * sizeof(int), stream);

    k_packWc<<<32, 256, 0, stream>>>(Wrel2, Wroot2, Wcb);
    k_packWpq<<<64, 256, 0, stream>>>(Wd0, Wpqb);
    k_packW2<<<8, 256, 0, stream>>>(Wrel1, Wroot1, W2b);

    k_csr_count<<<782, 256, 0, stream>>>(edges, cnt);
    k_csr_scan<<<N_G, 512, 0, stream>>>(cnt, offs);
    k_csr_fill<<<782, 256, 0, stream>>>(edges, ea, offs, fillc, esrc, ew);

    k_gath5<<<1563, 256, 0, stream>>>(cnt, offs, esrc, ew, x, agg5);
    k_dense1<<<6250, 256, 0, stream>>>(x, agg5, Wrel0, brel0, Wroot0, x1, c2h, c2l);
    k_gath32<<<6250, 256, 0, stream>>>(cnt, offs, esrc, ew, x1, c2h, c2l);
    k_g1b<<<782, 256, 0, stream>>>(c2h, c2l, W2b, brel1, x2, cath, catl);
    k_gath64<<<12500, 256, 0, stream>>>(cnt, offs, esrc, ew, x2, cath, catl);

    k_g1<<<(NCHUNK + 3) / 4, 256, 0, stream>>>(cath, catl, Wcb, brel2, x3h, x3l);
    k_g2<<<(NCHUNK + 1) / 2, 256, 0, stream>>>(x3h, x3l, Wpqb, bd0, P, Qb);

    k_h0s<<<N_G * 8, 256, 0, stream>>>(edges, ea, P, Qb, Wd0, part0);
    k_fin0<<<N_G, 256, 0, stream>>>(part0, gnw0, gnb0, gnms0, Wd1, bd1, W1b, gam);

    if (haveH1) {
        k_h1m<0, 1><<<N_G * 8, 256, 0, stream>>>(edges, ea, P, Qb, Wd0, W1b, gam,
                                                 ug, cg, part1, vals, o, h1ff);
        k_fin1<<<N_G, 64, 0, stream>>>(part1, gnw1, gnb1, gnms1, Wout, bout, ug, cg);
        k_vals<<<N_G * 16, 256, 0, stream>>>(edges, h1ff, ug, cg, vals, o);
    } else {
        k_h1m<0, 0><<<N_G * 8, 256, 0, stream>>>(edges, ea, P, Qb, Wd0, W1b, gam,
                                                 ug, cg, part1, vals, o, h1ff);
        k_fin1<<<N_G, 64, 0, stream>>>(part1, gnw1, gnb1, gnms1, Wout, bout, ug, cg);
        k_h1m<1, 0><<<N_G * 8, 256, 0, stream>>>(edges, ea, P, Qb, Wd0, W1b, gam,
                                                 ug, cg, part1, vals, o, h1ff);
    }

    k_softmax<<<N_G, 256, 0, stream>>>(vals, o);
}

// Round 10
// 376.211 us; speedup vs baseline: 1.3066x; 1.0495x over previous
//
#include <hip/hip_runtime.h>

// GraphNN R10: R9 + (a) P/Qb stored as bf16 (halves edge-pass gather bytes;
// self-consistent since stats+apply read same rounded values), (b) h-passes
// at grid N_G*16 / j<2 (R8-proven no-spill shape) for better CU balance.

#define N_NODES 50000
#define N_EDGES 400000
#define N_PAIRS 200000
#define N_G     100
#define EPG     4000
#define PPG     2000
#define NCHUNK  3125   // 50000/16

typedef float  f4   __attribute__((ext_vector_type(4)));
typedef short  bf8  __attribute__((ext_vector_type(8)));
typedef unsigned u32x4 __attribute__((ext_vector_type(4)));
typedef unsigned short ushort_t;

__device__ __forceinline__ float tanh_fast(float x) {
    float cx = fminf(15.f, fmaxf(-15.f, x));
    float e = __expf(2.f * cx);
    return (e - 1.f) * __builtin_amdgcn_rcpf(e + 1.f);
}
__device__ __forceinline__ unsigned f2bf(float f) {   // RNE fp32->bf16
    unsigned u = __float_as_uint(f);
    return (u + 0x7FFFu + ((u >> 16) & 1u)) >> 16;
}
__device__ __forceinline__ float bf2f(unsigned h) { return __uint_as_float(h << 16); }
__device__ __forceinline__ void unp8(u32x4 v, f4& a, f4& b) {  // 8 bf16 -> 2xf4
    a[0] = bf2f(v[0] & 0xFFFFu); a[1] = bf2f(v[0] >> 16);
    a[2] = bf2f(v[1] & 0xFFFFu); a[3] = bf2f(v[1] >> 16);
    b[0] = bf2f(v[2] & 0xFFFFu); b[1] = bf2f(v[2] >> 16);
    b[2] = bf2f(v[3] & 0xFFFFu); b[3] = bf2f(v[3] >> 16);
}

// ---------------- CSR build ---------------------------------------------------
__global__ void k_csr_count(const int* __restrict__ edges, int* __restrict__ cnt) {
    int p = blockIdx.x * 256 + threadIdx.x;
    if (p >= N_PAIRS) return;
    atomicAdd(&cnt[edges[N_EDGES + 2 * p]], 1);
}
__global__ __launch_bounds__(512) void k_csr_scan(const int* __restrict__ cnt,
                                                  int* __restrict__ offs) {
    __shared__ int s[512];
    int g = blockIdx.x, t = threadIdx.x;
    int v = (t < 500) ? cnt[g * 500 + t] : 0;
    s[t] = v; __syncthreads();
    for (int off = 1; off < 512; off <<= 1) {
        int a = (t >= off) ? s[t - off] : 0;
        __syncthreads();
        s[t] += a; __syncthreads();
    }
    if (t < 500) offs[g * 500 + t] = g * PPG + s[t] - v;
}
__global__ void k_csr_fill(const int* __restrict__ edges, const float* __restrict__ ea,
                           const int* __restrict__ offs, int* __restrict__ fillc,
                           int* __restrict__ esrc, float* __restrict__ ew) {
    int p = blockIdx.x * 256 + threadIdx.x;
    if (p >= N_PAIRS) return;
    int d = edges[N_EDGES + 2 * p];
    int pos = offs[d] + atomicAdd(&fillc[d], 1);
    esrc[pos] = edges[2 * p];
    ew[pos] = ea[4 * p] + ea[4 * p + 2];
}

// ---------------- gathers -----------------------------------------------------
__global__ __launch_bounds__(256) void k_gath5(
    const int* __restrict__ cnt, const int* __restrict__ offs,
    const int* __restrict__ esrc, const float* __restrict__ ew,
    const float* __restrict__ x, float* __restrict__ agg) {
    int t = blockIdx.x * 256 + threadIdx.x;
    int n = t >> 3, k = t & 7;
    if (n >= N_NODES || k >= 5) return;
    int o0 = offs[n], c = cnt[n];
    float acc = 0.f;
    for (int i = o0; i < o0 + c; ++i) acc += x[esrc[i] * 5 + k] * ew[i];
    agg[n * 5 + k] = acc;
}
__global__ __launch_bounds__(256) void k_gath32(
    const int* __restrict__ cnt, const int* __restrict__ offs,
    const int* __restrict__ esrc, const float* __restrict__ ew,
    const float* __restrict__ x1, ushort_t* __restrict__ c2h, ushort_t* __restrict__ c2l) {
    int n = blockIdx.x * 8 + (threadIdx.x >> 5), k = threadIdx.x & 31;
    if (n >= N_NODES) return;
    int o0 = offs[n], c = cnt[n];
    float acc = 0.f;
    for (int i = o0; i < o0 + c; ++i) acc += x1[esrc[i] * 32 + k] * ew[i];
    unsigned hi = f2bf(acc);
    size_t o = (size_t)n * 64 + k;
    c2h[o] = (ushort_t)hi;
    c2l[o] = (ushort_t)f2bf(acc - bf2f(hi));
}
__global__ __launch_bounds__(256) void k_gath64(
    const int* __restrict__ cnt, const int* __restrict__ offs,
    const int* __restrict__ esrc, const float* __restrict__ ew,
    const float* __restrict__ x2, ushort_t* __restrict__ ch, ushort_t* __restrict__ cl) {
    int n = blockIdx.x * 4 + (threadIdx.x >> 6), k = threadIdx.x & 63;
    if (n >= N_NODES) return;
    int o0 = offs[n], c = cnt[n];
    float acc = 0.f;
    for (int i = o0; i < o0 + c; ++i) acc += x2[esrc[i] * 64 + k] * ew[i];
    unsigned hi = f2bf(acc);
    size_t o = (size_t)n * 128 + k;
    ch[o] = (ushort_t)hi;
    cl[o] = (ushort_t)f2bf(acc - bf2f(hi));
}

// ---------------- layer1 dense 5->32 ------------------------------------------
__global__ __launch_bounds__(256) void k_dense1(
    const float* __restrict__ x, const float* __restrict__ agg,
    const float* __restrict__ Wrel, const float* __restrict__ brel,
    const float* __restrict__ Wroot, float* __restrict__ x1,
    ushort_t* __restrict__ c2h, ushort_t* __restrict__ c2l) {
    __shared__ float wr[160], wt[160], bb[32];
    __shared__ float sa[8][5], sx[8][5];
    for (int i = threadIdx.x; i < 160; i += 256) { wr[i] = Wrel[i]; wt[i] = Wroot[i]; }
    if (threadIdx.x < 32) bb[threadIdx.x] = brel[threadIdx.x];
    int j = threadIdx.x & 31, nl = threadIdx.x >> 5;
    int nb = blockIdx.x * 8;
    __syncthreads();
    for (int i = threadIdx.x; i < 40; i += 256) {
        int nn = nb + i / 5, kk = i % 5;
        float av = 0.f, xv = 0.f;
        if (nn < N_NODES) { av = agg[nn * 5 + kk]; xv = x[nn * 5 + kk]; }
        sa[i / 5][kk] = av; sx[i / 5][kk] = xv;
    }
    __syncthreads();
    int n = nb + nl;
    if (n < N_NODES) {
        float acc = bb[j];
        #pragma unroll
        for (int k = 0; k < 5; ++k)
            acc += sa[nl][k] * wr[k * 32 + j] + sx[nl][k] * wt[k * 32 + j];
        float v = tanhf(acc);
        x1[n * 32 + j] = v;
        unsigned hi = f2bf(v);
        size_t o = (size_t)n * 64 + 32 + j;
        c2h[o] = (ushort_t)hi;
        c2l[o] = (ushort_t)f2bf(v - bf2f(hi));
    }
}

// ---------------- weight frag packers -----------------------------------------
__global__ void k_packWc(const float* __restrict__ Wrel2, const float* __restrict__ Wroot2,
                         unsigned* __restrict__ dst) {
    int i = blockIdx.x * 256 + threadIdx.x;   // 8192
    int t = i & 3, l = (i >> 2) & 63, kk = (i >> 8) & 3, n = i >> 10;
    int k = kk * 32 + ((l >> 4) << 3) + 2 * t;
    int j = 16 * n + (l & 15);
    float v0 = (k < 64) ? Wrel2[k * 128 + j] : Wroot2[(k - 64) * 128 + j];
    float v1 = (k + 1 < 64) ? Wrel2[(k + 1) * 128 + j] : Wroot2[(k + 1 - 64) * 128 + j];
    dst[i] = f2bf(v0) | (f2bf(v1) << 16);
}
__global__ void k_packWpq(const float* __restrict__ Wd0, unsigned* __restrict__ dst) {
    int i = blockIdx.x * 256 + threadIdx.x;   // 16384
    int t = i & 3, l = (i >> 2) & 63, kk = (i >> 8) & 3, n = i >> 10;
    int k = kk * 32 + ((l >> 4) << 3) + 2 * t;
    int j = 16 * n + (l & 15);
    float v0 = (j < 128) ? Wd0[k * 128 + j] : Wd0[(129 + k) * 128 + (j - 128)];
    float v1 = (j < 128) ? Wd0[(k + 1) * 128 + j] : Wd0[(129 + k + 1) * 128 + (j - 128)];
    dst[i] = f2bf(v0) | (f2bf(v1) << 16);
}
__global__ void k_packW2(const float* __restrict__ Wrel1, const float* __restrict__ Wroot1,
                         unsigned* __restrict__ dst) {
    int i = blockIdx.x * 256 + threadIdx.x;   // 2048
    int t = i & 3, l = (i >> 2) & 63, kk = (i >> 8) & 1, n = i >> 9;
    int k = kk * 32 + ((l >> 4) << 3) + 2 * t;
    int j = 16 * n + (l & 15);
    float v0 = (k < 32) ? Wrel1[k * 64 + j] : Wroot1[(k - 32) * 64 + j];
    float v1 = (k + 1 < 32) ? Wrel1[(k + 1) * 64 + j] : Wroot1[(k + 1 - 32) * 64 + j];
    dst[i] = f2bf(v0) | (f2bf(v1) << 16);
}

// ---------------- G1b: x2 = tanh(cat2 @ W2 + brel1) ---------------------------
__global__ __launch_bounds__(256) void k_g1b(
    const ushort_t* __restrict__ Ah, const ushort_t* __restrict__ Al,
    const unsigned* __restrict__ Wb_, const float* __restrict__ bias,
    float* __restrict__ x2, ushort_t* __restrict__ ch, ushort_t* __restrict__ cl) {
    int wave = threadIdx.x >> 6, lane = threadIdx.x & 63;
    int rl = lane & 15, gp = lane >> 4;
    int cid = blockIdx.x * 4 + wave;
    if (cid >= NCHUNK) return;
    u32x4 B[4][2];
    const u32x4* Wb = (const u32x4*)Wb_;
    #pragma unroll
    for (int n = 0; n < 4; ++n)
        #pragma unroll
        for (int kk = 0; kk < 2; ++kk)
            B[n][kk] = Wb[(n * 2 + kk) * 64 + lane];
    float bs[4];
    #pragma unroll
    for (int n = 0; n < 4; ++n) bs[n] = bias[n * 16 + rl];
    const u32x4* ph = (const u32x4*)(Ah + (size_t)(cid * 16 + rl) * 64 + gp * 8);
    const u32x4* pl = (const u32x4*)(Al + (size_t)(cid * 16 + rl) * 64 + gp * 8);
    bf8 ah[2], al4[2];
    #pragma unroll
    for (int kk = 0; kk < 2; ++kk) {
        ah[kk]  = __builtin_bit_cast(bf8, ph[kk * 4]);
        al4[kk] = __builtin_bit_cast(bf8, pl[kk * 4]);
    }
    f4 acc[4];
    #pragma unroll
    for (int n = 0; n < 4; ++n) acc[n] = (f4)0.f;
    #pragma unroll
    for (int kk = 0; kk < 2; ++kk) {
        #pragma unroll
        for (int n = 0; n < 4; ++n)
            acc[n] = __builtin_amdgcn_mfma_f32_16x16x32_bf16(
                ah[kk], __builtin_bit_cast(bf8, B[n][kk]), acc[n], 0, 0, 0);
        #pragma unroll
        for (int n = 0; n < 4; ++n)
            acc[n] = __builtin_amdgcn_mfma_f32_16x16x32_bf16(
                al4[kk], __builtin_bit_cast(bf8, B[n][kk]), acc[n], 0, 0, 0);
    }
    #pragma unroll
    for (int n = 0; n < 4; ++n)
        #pragma unroll
        for (int t = 0; t < 4; ++t) {
            float v = tanh_fast(acc[n][t] + bs[n]);
            int node = cid * 16 + gp * 4 + t;
            int col = n * 16 + rl;
            x2[(size_t)node * 64 + col] = v;
            unsigned hi = f2bf(v);
            size_t o = (size_t)node * 128 + 64 + col;
            ch[o] = (ushort_t)hi;
            cl[o] = (ushort_t)f2bf(v - bf2f(hi));
        }
}

// ---------------- G1: x3 = tanh(cat @ Wc + brel2) -----------------------------
__global__ __launch_bounds__(256) void k_g1(
    const ushort_t* __restrict__ Ah, const ushort_t* __restrict__ Al,
    const unsigned* __restrict__ Wb_, const float* __restrict__ bias,
    ushort_t* __restrict__ Oh, ushort_t* __restrict__ Ol) {
    int wave = threadIdx.x >> 6, lane = threadIdx.x & 63;
    int cg = wave & 1, mg = wave >> 1;
    int rl = lane & 15, gp = lane >> 4;
    u32x4 B[4][4];
    const u32x4* Wb = (const u32x4*)Wb_;
    #pragma unroll
    for (int n = 0; n < 4; ++n)
        #pragma unroll
        for (int kk = 0; kk < 4; ++kk)
            B[n][kk] = Wb[((cg * 4 + n) * 4 + kk) * 64 + lane];
    float bs[4];
    #pragma unroll
    for (int n = 0; n < 4; ++n) bs[n] = bias[cg * 64 + n * 16 + rl];
    for (int it = 0; it < 2; ++it) {
        int cid = (blockIdx.x * 2 + it) * 2 + mg;
        if (cid >= NCHUNK) continue;
        const u32x4* ph = (const u32x4*)(Ah + (size_t)(cid * 16 + rl) * 128 + gp * 8);
        const u32x4* pl = (const u32x4*)(Al + (size_t)(cid * 16 + rl) * 128 + gp * 8);
        bf8 ah[4], al4[4];
        #pragma unroll
        for (int kk = 0; kk < 4; ++kk) {
            ah[kk]  = __builtin_bit_cast(bf8, ph[kk * 4]);
            al4[kk] = __builtin_bit_cast(bf8, pl[kk * 4]);
        }
        f4 acc[4];
        #pragma unroll
        for (int n = 0; n < 4; ++n) acc[n] = (f4)0.f;
        #pragma unroll
        for (int kk = 0; kk < 4; ++kk) {
            #pragma unroll
            for (int n = 0; n < 4; ++n)
                acc[n] = __builtin_amdgcn_mfma_f32_16x16x32_bf16(
                    ah[kk], __builtin_bit_cast(bf8, B[n][kk]), acc[n], 0, 0, 0);
            #pragma unroll
            for (int n = 0; n < 4; ++n)
                acc[n] = __builtin_amdgcn_mfma_f32_16x16x32_bf16(
                    al4[kk], __builtin_bit_cast(bf8, B[n][kk]), acc[n], 0, 0, 0);
        }
        #pragma unroll
        for (int n = 0; n < 4; ++n)
            #pragma unroll
            for (int t = 0; t < 4; ++t) {
                float v = tanh_fast(acc[n][t] + bs[n]);
                unsigned hi = f2bf(v);
                int node = cid * 16 + gp * 4 + t;
                int col = cg * 64 + n * 16 + rl;
                Oh[(size_t)node * 128 + col] = (ushort_t)hi;
                Ol[(size_t)node * 128 + col] = (ushort_t)f2bf(v - bf2f(hi));
            }
    }
}

// ---------------- G2: [P|Q] = x3 @ Wpq (+bd0), bf16 out -----------------------
__global__ __launch_bounds__(256) void k_g2(
    const ushort_t* __restrict__ Ah, const ushort_t* __restrict__ Al,
    const unsigned* __restrict__ Wb_, const float* __restrict__ bd0,
    ushort_t* __restrict__ P16, ushort_t* __restrict__ Q16) {
    int cg = threadIdx.x >> 6, lane = threadIdx.x & 63;
    int rl = lane & 15, gp = lane >> 4;
    u32x4 B[4][4];
    const u32x4* Wb = (const u32x4*)Wb_;
    #pragma unroll
    for (int n = 0; n < 4; ++n)
        #pragma unroll
        for (int kk = 0; kk < 4; ++kk)
            B[n][kk] = Wb[((cg * 4 + n) * 4 + kk) * 64 + lane];
    float bs[4];
    #pragma unroll
    for (int n = 0; n < 4; ++n) {
        int j = cg * 64 + n * 16 + rl;
        bs[n] = (j < 128) ? bd0[j] : 0.f;
    }
    for (int it = 0; it < 2; ++it) {
        int cid = blockIdx.x * 2 + it;
        if (cid >= NCHUNK) continue;
        const u32x4* ph = (const u32x4*)(Ah + (size_t)(cid * 16 + rl) * 128 + gp * 8);
        const u32x4* pl = (const u32x4*)(Al + (size_t)(cid * 16 + rl) * 128 + gp * 8);
        bf8 ah[4], al4[4];
        #pragma unroll
        for (int kk = 0; kk < 4; ++kk) {
            ah[kk]  = __builtin_bit_cast(bf8, ph[kk * 4]);
            al4[kk] = __builtin_bit_cast(bf8, pl[kk * 4]);
        }
        f4 acc[4];
        #pragma unroll
        for (int n = 0; n < 4; ++n) acc[n] = (f4)0.f;
        #pragma unroll
        for (int kk = 0; kk < 4; ++kk) {
            #pragma unroll
            for (int n = 0; n < 4; ++n)
                acc[n] = __builtin_amdgcn_mfma_f32_16x16x32_bf16(
                    ah[kk], __builtin_bit_cast(bf8, B[n][kk]), acc[n], 0, 0, 0);
            #pragma unroll
            for (int n = 0; n < 4; ++n)
                acc[n] = __builtin_amdgcn_mfma_f32_16x16x32_bf16(
                    al4[kk], __builtin_bit_cast(bf8, B[n][kk]), acc[n], 0, 0, 0);
        }
        #pragma unroll
        for (int n = 0; n < 4; ++n) {
            int j = cg * 64 + n * 16 + rl;
            #pragma unroll
            for (int t = 0; t < 4; ++t) {
                float v = acc[n][t] + bs[n];
                int node = cid * 16 + gp * 4 + t;
                if (j < 128) P16[(size_t)node * 128 + j] = (ushort_t)f2bf(v);
                else         Q16[(size_t)node * 128 + (j - 128)] = (ushort_t)f2bf(v);
            }
        }
    }
}

// ---------------- h0 stats: N_G*16, j<2, LDS block-reduce ---------------------
__global__ __launch_bounds__(256, 1) void k_h0s(
    const int* __restrict__ edges, const float* __restrict__ ea,
    const ushort_t* __restrict__ P16, const ushort_t* __restrict__ Q16,
    const float* __restrict__ Wd0, float* __restrict__ part0) {
    __shared__ float ls[2][4][128];
    int g = blockIdx.x >> 4, tb = blockIdx.x & 15;
    int wave = threadIdx.x >> 6, lane = threadIdx.x & 63;
    int row = lane & 15, grp = lane >> 4;
    int slot = tb * 4 + wave;
    f4 wmr[4][2];
    #pragma unroll
    for (int kk = 0; kk < 4; ++kk) {
        const f4* wmp = (const f4*)(Wd0 + 16384 + kk * 32 + grp * 8);
        wmr[kk][0] = wmp[0]; wmr[kk][1] = wmp[1];
    }
    f4 s[4][2], q[4][2];
    #pragma unroll
    for (int kk = 0; kk < 4; ++kk)
        #pragma unroll
        for (int h = 0; h < 2; ++h) { s[kk][h] = (f4)0.f; q[kk][h] = (f4)0.f; }

    for (int j = 0; j < 2; ++j) {
        int tile = slot + 64 * j;
        if (tile >= 125) break;
        int eg0 = g * EPG + tile * 32;
        #pragma unroll
        for (int m = 0; m < 2; ++m) {
            int e = eg0 + 16 * m + row;
            int sn = edges[e], dn = edges[N_EDGES + e];
            float w = ea[2 * e];
            const u32x4* Pr = (const u32x4*)(P16 + (size_t)sn * 128);
            const u32x4* Qr = (const u32x4*)(Q16 + (size_t)dn * 128);
            #pragma unroll
            for (int kk = 0; kk < 4; ++kk) {
                f4 p0, p1, q0, q1;
                unp8(Pr[kk * 4 + grp], p0, p1);
                unp8(Qr[kk * 4 + grp], q0, q1);
                #pragma unroll
                for (int r = 0; r < 4; ++r) {
                    float h0 = tanh_fast(p0[r] + q0[r] + w * wmr[kk][0][r]);
                    float h1 = tanh_fast(p1[r] + q1[r] + w * wmr[kk][1][r]);
                    s[kk][0][r] += h0; q[kk][0][r] += h0 * h0;
                    s[kk][1][r] += h1; q[kk][1][r] += h1 * h1;
                }
            }
        }
    }
    #pragma unroll
    for (int kk = 0; kk < 4; ++kk)
        #pragma unroll
        for (int h = 0; h < 2; ++h)
            #pragma unroll
            for (int r = 0; r < 4; ++r) {
                float sv = s[kk][h][r], qv = q[kk][h][r];
                sv += __shfl_xor(sv, 1); sv += __shfl_xor(sv, 2);
                sv += __shfl_xor(sv, 4); sv += __shfl_xor(sv, 8);
                qv += __shfl_xor(qv, 1); qv += __shfl_xor(qv, 2);
                qv += __shfl_xor(qv, 4); qv += __shfl_xor(qv, 8);
                if (row == 0) {
                    int k = kk * 32 + grp * 8 + h * 4 + r;
                    ls[0][wave][k] = sv;
                    ls[1][wave][k] = qv;
                }
            }
    __syncthreads();
    int st = threadIdx.x >> 7, k = threadIdx.x & 127;
    float v = ls[st][0][k] + ls[st][1][k] + ls[st][2][k] + ls[st][3][k];
    part0[((size_t)(g * 16 + tb) * 2 + st) * 128 + k] = v;
}

// ---------------- fold gnorm0 (sums 16 partials) -> W1b + gam -----------------
__global__ __launch_bounds__(256) void k_fin0(
    const float* __restrict__ part0,
    const float* __restrict__ gnw, const float* __restrict__ gnb, const float* __restrict__ gnms,
    const float* __restrict__ Wd1, const float* __restrict__ bd1,
    unsigned* __restrict__ W1b, float* __restrict__ gam) {
    int g = blockIdx.x;
    __shared__ float al[128], be[128];
    if (threadIdx.x < 128) {
        int k = threadIdx.x;
        float S = 0.f, Q = 0.f;
        #pragma unroll
        for (int tb = 0; tb < 16; ++tb) {
            S += part0[((size_t)(g * 16 + tb) * 2 + 0) * 128 + k];
            Q += part0[((size_t)(g * 16 + tb) * 2 + 1) * 128 + k];
        }
        float mean = S * (1.f / EPG);
        float t = mean * gnms[k];
        float var = (Q - 2.f * t * S) * (1.f / EPG) + t * t;
        float a = gnw[k] * rsqrtf(var + 1e-5f);
        al[k] = a;
        be[k] = gnb[k] - a * t;
    }
    __syncthreads();
    unsigned* Wb = W1b + (size_t)g * 4096;
    for (int i = threadIdx.x; i < 4096; i += 256) {
        int t = i & 3, l = (i >> 2) & 63, kk = (i >> 8) & 3, n = i >> 10;
        int k = kk * 32 + ((l >> 4) << 3) + 2 * t;
        int j = 16 * n + (l & 15);
        unsigned lo = f2bf(al[k] * Wd1[k * 64 + j]);
        unsigned hi = f2bf(al[k + 1] * Wd1[(k + 1) * 64 + j]);
        Wb[i] = lo | (hi << 16);
    }
    if (threadIdx.x < 64) {
        int j = threadIdx.x;
        float acc = bd1[j];
        #pragma unroll 8
        for (int k = 0; k < 128; ++k) acc += be[k] * Wd1[k * 64 + j];
        gam[g * 64 + j] = acc;
    }
}

// ---------------- h1 pass: N_G*16, j<2; stats(+h1 store) or vals --------------
template<int DO_VALS, int STORE>
__global__ __launch_bounds__(256, 1) void k_h1m(
    const int* __restrict__ edges, const float* __restrict__ ea,
    const ushort_t* __restrict__ P16, const ushort_t* __restrict__ Q16,
    const float* __restrict__ Wd0,
    const unsigned* __restrict__ W1b, const float* __restrict__ gam,
    const float* __restrict__ ug, const float* __restrict__ cg,
    float* __restrict__ part1,
    float* __restrict__ vals, float* __restrict__ outp, unsigned* __restrict__ h1ff) {
    __shared__ float ls[2][4][64];
    int g = blockIdx.x >> 4, tb = blockIdx.x & 15;
    int wave = threadIdx.x >> 6, lane = threadIdx.x & 63;
    int col = lane & 15, grp = lane >> 4;
    int slot = tb * 4 + wave;

    bf8 bfr[4][4];
    {
        const u32x4* Wb = (const u32x4*)(W1b + (size_t)g * 4096);
        #pragma unroll
        for (int n = 0; n < 4; ++n)
            #pragma unroll
            for (int kk = 0; kk < 4; ++kk)
                bfr[n][kk] = __builtin_bit_cast(bf8, Wb[(n * 4 + kk) * 64 + lane]);
    }
    f4 wmr[4][2];
    #pragma unroll
    for (int kk = 0; kk < 4; ++kk) {
        const f4* wmp = (const f4*)(Wd0 + 16384 + kk * 32 + grp * 8);
        wmr[kk][0] = wmp[0]; wmr[kk][1] = wmp[1];
    }
    float gamn[4], un[4] = {0.f, 0.f, 0.f, 0.f};
    #pragma unroll
    for (int n = 0; n < 4; ++n) gamn[n] = gam[g * 64 + 16 * n + col];
    float cgv = 0.f;
    if (DO_VALS) {
        #pragma unroll
        for (int n = 0; n < 4; ++n) un[n] = ug[g * 64 + 16 * n + col];
        cgv = cg[g];
    }
    float sacc[4] = {0.f, 0.f, 0.f, 0.f}, qacc[4] = {0.f, 0.f, 0.f, 0.f};

    for (int j = 0; j < 2; ++j) {
        int tile = slot + 64 * j;
        if (tile >= 125) break;
        int eg0 = g * EPG + tile * 32;
        bf8 af[2][4];
        #pragma unroll
        for (int m = 0; m < 2; ++m) {
            int e = eg0 + 16 * m + col;
            int sn = edges[e], dn = edges[N_EDGES + e];
            float w = ea[2 * e];
            const u32x4* Pr = (const u32x4*)(P16 + (size_t)sn * 128);
            const u32x4* Qr = (const u32x4*)(Q16 + (size_t)dn * 128);
            #pragma unroll
            for (int kk = 0; kk < 4; ++kk) {
                f4 p0, p1, q0, q1;
                unp8(Pr[kk * 4 + grp], p0, p1);
                unp8(Qr[kk * 4 + grp], q0, q1);
                bf8 a;
                #pragma unroll
                for (int r = 0; r < 4; ++r) {
                    float h0 = tanh_fast(p0[r] + q0[r] + w * wmr[kk][0][r]);
                    float h1 = tanh_fast(p1[r] + q1[r] + w * wmr[kk][1][r]);
                    a[r]     = (short)f2bf(h0);
                    a[4 + r] = (short)f2bf(h1);
                }
                af[m][kk] = a;
            }
        }
        f4 acc[2][4];
        #pragma unroll
        for (int m = 0; m < 2; ++m)
            #pragma unroll
            for (int n = 0; n < 4; ++n) acc[m][n] = (f4)0.f;
        #pragma unroll
        for (int kk = 0; kk < 4; ++kk)
            #pragma unroll
            for (int m = 0; m < 2; ++m)
                #pragma unroll
                for (int n = 0; n < 4; ++n)
                    acc[m][n] = __builtin_amdgcn_mfma_f32_16x16x32_bf16(
                        af[m][kk], bfr[n][kk], acc[m][n], 0, 0, 0);

        if (DO_VALS) {
            float rp[2][4];
            #pragma unroll
            for (int m = 0; m < 2; ++m)
                #pragma unroll
                for (int t = 0; t < 4; ++t) {
                    float v = 0.f;
                    #pragma unroll
                    for (int n = 0; n < 4; ++n)
                        v += un[n] * tanh_fast(acc[m][n][t] + gamn[n]);
                    v += __shfl_xor(v, 1); v += __shfl_xor(v, 2);
                    v += __shfl_xor(v, 4); v += __shfl_xor(v, 8);
                    rp[m][t] = v + cgv;
                }
            if (col == 0) {
                #pragma unroll
                for (int m = 0; m < 2; ++m)
                    #pragma unroll
                    for (int pr = 0; pr < 2; ++pr) {
                        float va = rp[m][2 * pr], vb = rp[m][2 * pr + 1];
                        int p = ((eg0 + 16 * m + grp * 4) >> 1) + pr;
                        vals[p] = fminf(va, vb);
                        outp[600000 + p] = (vb < va) ? 1.f : 0.f;
                        int e = 2 * p;
                        outp[p]          = (float)edges[e];
                        outp[200000 + p] = (float)edges[N_EDGES + e];
                    }
            }
        } else {
            int tileG = g * 125 + tile;
            #pragma unroll
            for (int m = 0; m < 2; ++m)
                #pragma unroll
                for (int n = 0; n < 4; ++n) {
                    float h[4];
                    #pragma unroll
                    for (int t = 0; t < 4; ++t) {
                        h[t] = tanh_fast(acc[m][n][t] + gamn[n]);
                        sacc[n] += h[t]; qacc[n] += h[t] * h[t];
                    }
                    if (STORE) {
                        unsigned w0 = f2bf(h[0]) | (f2bf(h[1]) << 16);
                        unsigned w1 = f2bf(h[2]) | (f2bf(h[3]) << 16);
                        size_t base = ((size_t)(tileG * 2 + m) * 4 + n) * 2;
                        h1ff[(base + 0) * 64 + lane] = w0;
                        h1ff[(base + 1) * 64 + lane] = w1;
                    }
                }
        }
    }
    if (!DO_VALS) {
        #pragma unroll
        for (int n = 0; n < 4; ++n) {
            float s = sacc[n], q = qacc[n];
            s += __shfl_xor(s, 16); s += __shfl_xor(s, 32);
            q += __shfl_xor(q, 16); q += __shfl_xor(q, 32);
            if (lane < 16) {
                ls[0][wave][n * 16 + col] = s;
                ls[1][wave][n * 16 + col] = q;
            }
        }
        __syncthreads();
        if (threadIdx.x < 128) {
            int st = threadIdx.x >> 6, k = threadIdx.x & 63;
            float v = ls[st][0][k] + ls[st][1][k] + ls[st][2][k] + ls[st][3][k];
            part1[((size_t)(g * 16 + tb) * 2 + st) * 64 + k] = v;
        }
    }
}

// ---------------- vals pass: read h1ff, dot, pair-min -------------------------
__global__ __launch_bounds__(256) void k_vals(
    const int* __restrict__ edges, const unsigned* __restrict__ h1ff,
    const float* __restrict__ ug, const float* __restrict__ cg,
    float* __restrict__ vals, float* __restrict__ outp) {
    int g = blockIdx.x >> 4, tb = blockIdx.x & 15;
    int wave = threadIdx.x >> 6, lane = threadIdx.x & 63;
    int col = lane & 15, grp = lane >> 4;
    int slot = tb * 4 + wave;
    float un[4];
    #pragma unroll
    for (int n = 0; n < 4; ++n) un[n] = ug[g * 64 + 16 * n + col];
    float cgv = cg[g];
    for (int j = 0; j < 2; ++j) {
        int tile = slot + 64 * j;
        if (tile >= 125) break;
        int tileG = g * 125 + tile;
        int eg0 = g * EPG + tile * 32;
        #pragma unroll
        for (int m = 0; m < 2; ++m) {
            float v[4] = {0.f, 0.f, 0.f, 0.f};
            #pragma unroll
            for (int n = 0; n < 4; ++n) {
                size_t base = ((size_t)(tileG * 2 + m) * 4 + n) * 2;
                unsigned w0 = h1ff[(base + 0) * 64 + lane];
                unsigned w1 = h1ff[(base + 1) * 64 + lane];
                v[0] += un[n] * bf2f(w0 & 0xFFFFu);
                v[1] += un[n] * bf2f(w0 >> 16);
                v[2] += un[n] * bf2f(w1 & 0xFFFFu);
                v[3] += un[n] * bf2f(w1 >> 16);
            }
            float rp[4];
            #pragma unroll
            for (int t = 0; t < 4; ++t) {
                float vv = v[t];
                vv += __shfl_xor(vv, 1); vv += __shfl_xor(vv, 2);
                vv += __shfl_xor(vv, 4); vv += __shfl_xor(vv, 8);
                rp[t] = vv + cgv;
            }
            if (col == 0) {
                #pragma unroll
                for (int pr = 0; pr < 2; ++pr) {
                    float va = rp[2 * pr], vb = rp[2 * pr + 1];
                    int p = ((eg0 + 16 * m + grp * 4) >> 1) + pr;
                    vals[p] = fminf(va, vb);
                    outp[600000 + p] = (vb < va) ? 1.f : 0.f;
                    int e = 2 * p;
                    outp[p]          = (float)edges[e];
                    outp[200000 + p] = (float)edges[N_EDGES + e];
                }
            }
        }
    }
}

// ---------------- fold gnorm1 (sums 16 partials) into Wout --------------------
__global__ void k_fin1(const float* __restrict__ part1,
                       const float* __restrict__ gnw, const float* __restrict__ gnb,
                       const float* __restrict__ gnms,
                       const float* __restrict__ Wout, const float* __restrict__ bout,
                       float* __restrict__ ug, float* __restrict__ cg) {
    int g = blockIdx.x; int j = threadIdx.x;  // 64 threads
    float S = 0.f, Q = 0.f;
    #pragma unroll
    for (int tb = 0; tb < 16; ++tb) {
        S += part1[((size_t)(g * 16 + tb) * 2 + 0) * 64 + j];
        Q += part1[((size_t)(g * 16 + tb) * 2 + 1) * 64 + j];
    }
    float mean = S * (1.f / EPG);
    float t = mean * gnms[j];
    float var = (Q - 2.f * t * S) * (1.f / EPG) + t * t;
    float a = gnw[j] * rsqrtf(var + 1e-5f);
    float b = gnb[j] - a * t;
    ug[g * 64 + j] = a * Wout[j];
    float c = b * Wout[j];
    #pragma unroll
    for (int off = 32; off; off >>= 1) c += __shfl_xor(c, off);
    if (j == 0) cg[g] = c + bout[0];
}

// ---------------- per-graph softmax -------------------------------------------
__global__ __launch_bounds__(256) void k_softmax(const float* __restrict__ vals,
                                                 float* __restrict__ outp) {
    int g = blockIdx.x;
    __shared__ float rbuf[4], rbuf2[4];
    int t = threadIdx.x;
    const float* v = vals + g * PPG;
    float mx = -1e30f;
    for (int i = t; i < PPG; i += 256) mx = fmaxf(mx, v[i]);
    #pragma unroll
    for (int off = 32; off; off >>= 1) mx = fmaxf(mx, __shfl_xor(mx, off));
    if ((t & 63) == 0) rbuf[t >> 6] = mx;
    __syncthreads();
    mx = fmaxf(fmaxf(rbuf[0], rbuf[1]), fmaxf(rbuf[2], rbuf[3]));
    float sm = 0.f;
    for (int i = t; i < PPG; i += 256) sm += expf(v[i] - mx);
    #pragma unroll
    for (int off = 32; off; off >>= 1) sm += __shfl_xor(sm, off);
    if ((t & 63) == 0) rbuf2[t >> 6] = sm;
    __syncthreads();
    sm = rbuf2[0] + rbuf2[1] + rbuf2[2] + rbuf2[3];
    for (int i = t; i < PPG; i += 256)
        outp[400000 + g * PPG + i] = expf(v[i] - mx) / (sm + 1e-16f);
}

extern "C" void kernel_launch(void* const* d_in, const int* in_sizes, int n_in,
                              void* d_out, int out_size, void* d_ws, size_t ws_size,
                              hipStream_t stream) {
    const float* x     = (const float*)d_in[0];
    const int*   edges = (const int*)d_in[1];
    const float* ea    = (const float*)d_in[2];
    const float* Wrel0 = (const float*)d_in[6],  *brel0 = (const float*)d_in[7],  *Wroot0 = (const float*)d_in[8];
    const float* Wrel1 = (const float*)d_in[9],  *brel1 = (const float*)d_in[10], *Wroot1 = (const float*)d_in[11];
    const float* Wrel2 = (const float*)d_in[12], *brel2 = (const float*)d_in[13], *Wroot2 = (const float*)d_in[14];
    const float* Wd0 = (const float*)d_in[15],  *bd0 = (const float*)d_in[16];
    const float* gnw0 = (const float*)d_in[17], *gnb0 = (const float*)d_in[18], *gnms0 = (const float*)d_in[19];
    const float* Wd1 = (const float*)d_in[20],  *bd1 = (const float*)d_in[21];
    const float* gnw1 = (const float*)d_in[22], *gnb1 = (const float*)d_in[23], *gnms1 = (const float*)d_in[24];
    const float* Wout = (const float*)d_in[25], *bout = (const float*)d_in[26];
    float* o = (float*)d_out;
    float* w = (float*)d_ws;

    // region A [0, 8.25M): early node tensors -> x3 planes
    float* agg5 = w;
    float* x1   = w + 250000;
    float* x2   = w + 1850000;
    ushort_t* c2h = (ushort_t*)(w + 5050000);
    ushort_t* c2l = (ushort_t*)(w + 6650000);
    ushort_t* x3h = (ushort_t*)(w + 0);
    ushort_t* x3l = (ushort_t*)(w + 3200000);
    // region B [8.25M, 21.05M): cat planes -> P16|Q16 (bf16)
    ushort_t* cath = (ushort_t*)(w + 8250000);
    ushort_t* catl = (ushort_t*)(w + 11450000);
    ushort_t* P16  = (ushort_t*)(w + 8250000);     // 6.4M ushort (3.2M floats)
    ushort_t* Q16  = (ushort_t*)(w + 11450000);
    // tail [21.05M, ~22.9M)
    float* tail = w + 21050000;
    unsigned* Wcb  = (unsigned*)tail;
    unsigned* Wpqb = Wcb + 8192;
    unsigned* W2b  = Wpqb + 16384;
    int* cnt   = (int*)(W2b + 2048);
    int* fillc = cnt + 50000;
    int* offs  = fillc + 50000;
    int* esrc  = offs + 50000;
    float* ew  = (float*)(esrc + 200000);
    unsigned* W1b = (unsigned*)(ew + 200000);      // 409600
    float* gam = (float*)(W1b + 409600);           // 6400
    float* ug  = gam + 6400;                       // 6400
    float* cg  = ug + 6400;                        // 100
    float* vals = cg + 100;                        // 200000
    float* part0 = vals + 200000;                  // 409600
    float* part1 = part0 + 409600;                 // 204800
    // h1ff: DISJOINT region [25.6M, 38.4M) floats — requires ws >= 153.6MB.
    unsigned* h1ff = (unsigned*)(w + 25600000);
    const bool haveH1 = ws_size >= 155000000ULL;   // proven >=159.2MB in R6

    hipMemsetAsync(cnt, 0, 100000 * sizeof(int), stream);

    k_packWc<<<32, 256, 0, stream>>>(Wrel2, Wroot2, Wcb);
    k_packWpq<<<64, 256, 0, stream>>>(Wd0, Wpqb);
    k_packW2<<<8, 256, 0, stream>>>(Wrel1, Wroot1, W2b);

    k_csr_count<<<782, 256, 0, stream>>>(edges, cnt);
    k_csr_scan<<<N_G, 512, 0, stream>>>(cnt, offs);
    k_csr_fill<<<782, 256, 0, stream>>>(edges, ea, offs, fillc, esrc, ew);

    k_gath5<<<1563, 256, 0, stream>>>(cnt, offs, esrc, ew, x, agg5);
    k_dense1<<<6250, 256, 0, stream>>>(x, agg5, Wrel0, brel0, Wroot0, x1, c2h, c2l);
    k_gath32<<<6250, 256, 0, stream>>>(cnt, offs, esrc, ew, x1, c2h, c2l);
    k_g1b<<<782, 256, 0, stream>>>(c2h, c2l, W2b, brel1, x2, cath, catl);
    k_gath64<<<12500, 256, 0, stream>>>(cnt, offs, esrc, ew, x2, cath, catl);

    k_g1<<<(NCHUNK + 3) / 4, 256, 0, stream>>>(cath, catl, Wcb, brel2, x3h, x3l);
    k_g2<<<(NCHUNK + 1) / 2, 256, 0, stream>>>(x3h, x3l, Wpqb, bd0, P16, Q16);

    k_h0s<<<N_G * 16, 256, 0, stream>>>(edges, ea, P16, Q16, Wd0, part0);
    k_fin0<<<N_G, 256, 0, stream>>>(part0, gnw0, gnb0, gnms0, Wd1, bd1, W1b, gam);

    if (haveH1) {
        k_h1m<0, 1><<<N_G * 16, 256, 0, stream>>>(edges, ea, P16, Q16, Wd0, W1b, gam,
                                                  ug, cg, part1, vals, o, h1ff);
        k_fin1<<<N_G, 64, 0, stream>>>(part1, gnw1, gnb1, gnms1, Wout, bout, ug, cg);
        k_vals<<<N_G * 16, 256, 0, stream>>>(edges, h1ff, ug, cg, vals, o);
    } else {
        k_h1m<0, 0><<<N_G * 16, 256, 0, stream>>>(edges, ea, P16, Q16, Wd0, W1b, gam,
                                                  ug, cg, part1, vals, o, h1ff);
        k_fin1<<<N_G, 64, 0, stream>>>(part1, gnw1, gnb1, gnms1, Wout, bout, ug, cg);
        k_h1m<1, 0><<<N_G * 16, 256, 0, stream>>>(edges, ea, P16, Q16, Wd0, W1b, gam,
                                                  ug, cg, part1, vals, o, h1ff);
    }

    k_softmax<<<N_G, 256, 0, stream>>>(vals, o);
}

// Round 11
// 372.652 us; speedup vs baseline: 1.3191x; 1.0096x over previous
//
#include <hip/hip_runtime.h>

// GraphNN R11: R10 + bijective XCD-aware block swizzle on the 4 random-gather
// kernels (gath32/gath64/h0s/h1m) so each XCD's L2 holds its graphs' P/Q slice
// (3.2MB < 4MB); + pack kernels merged. Numerically identical to R10.

#define N_NODES 50000
#define N_EDGES 400000
#define N_PAIRS 200000
#define N_G     100
#define EPG     4000
#define PPG     2000
#define NCHUNK  3125   // 50000/16

typedef float  f4   __attribute__((ext_vector_type(4)));
typedef short  bf8  __attribute__((ext_vector_type(8)));
typedef unsigned u32x4 __attribute__((ext_vector_type(4)));
typedef unsigned short ushort_t;

__device__ __forceinline__ float tanh_fast(float x) {
    float cx = fminf(15.f, fmaxf(-15.f, x));
    float e = __expf(2.f * cx);
    return (e - 1.f) * __builtin_amdgcn_rcpf(e + 1.f);
}
__device__ __forceinline__ unsigned f2bf(float f) {   // RNE fp32->bf16
    unsigned u = __float_as_uint(f);
    return (u + 0x7FFFu + ((u >> 16) & 1u)) >> 16;
}
__device__ __forceinline__ float bf2f(unsigned h) { return __uint_as_float(h << 16); }
__device__ __forceinline__ void unp8(u32x4 v, f4& a, f4& b) {  // 8 bf16 -> 2xf4
    a[0] = bf2f(v[0] & 0xFFFFu); a[1] = bf2f(v[0] >> 16);
    a[2] = bf2f(v[1] & 0xFFFFu); a[3] = bf2f(v[1] >> 16);
    b[0] = bf2f(v[2] & 0xFFFFu); b[1] = bf2f(v[2] >> 16);
    b[2] = bf2f(v[3] & 0xFFFFu); b[3] = bf2f(v[3] >> 16);
}
// bijective XCD swizzle (m204 form): XCD x = bid%8 gets a contiguous virtual range
__device__ __forceinline__ int xcd_swz(int bid, int nwg) {
    int xcd = bid & 7, loc = bid >> 3;
    int q = nwg >> 3, r = nwg & 7;
    return (xcd < r ? xcd * (q + 1) : r * (q + 1) + (xcd - r) * q) + loc;
}

// ---------------- CSR build ---------------------------------------------------
__global__ void k_csr_count(const int* __restrict__ edges, int* __restrict__ cnt) {
    int p = blockIdx.x * 256 + threadIdx.x;
    if (p >= N_PAIRS) return;
    atomicAdd(&cnt[edges[N_EDGES + 2 * p]], 1);
}
__global__ __launch_bounds__(512) void k_csr_scan(const int* __restrict__ cnt,
                                                  int* __restrict__ offs) {
    __shared__ int s[512];
    int g = blockIdx.x, t = threadIdx.x;
    int v = (t < 500) ? cnt[g * 500 + t] : 0;
    s[t] = v; __syncthreads();
    for (int off = 1; off < 512; off <<= 1) {
        int a = (t >= off) ? s[t - off] : 0;
        __syncthreads();
        s[t] += a; __syncthreads();
    }
    if (t < 500) offs[g * 500 + t] = g * PPG + s[t] - v;
}
__global__ void k_csr_fill(const int* __restrict__ edges, const float* __restrict__ ea,
                           const int* __restrict__ offs, int* __restrict__ fillc,
                           int* __restrict__ esrc, float* __restrict__ ew) {
    int p = blockIdx.x * 256 + threadIdx.x;
    if (p >= N_PAIRS) return;
    int d = edges[N_EDGES + 2 * p];
    int pos = offs[d] + atomicAdd(&fillc[d], 1);
    esrc[pos] = edges[2 * p];
    ew[pos] = ea[4 * p] + ea[4 * p + 2];
}

// ---------------- gathers -----------------------------------------------------
__global__ __launch_bounds__(256) void k_gath5(
    const int* __restrict__ cnt, const int* __restrict__ offs,
    const int* __restrict__ esrc, const float* __restrict__ ew,
    const float* __restrict__ x, float* __restrict__ agg) {
    int t = blockIdx.x * 256 + threadIdx.x;
    int n = t >> 3, k = t & 7;
    if (n >= N_NODES || k >= 5) return;
    int o0 = offs[n], c = cnt[n];
    float acc = 0.f;
    for (int i = o0; i < o0 + c; ++i) acc += x[esrc[i] * 5 + k] * ew[i];
    agg[n * 5 + k] = acc;
}
__global__ __launch_bounds__(256) void k_gath32(
    const int* __restrict__ cnt, const int* __restrict__ offs,
    const int* __restrict__ esrc, const float* __restrict__ ew,
    const float* __restrict__ x1, ushort_t* __restrict__ c2h, ushort_t* __restrict__ c2l) {
    int vb = xcd_swz(blockIdx.x, gridDim.x);
    int n = vb * 8 + (threadIdx.x >> 5), k = threadIdx.x & 31;
    if (n >= N_NODES) return;
    int o0 = offs[n], c = cnt[n];
    float acc = 0.f;
    for (int i = o0; i < o0 + c; ++i) acc += x1[esrc[i] * 32 + k] * ew[i];
    unsigned hi = f2bf(acc);
    size_t o = (size_t)n * 64 + k;
    c2h[o] = (ushort_t)hi;
    c2l[o] = (ushort_t)f2bf(acc - bf2f(hi));
}
__global__ __launch_bounds__(256) void k_gath64(
    const int* __restrict__ cnt, const int* __restrict__ offs,
    const int* __restrict__ esrc, const float* __restrict__ ew,
    const float* __restrict__ x2, ushort_t* __restrict__ ch, ushort_t* __restrict__ cl) {
    int vb = xcd_swz(blockIdx.x, gridDim.x);
    int n = vb * 4 + (threadIdx.x >> 6), k = threadIdx.x & 63;
    if (n >= N_NODES) return;
    int o0 = offs[n], c = cnt[n];
    float acc = 0.f;
    for (int i = o0; i < o0 + c; ++i) acc += x2[esrc[i] * 64 + k] * ew[i];
    unsigned hi = f2bf(acc);
    size_t o = (size_t)n * 128 + k;
    ch[o] = (ushort_t)hi;
    cl[o] = (ushort_t)f2bf(acc - bf2f(hi));
}

// ---------------- layer1 dense 5->32 ------------------------------------------
__global__ __launch_bounds__(256) void k_dense1(
    const float* __restrict__ x, const float* __restrict__ agg,
    const float* __restrict__ Wrel, const float* __restrict__ brel,
    const float* __restrict__ Wroot, float* __restrict__ x1,
    ushort_t* __restrict__ c2h, ushort_t* __restrict__ c2l) {
    __shared__ float wr[160], wt[160], bb[32];
    __shared__ float sa[8][5], sx[8][5];
    for (int i = threadIdx.x; i < 160; i += 256) { wr[i] = Wrel[i]; wt[i] = Wroot[i]; }
    if (threadIdx.x < 32) bb[threadIdx.x] = brel[threadIdx.x];
    int j = threadIdx.x & 31, nl = threadIdx.x >> 5;
    int nb = blockIdx.x * 8;
    __syncthreads();
    for (int i = threadIdx.x; i < 40; i += 256) {
        int nn = nb + i / 5, kk = i % 5;
        float av = 0.f, xv = 0.f;
        if (nn < N_NODES) { av = agg[nn * 5 + kk]; xv = x[nn * 5 + kk]; }
        sa[i / 5][kk] = av; sx[i / 5][kk] = xv;
    }
    __syncthreads();
    int n = nb + nl;
    if (n < N_NODES) {
        float acc = bb[j];
        #pragma unroll
        for (int k = 0; k < 5; ++k)
            acc += sa[nl][k] * wr[k * 32 + j] + sx[nl][k] * wt[k * 32 + j];
        float v = tanhf(acc);
        x1[n * 32 + j] = v;
        unsigned hi = f2bf(v);
        size_t o = (size_t)n * 64 + 32 + j;
        c2h[o] = (ushort_t)hi;
        c2l[o] = (ushort_t)f2bf(v - bf2f(hi));
    }
}

// ---------------- merged weight frag packer -----------------------------------
// blocks 0-31: Wc (8192), 32-95: Wpq (16384), 96-103: W2 (2048)
__global__ void k_packAll(const float* __restrict__ Wrel2, const float* __restrict__ Wroot2,
                          const float* __restrict__ Wd0,
                          const float* __restrict__ Wrel1, const float* __restrict__ Wroot1,
                          unsigned* __restrict__ Wcb, unsigned* __restrict__ Wpqb,
                          unsigned* __restrict__ W2b) {
    int b = blockIdx.x;
    if (b < 32) {
        int i = b * 256 + threadIdx.x;
        int t = i & 3, l = (i >> 2) & 63, kk = (i >> 8) & 3, n = i >> 10;
        int k = kk * 32 + ((l >> 4) << 3) + 2 * t;
        int j = 16 * n + (l & 15);
        float v0 = (k < 64) ? Wrel2[k * 128 + j] : Wroot2[(k - 64) * 128 + j];
        float v1 = (k + 1 < 64) ? Wrel2[(k + 1) * 128 + j] : Wroot2[(k + 1 - 64) * 128 + j];
        Wcb[i] = f2bf(v0) | (f2bf(v1) << 16);
    } else if (b < 96) {
        int i = (b - 32) * 256 + threadIdx.x;
        int t = i & 3, l = (i >> 2) & 63, kk = (i >> 8) & 3, n = i >> 10;
        int k = kk * 32 + ((l >> 4) << 3) + 2 * t;
        int j = 16 * n + (l & 15);
        float v0 = (j < 128) ? Wd0[k * 128 + j] : Wd0[(129 + k) * 128 + (j - 128)];
        float v1 = (j < 128) ? Wd0[(k + 1) * 128 + j] : Wd0[(129 + k + 1) * 128 + (j - 128)];
        Wpqb[i] = f2bf(v0) | (f2bf(v1) << 16);
    } else {
        int i = (b - 96) * 256 + threadIdx.x;
        int t = i & 3, l = (i >> 2) & 63, kk = (i >> 8) & 1, n = i >> 9;
        int k = kk * 32 + ((l >> 4) << 3) + 2 * t;
        int j = 16 * n + (l & 15);
        float v0 = (k < 32) ? Wrel1[k * 64 + j] : Wroot1[(k - 32) * 64 + j];
        float v1 = (k + 1 < 32) ? Wrel1[(k + 1) * 64 + j] : Wroot1[(k + 1 - 32) * 64 + j];
        W2b[i] = f2bf(v0) | (f2bf(v1) << 16);
    }
}

// ---------------- G1b: x2 = tanh(cat2 @ W2 + brel1) ---------------------------
__global__ __launch_bounds__(256) void k_g1b(
    const ushort_t* __restrict__ Ah, const ushort_t* __restrict__ Al,
    const unsigned* __restrict__ Wb_, const float* __restrict__ bias,
    float* __restrict__ x2, ushort_t* __restrict__ ch, ushort_t* __restrict__ cl) {
    int wave = threadIdx.x >> 6, lane = threadIdx.x & 63;
    int rl = lane & 15, gp = lane >> 4;
    int cid = blockIdx.x * 4 + wave;
    if (cid >= NCHUNK) return;
    u32x4 B[4][2];
    const u32x4* Wb = (const u32x4*)Wb_;
    #pragma unroll
    for (int n = 0; n < 4; ++n)
        #pragma unroll
        for (int kk = 0; kk < 2; ++kk)
            B[n][kk] = Wb[(n * 2 + kk) * 64 + lane];
    float bs[4];
    #pragma unroll
    for (int n = 0; n < 4; ++n) bs[n] = bias[n * 16 + rl];
    const u32x4* ph = (const u32x4*)(Ah + (size_t)(cid * 16 + rl) * 64 + gp * 8);
    const u32x4* pl = (const u32x4*)(Al + (size_t)(cid * 16 + rl) * 64 + gp * 8);
    bf8 ah[2], al4[2];
    #pragma unroll
    for (int kk = 0; kk < 2; ++kk) {
        ah[kk]  = __builtin_bit_cast(bf8, ph[kk * 4]);
        al4[kk] = __builtin_bit_cast(bf8, pl[kk * 4]);
    }
    f4 acc[4];
    #pragma unroll
    for (int n = 0; n < 4; ++n) acc[n] = (f4)0.f;
    #pragma unroll
    for (int kk = 0; kk < 2; ++kk) {
        #pragma unroll
        for (int n = 0; n < 4; ++n)
            acc[n] = __builtin_amdgcn_mfma_f32_16x16x32_bf16(
                ah[kk], __builtin_bit_cast(bf8, B[n][kk]), acc[n], 0, 0, 0);
        #pragma unroll
        for (int n = 0; n < 4; ++n)
            acc[n] = __builtin_amdgcn_mfma_f32_16x16x32_bf16(
                al4[kk], __builtin_bit_cast(bf8, B[n][kk]), acc[n], 0, 0, 0);
    }
    #pragma unroll
    for (int n = 0; n < 4; ++n)
        #pragma unroll
        for (int t = 0; t < 4; ++t) {
            float v = tanh_fast(acc[n][t] + bs[n]);
            int node = cid * 16 + gp * 4 + t;
            int col = n * 16 + rl;
            x2[(size_t)node * 64 + col] = v;
            unsigned hi = f2bf(v);
            size_t o = (size_t)node * 128 + 64 + col;
            ch[o] = (ushort_t)hi;
            cl[o] = (ushort_t)f2bf(v - bf2f(hi));
        }
}

// ---------------- G1: x3 = tanh(cat @ Wc + brel2) -----------------------------
__global__ __launch_bounds__(256) void k_g1(
    const ushort_t* __restrict__ Ah, const ushort_t* __restrict__ Al,
    const unsigned* __restrict__ Wb_, const float* __restrict__ bias,
    ushort_t* __restrict__ Oh, ushort_t* __restrict__ Ol) {
    int wave = threadIdx.x >> 6, lane = threadIdx.x & 63;
    int cg = wave & 1, mg = wave >> 1;
    int rl = lane & 15, gp = lane >> 4;
    u32x4 B[4][4];
    const u32x4* Wb = (const u32x4*)Wb_;
    #pragma unroll
    for (int n = 0; n < 4; ++n)
        #pragma unroll
        for (int kk = 0; kk < 4; ++kk)
            B[n][kk] = Wb[((cg * 4 + n) * 4 + kk) * 64 + lane];
    float bs[4];
    #pragma unroll
    for (int n = 0; n < 4; ++n) bs[n] = bias[cg * 64 + n * 16 + rl];
    for (int it = 0; it < 2; ++it) {
        int cid = (blockIdx.x * 2 + it) * 2 + mg;
        if (cid >= NCHUNK) continue;
        const u32x4* ph = (const u32x4*)(Ah + (size_t)(cid * 16 + rl) * 128 + gp * 8);
        const u32x4* pl = (const u32x4*)(Al + (size_t)(cid * 16 + rl) * 128 + gp * 8);
        bf8 ah[4], al4[4];
        #pragma unroll
        for (int kk = 0; kk < 4; ++kk) {
            ah[kk]  = __builtin_bit_cast(bf8, ph[kk * 4]);
            al4[kk] = __builtin_bit_cast(bf8, pl[kk * 4]);
        }
        f4 acc[4];
        #pragma unroll
        for (int n = 0; n < 4; ++n) acc[n] = (f4)0.f;
        #pragma unroll
        for (int kk = 0; kk < 4; ++kk) {
            #pragma unroll
            for (int n = 0; n < 4; ++n)
                acc[n] = __builtin_amdgcn_mfma_f32_16x16x32_bf16(
                    ah[kk], __builtin_bit_cast(bf8, B[n][kk]), acc[n], 0, 0, 0);
            #pragma unroll
            for (int n = 0; n < 4; ++n)
                acc[n] = __builtin_amdgcn_mfma_f32_16x16x32_bf16(
                    al4[kk], __builtin_bit_cast(bf8, B[n][kk]), acc[n], 0, 0, 0);
        }
        #pragma unroll
        for (int n = 0; n < 4; ++n)
            #pragma unroll
            for (int t = 0; t < 4; ++t) {
                float v = tanh_fast(acc[n][t] + bs[n]);
                unsigned hi = f2bf(v);
                int node = cid * 16 + gp * 4 + t;
                int col = cg * 64 + n * 16 + rl;
                Oh[(size_t)node * 128 + col] = (ushort_t)hi;
                Ol[(size_t)node * 128 + col] = (ushort_t)f2bf(v - bf2f(hi));
            }
    }
}

// ---------------- G2: [P|Q] = x3 @ Wpq (+bd0), bf16 out -----------------------
__global__ __launch_bounds__(256) void k_g2(
    const ushort_t* __restrict__ Ah, const ushort_t* __restrict__ Al,
    const unsigned* __restrict__ Wb_, const float* __restrict__ bd0,
    ushort_t* __restrict__ P16, ushort_t* __restrict__ Q16) {
    int cg = threadIdx.x >> 6, lane = threadIdx.x & 63;
    int rl = lane & 15, gp = lane >> 4;
    u32x4 B[4][4];
    const u32x4* Wb = (const u32x4*)Wb_;
    #pragma unroll
    for (int n = 0; n < 4; ++n)
        #pragma unroll
        for (int kk = 0; kk < 4; ++kk)
            B[n][kk] = Wb[((cg * 4 + n) * 4 + kk) * 64 + lane];
    float bs[4];
    #pragma unroll
    for (int n = 0; n < 4; ++n) {
        int j = cg * 64 + n * 16 + rl;
        bs[n] = (j < 128) ? bd0[j] : 0.f;
    }
    for (int it = 0; it < 2; ++it) {
        int cid = blockIdx.x * 2 + it;
        if (cid >= NCHUNK) continue;
        const u32x4* ph = (const u32x4*)(Ah + (size_t)(cid * 16 + rl) * 128 + gp * 8);
        const u32x4* pl = (const u32x4*)(Al + (size_t)(cid * 16 + rl) * 128 + gp * 8);
        bf8 ah[4], al4[4];
        #pragma unroll
        for (int kk = 0; kk < 4; ++kk) {
            ah[kk]  = __builtin_bit_cast(bf8, ph[kk * 4]);
            al4[kk] = __builtin_bit_cast(bf8, pl[kk * 4]);
        }
        f4 acc[4];
        #pragma unroll
        for (int n = 0; n < 4; ++n) acc[n] = (f4)0.f;
        #pragma unroll
        for (int kk = 0; kk < 4; ++kk) {
            #pragma unroll
            for (int n = 0; n < 4; ++n)
                acc[n] = __builtin_amdgcn_mfma_f32_16x16x32_bf16(
                    ah[kk], __builtin_bit_cast(bf8, B[n][kk]), acc[n], 0, 0, 0);
            #pragma unroll
            for (int n = 0; n < 4; ++n)
                acc[n] = __builtin_amdgcn_mfma_f32_16x16x32_bf16(
                    al4[kk], __builtin_bit_cast(bf8, B[n][kk]), acc[n], 0, 0, 0);
        }
        #pragma unroll
        for (int n = 0; n < 4; ++n) {
            int j = cg * 64 + n * 16 + rl;
            #pragma unroll
            for (int t = 0; t < 4; ++t) {
                float v = acc[n][t] + bs[n];
                int node = cid * 16 + gp * 4 + t;
                if (j < 128) P16[(size_t)node * 128 + j] = (ushort_t)f2bf(v);
                else         Q16[(size_t)node * 128 + (j - 128)] = (ushort_t)f2bf(v);
            }
        }
    }
}

// ---------------- h0 stats: N_G*16, j<2, LDS block-reduce, XCD-swizzled -------
__global__ __launch_bounds__(256, 1) void k_h0s(
    const int* __restrict__ edges, const float* __restrict__ ea,
    const ushort_t* __restrict__ P16, const ushort_t* __restrict__ Q16,
    const float* __restrict__ Wd0, float* __restrict__ part0) {
    __shared__ float ls[2][4][128];
    int vb = xcd_swz(blockIdx.x, gridDim.x);
    int g = vb >> 4, tb = vb & 15;
    int wave = threadIdx.x >> 6, lane = threadIdx.x & 63;
    int row = lane & 15, grp = lane >> 4;
    int slot = tb * 4 + wave;
    f4 wmr[4][2];
    #pragma unroll
    for (int kk = 0; kk < 4; ++kk) {
        const f4* wmp = (const f4*)(Wd0 + 16384 + kk * 32 + grp * 8);
        wmr[kk][0] = wmp[0]; wmr[kk][1] = wmp[1];
    }
    f4 s[4][2], q[4][2];
    #pragma unroll
    for (int kk = 0; kk < 4; ++kk)
        #pragma unroll
        for (int h = 0; h < 2; ++h) { s[kk][h] = (f4)0.f; q[kk][h] = (f4)0.f; }

    for (int j = 0; j < 2; ++j) {
        int tile = slot + 64 * j;
        if (tile >= 125) break;
        int eg0 = g * EPG + tile * 32;
        #pragma unroll
        for (int m = 0; m < 2; ++m) {
            int e = eg0 + 16 * m + row;
            int sn = edges[e], dn = edges[N_EDGES + e];
            float w = ea[2 * e];
            const u32x4* Pr = (const u32x4*)(P16 + (size_t)sn * 128);
            const u32x4* Qr = (const u32x4*)(Q16 + (size_t)dn * 128);
            #pragma unroll
            for (int kk = 0; kk < 4; ++kk) {
                f4 p0, p1, q0, q1;
                unp8(Pr[kk * 4 + grp], p0, p1);
                unp8(Qr[kk * 4 + grp], q0, q1);
                #pragma unroll
                for (int r = 0; r < 4; ++r) {
                    float h0 = tanh_fast(p0[r] + q0[r] + w * wmr[kk][0][r]);
                    float h1 = tanh_fast(p1[r] + q1[r] + w * wmr[kk][1][r]);
                    s[kk][0][r] += h0; q[kk][0][r] += h0 * h0;
                    s[kk][1][r] += h1; q[kk][1][r] += h1 * h1;
                }
            }
        }
    }
    #pragma unroll
    for (int kk = 0; kk < 4; ++kk)
        #pragma unroll
        for (int h = 0; h < 2; ++h)
            #pragma unroll
            for (int r = 0; r < 4; ++r) {
                float sv = s[kk][h][r], qv = q[kk][h][r];
                sv += __shfl_xor(sv, 1); sv += __shfl_xor(sv, 2);
                sv += __shfl_xor(sv, 4); sv += __shfl_xor(sv, 8);
                qv += __shfl_xor(qv, 1); qv += __shfl_xor(qv, 2);
                qv += __shfl_xor(qv, 4); qv += __shfl_xor(qv, 8);
                if (row == 0) {
                    int k = kk * 32 + grp * 8 + h * 4 + r;
                    ls[0][wave][k] = sv;
                    ls[1][wave][k] = qv;
                }
            }
    __syncthreads();
    int st = threadIdx.x >> 7, k = threadIdx.x & 127;
    float v = ls[st][0][k] + ls[st][1][k] + ls[st][2][k] + ls[st][3][k];
    part0[((size_t)(g * 16 + tb) * 2 + st) * 128 + k] = v;
}

// ---------------- fold gnorm0 (sums 16 partials) -> W1b + gam -----------------
__global__ __launch_bounds__(256) void k_fin0(
    const float* __restrict__ part0,
    const float* __restrict__ gnw, const float* __restrict__ gnb, const float* __restrict__ gnms,
    const float* __restrict__ Wd1, const float* __restrict__ bd1,
    unsigned* __restrict__ W1b, float* __restrict__ gam) {
    int g = blockIdx.x;
    __shared__ float al[128], be[128];
    if (threadIdx.x < 128) {
        int k = threadIdx.x;
        float S = 0.f, Q = 0.f;
        #pragma unroll
        for (int tb = 0; tb < 16; ++tb) {
            S += part0[((size_t)(g * 16 + tb) * 2 + 0) * 128 + k];
            Q += part0[((size_t)(g * 16 + tb) * 2 + 1) * 128 + k];
        }
        float mean = S * (1.f / EPG);
        float t = mean * gnms[k];
        float var = (Q - 2.f * t * S) * (1.f / EPG) + t * t;
        float a = gnw[k] * rsqrtf(var + 1e-5f);
        al[k] = a;
        be[k] = gnb[k] - a * t;
    }
    __syncthreads();
    unsigned* Wb = W1b + (size_t)g * 4096;
    for (int i = threadIdx.x; i < 4096; i += 256) {
        int t = i & 3, l = (i >> 2) & 63, kk = (i >> 8) & 3, n = i >> 10;
        int k = kk * 32 + ((l >> 4) << 3) + 2 * t;
        int j = 16 * n + (l & 15);
        unsigned lo = f2bf(al[k] * Wd1[k * 64 + j]);
        unsigned hi = f2bf(al[k + 1] * Wd1[(k + 1) * 64 + j]);
        Wb[i] = lo | (hi << 16);
    }
    if (threadIdx.x < 64) {
        int j = threadIdx.x;
        float acc = bd1[j];
        #pragma unroll 8
        for (int k = 0; k < 128; ++k) acc += be[k] * Wd1[k * 64 + j];
        gam[g * 64 + j] = acc;
    }
}

// ---------------- h1 pass: N_G*16, j<2, XCD-swizzled; stats(+h1 store) --------
template<int DO_VALS, int STORE>
__global__ __launch_bounds__(256, 1) void k_h1m(
    const int* __restrict__ edges, const float* __restrict__ ea,
    const ushort_t* __restrict__ P16, const ushort_t* __restrict__ Q16,
    const float* __restrict__ Wd0,
    const unsigned* __restrict__ W1b, const float* __restrict__ gam,
    const float* __restrict__ ug, const float* __restrict__ cg,
    float* __restrict__ part1,
    float* __restrict__ vals, float* __restrict__ outp, unsigned* __restrict__ h1ff) {
    __shared__ float ls[2][4][64];
    int vb = xcd_swz(blockIdx.x, gridDim.x);
    int g = vb >> 4, tb = vb & 15;
    int wave = threadIdx.x >> 6, lane = threadIdx.x & 63;
    int col = lane & 15, grp = lane >> 4;
    int slot = tb * 4 + wave;

    bf8 bfr[4][4];
    {
        const u32x4* Wb = (const u32x4*)(W1b + (size_t)g * 4096);
        #pragma unroll
        for (int n = 0; n < 4; ++n)
            #pragma unroll
            for (int kk = 0; kk < 4; ++kk)
                bfr[n][kk] = __builtin_bit_cast(bf8, Wb[(n * 4 + kk) * 64 + lane]);
    }
    f4 wmr[4][2];
    #pragma unroll
    for (int kk = 0; kk < 4; ++kk) {
        const f4* wmp = (const f4*)(Wd0 + 16384 + kk * 32 + grp * 8);
        wmr[kk][0] = wmp[0]; wmr[kk][1] = wmp[1];
    }
    float gamn[4], un[4] = {0.f, 0.f, 0.f, 0.f};
    #pragma unroll
    for (int n = 0; n < 4; ++n) gamn[n] = gam[g * 64 + 16 * n + col];
    float cgv = 0.f;
    if (DO_VALS) {
        #pragma unroll
        for (int n = 0; n < 4; ++n) un[n] = ug[g * 64 + 16 * n + col];
        cgv = cg[g];
    }
    float sacc[4] = {0.f, 0.f, 0.f, 0.f}, qacc[4] = {0.f, 0.f, 0.f, 0.f};

    for (int j = 0; j < 2; ++j) {
        int tile = slot + 64 * j;
        if (tile >= 125) break;
        int eg0 = g * EPG + tile * 32;
        bf8 af[2][4];
        #pragma unroll
        for (int m = 0; m < 2; ++m) {
            int e = eg0 + 16 * m + col;
            int sn = edges[e], dn = edges[N_EDGES + e];
            float w = ea[2 * e];
            const u32x4* Pr = (const u32x4*)(P16 + (size_t)sn * 128);
            const u32x4* Qr = (const u32x4*)(Q16 + (size_t)dn * 128);
            #pragma unroll
            for (int kk = 0; kk < 4; ++kk) {
                f4 p0, p1, q0, q1;
                unp8(Pr[kk * 4 + grp], p0, p1);
                unp8(Qr[kk * 4 + grp], q0, q1);
                bf8 a;
                #pragma unroll
                for (int r = 0; r < 4; ++r) {
                    float h0 = tanh_fast(p0[r] + q0[r] + w * wmr[kk][0][r]);
                    float h1 = tanh_fast(p1[r] + q1[r] + w * wmr[kk][1][r]);
                    a[r]     = (short)f2bf(h0);
                    a[4 + r] = (short)f2bf(h1);
                }
                af[m][kk] = a;
            }
        }
        f4 acc[2][4];
        #pragma unroll
        for (int m = 0; m < 2; ++m)
            #pragma unroll
            for (int n = 0; n < 4; ++n) acc[m][n] = (f4)0.f;
        #pragma unroll
        for (int kk = 0; kk < 4; ++kk)
            #pragma unroll
            for (int m = 0; m < 2; ++m)
                #pragma unroll
                for (int n = 0; n < 4; ++n)
                    acc[m][n] = __builtin_amdgcn_mfma_f32_16x16x32_bf16(
                        af[m][kk], bfr[n][kk], acc[m][n], 0, 0, 0);

        if (DO_VALS) {
            float rp[2][4];
            #pragma unroll
            for (int m = 0; m < 2; ++m)
                #pragma unroll
                for (int t = 0; t < 4; ++t) {
                    float v = 0.f;
                    #pragma unroll
                    for (int n = 0; n < 4; ++n)
                        v += un[n] * tanh_fast(acc[m][n][t] + gamn[n]);
                    v += __shfl_xor(v, 1); v += __shfl_xor(v, 2);
                    v += __shfl_xor(v, 4); v += __shfl_xor(v, 8);
                    rp[m][t] = v + cgv;
                }
            if (col == 0) {
                #pragma unroll
                for (int m = 0; m < 2; ++m)
                    #pragma unroll
                    for (int pr = 0; pr < 2; ++pr) {
                        float va = rp[m][2 * pr], vb2 = rp[m][2 * pr + 1];
                        int p = ((eg0 + 16 * m + grp * 4) >> 1) + pr;
                        vals[p] = fminf(va, vb2);
                        outp[600000 + p] = (vb2 < va) ? 1.f : 0.f;
                        int e = 2 * p;
                        outp[p]          = (float)edges[e];
                        outp[200000 + p] = (float)edges[N_EDGES + e];
                    }
            }
        } else {
            int tileG = g * 125 + tile;
            #pragma unroll
            for (int m = 0; m < 2; ++m)
                #pragma unroll
                for (int n = 0; n < 4; ++n) {
                    float h[4];
                    #pragma unroll
                    for (int t = 0; t < 4; ++t) {
                        h[t] = tanh_fast(acc[m][n][t] + gamn[n]);
                        sacc[n] += h[t]; qacc[n] += h[t] * h[t];
                    }
                    if (STORE) {
                        unsigned w0 = f2bf(h[0]) | (f2bf(h[1]) << 16);
                        unsigned w1 = f2bf(h[2]) | (f2bf(h[3]) << 16);
                        size_t base = ((size_t)(tileG * 2 + m) * 4 + n) * 2;
                        h1ff[(base + 0) * 64 + lane] = w0;
                        h1ff[(base + 1) * 64 + lane] = w1;
                    }
                }
        }
    }
    if (!DO_VALS) {
        #pragma unroll
        for (int n = 0; n < 4; ++n) {
            float s = sacc[n], q = qacc[n];
            s += __shfl_xor(s, 16); s += __shfl_xor(s, 32);
            q += __shfl_xor(q, 16); q += __shfl_xor(q, 32);
            if (lane < 16) {
                ls[0][wave][n * 16 + col] = s;
                ls[1][wave][n * 16 + col] = q;
            }
        }
        __syncthreads();
        if (threadIdx.x < 128) {
            int st = threadIdx.x >> 6, k = threadIdx.x & 63;
            float v = ls[st][0][k] + ls[st][1][k] + ls[st][2][k] + ls[st][3][k];
            part1[((size_t)(g * 16 + tb) * 2 + st) * 64 + k] = v;
        }
    }
}

// ---------------- vals pass: read h1ff, dot, pair-min -------------------------
__global__ __launch_bounds__(256) void k_vals(
    const int* __restrict__ edges, const unsigned* __restrict__ h1ff,
    const float* __restrict__ ug, const float* __restrict__ cg,
    float* __restrict__ vals, float* __restrict__ outp) {
    int g = blockIdx.x >> 4, tb = blockIdx.x & 15;
    int wave = threadIdx.x >> 6, lane = threadIdx.x & 63;
    int col = lane & 15, grp = lane >> 4;
    int slot = tb * 4 + wave;
    float un[4];
    #pragma unroll
    for (int n = 0; n < 4; ++n) un[n] = ug[g * 64 + 16 * n + col];
    float cgv = cg[g];
    for (int j = 0; j < 2; ++j) {
        int tile = slot + 64 * j;
        if (tile >= 125) break;
        int tileG = g * 125 + tile;
        int eg0 = g * EPG + tile * 32;
        #pragma unroll
        for (int m = 0; m < 2; ++m) {
            float v[4] = {0.f, 0.f, 0.f, 0.f};
            #pragma unroll
            for (int n = 0; n < 4; ++n) {
                size_t base = ((size_t)(tileG * 2 + m) * 4 + n) * 2;
                unsigned w0 = h1ff[(base + 0) * 64 + lane];
                unsigned w1 = h1ff[(base + 1) * 64 + lane];
                v[0] += un[n] * bf2f(w0 & 0xFFFFu);
                v[1] += un[n] * bf2f(w0 >> 16);
                v[2] += un[n] * bf2f(w1 & 0xFFFFu);
                v[3] += un[n] * bf2f(w1 >> 16);
            }
            float rp[4];
            #pragma unroll
            for (int t = 0; t < 4; ++t) {
                float vv = v[t];
                vv += __shfl_xor(vv, 1); vv += __shfl_xor(vv, 2);
                vv += __shfl_xor(vv, 4); vv += __shfl_xor(vv, 8);
                rp[t] = vv + cgv;
            }
            if (col == 0) {
                #pragma unroll
                for (int pr = 0; pr < 2; ++pr) {
                    float va = rp[2 * pr], vb = rp[2 * pr + 1];
                    int p = ((eg0 + 16 * m + grp * 4) >> 1) + pr;
                    vals[p] = fminf(va, vb);
                    outp[600000 + p] = (vb < va) ? 1.f : 0.f;
                    int e = 2 * p;
                    outp[p]          = (float)edges[e];
                    outp[200000 + p] = (float)edges[N_EDGES + e];
                }
            }
        }
    }
}

// ---------------- fold gnorm1 (sums 16 partials) into Wout --------------------
__global__ void k_fin1(const float* __restrict__ part1,
                       const float* __restrict__ gnw, const float* __restrict__ gnb,
                       const float* __restrict__ gnms,
                       const float* __restrict__ Wout, const float* __restrict__ bout,
                       float* __restrict__ ug, float* __restrict__ cg) {
    int g = blockIdx.x; int j = threadIdx.x;  // 64 threads
    float S = 0.f, Q = 0.f;
    #pragma unroll
    for (int tb = 0; tb < 16; ++tb) {
        S += part1[((size_t)(g * 16 + tb) * 2 + 0) * 64 + j];
        Q += part1[((size_t)(g * 16 + tb) * 2 + 1) * 64 + j];
    }
    float mean = S * (1.f / EPG);
    float t = mean * gnms[j];
    float var = (Q - 2.f * t * S) * (1.f / EPG) + t * t;
    float a = gnw[j] * rsqrtf(var + 1e-5f);
    float b = gnb[j] - a * t;
    ug[g * 64 + j] = a * Wout[j];
    float c = b * Wout[j];
    #pragma unroll
    for (int off = 32; off; off >>= 1) c += __shfl_xor(c, off);
    if (j == 0) cg[g] = c + bout[0];
}

// ---------------- per-graph softmax -------------------------------------------
__global__ __launch_bounds__(256) void k_softmax(const float* __restrict__ vals,
                                                 float* __restrict__ outp) {
    int g = blockIdx.x;
    __shared__ float rbuf[4], rbuf2[4];
    int t = threadIdx.x;
    const float* v = vals + g * PPG;
    float mx = -1e30f;
    for (int i = t; i < PPG; i += 256) mx = fmaxf(mx, v[i]);
    #pragma unroll
    for (int off = 32; off; off >>= 1) mx = fmaxf(mx, __shfl_xor(mx, off));
    if ((t & 63) == 0) rbuf[t >> 6] = mx;
    __syncthreads();
    mx = fmaxf(fmaxf(rbuf[0], rbuf[1]), fmaxf(rbuf[2], rbuf[3]));
    float sm = 0.f;
    for (int i = t; i < PPG; i += 256) sm += expf(v[i] - mx);
    #pragma unroll
    for (int off = 32; off; off >>= 1) sm += __shfl_xor(sm, off);
    if ((t & 63) == 0) rbuf2[t >> 6] = sm;
    __syncthreads();
    sm = rbuf2[0] + rbuf2[1] + rbuf2[2] + rbuf2[3];
    for (int i = t; i < PPG; i += 256)
        outp[400000 + g * PPG + i] = expf(v[i] - mx) / (sm + 1e-16f);
}

extern "C" void kernel_launch(void* const* d_in, const int* in_sizes, int n_in,
                              void* d_out, int out_size, void* d_ws, size_t ws_size,
                              hipStream_t stream) {
    const float* x     = (const float*)d_in[0];
    const int*   edges = (const int*)d_in[1];
    const float* ea    = (const float*)d_in[2];
    const float* Wrel0 = (const float*)d_in[6],  *brel0 = (const float*)d_in[7],  *Wroot0 = (const float*)d_in[8];
    const float* Wrel1 = (const float*)d_in[9],  *brel1 = (const float*)d_in[10], *Wroot1 = (const float*)d_in[11];
    const float* Wrel2 = (const float*)d_in[12], *brel2 = (const float*)d_in[13], *Wroot2 = (const float*)d_in[14];
    const float* Wd0 = (const float*)d_in[15],  *bd0 = (const float*)d_in[16];
    const float* gnw0 = (const float*)d_in[17], *gnb0 = (const float*)d_in[18], *gnms0 = (const float*)d_in[19];
    const float* Wd1 = (const float*)d_in[20],  *bd1 = (const float*)d_in[21];
    const float* gnw1 = (const float*)d_in[22], *gnb1 = (const float*)d_in[23], *gnms1 = (const float*)d_in[24];
    const float* Wout = (const float*)d_in[25], *bout = (const float*)d_in[26];
    float* o = (float*)d_out;
    float* w = (float*)d_ws;

    // region A [0, 8.25M): early node tensors -> x3 planes
    float* agg5 = w;
    float* x1   = w + 250000;
    float* x2   = w + 1850000;
    ushort_t* c2h = (ushort_t*)(w + 5050000);
    ushort_t* c2l = (ushort_t*)(w + 6650000);
    ushort_t* x3h = (ushort_t*)(w + 0);
    ushort_t* x3l = (ushort_t*)(w + 3200000);
    // region B [8.25M, 21.05M): cat planes -> P16|Q16 (bf16)
    ushort_t* cath = (ushort_t*)(w + 8250000);
    ushort_t* catl = (ushort_t*)(w + 11450000);
    ushort_t* P16  = (ushort_t*)(w + 8250000);
    ushort_t* Q16  = (ushort_t*)(w + 11450000);
    // tail [21.05M, ~22.9M)
    float* tail = w + 21050000;
    unsigned* Wcb  = (unsigned*)tail;
    unsigned* Wpqb = Wcb + 8192;
    unsigned* W2b  = Wpqb + 16384;
    int* cnt   = (int*)(W2b + 2048);
    int* fillc = cnt + 50000;
    int* offs  = fillc + 50000;
    int* esrc  = offs + 50000;
    float* ew  = (float*)(esrc + 200000);
    unsigned* W1b = (unsigned*)(ew + 200000);
    float* gam = (float*)(W1b + 409600);
    float* ug  = gam + 6400;
    float* cg  = ug + 6400;
    float* vals = cg + 100;
    float* part0 = vals + 200000;                  // 409600
    float* part1 = part0 + 409600;                 // 204800
    unsigned* h1ff = (unsigned*)(w + 25600000);
    const bool haveH1 = ws_size >= 155000000ULL;

    hipMemsetAsync(cnt, 0, 100000 * sizeof(int), stream);

    k_packAll<<<104, 256, 0, stream>>>(Wrel2, Wroot2, Wd0, Wrel1, Wroot1, Wcb, Wpqb, W2b);

    k_csr_count<<<782, 256, 0, stream>>>(edges, cnt);
    k_csr_scan<<<N_G, 512, 0, stream>>>(cnt, offs);
    k_csr_fill<<<782, 256, 0, stream>>>(edges, ea, offs, fillc, esrc, ew);

    k_gath5<<<1563, 256, 0, stream>>>(cnt, offs, esrc, ew, x, agg5);
    k_dense1<<<6250, 256, 0, stream>>>(x, agg5, Wrel0, brel0, Wroot0, x1, c2h, c2l);
    k_gath32<<<6250, 256, 0, stream>>>(cnt, offs, esrc, ew, x1, c2h, c2l);
    k_g1b<<<782, 256, 0, stream>>>(c2h, c2l, W2b, brel1, x2, cath, catl);
    k_gath64<<<12500, 256, 0, stream>>>(cnt, offs, esrc, ew, x2, cath, catl);

    k_g1<<<(NCHUNK + 3) / 4, 256, 0, stream>>>(cath, catl, Wcb, brel2, x3h, x3l);
    k_g2<<<(NCHUNK + 1) / 2, 256, 0, stream>>>(x3h, x3l, Wpqb, bd0, P16, Q16);

    k_h0s<<<N_G * 16, 256, 0, stream>>>(edges, ea, P16, Q16, Wd0, part0);
    k_fin0<<<N_G, 256, 0, stream>>>(part0, gnw0, gnb0, gnms0, Wd1, bd1, W1b, gam);

    if (haveH1) {
        k_h1m<0, 1><<<N_G * 16, 256, 0, stream>>>(edges, ea, P16, Q16, Wd0, W1b, gam,
                                                  ug, cg, part1, vals, o, h1ff);
        k_fin1<<<N_G, 64, 0, stream>>>(part1, gnw1, gnb1, gnms1, Wout, bout, ug, cg);
        k_vals<<<N_G * 16, 256, 0, stream>>>(edges, h1ff, ug, cg, vals, o);
    } else {
        k_h1m<0, 0><<<N_G * 16, 256, 0, stream>>>(edges, ea, P16, Q16, Wd0, W1b, gam,
                                                  ug, cg, part1, vals, o, h1ff);
        k_fin1<<<N_G, 64, 0, stream>>>(part1, gnw1, gnb1, gnms1, Wout, bout, ug, cg);
        k_h1m<1, 0><<<N_G * 16, 256, 0, stream>>>(edges, ea, P16, Q16, Wd0, W1b, gam,
                                                  ug, cg, part1, vals, o, h1ff);
    }

    k_softmax<<<N_G, 256, 0, stream>>>(vals, o);
}

// Round 12
// 355.798 us; speedup vs baseline: 1.3816x; 1.0474x over previous
//
#include <hip/hip_runtime.h>

// GraphNN R12: R11 + on the edge passes:
//  - k_h1m: W1b frags in LDS (-64 VGPR), nontemporal h1ff stores (no L2 thrash),
//    edge-index prefetch (unrolled j, static idx);
//  - k_h0s: edge-index prefetch;  - k_vals: nontemporal h1ff loads.

#define N_NODES 50000
#define N_EDGES 400000
#define N_PAIRS 200000
#define N_G     100
#define EPG     4000
#define PPG     2000
#define NCHUNK  3125   // 50000/16

typedef float  f4   __attribute__((ext_vector_type(4)));
typedef short  bf8  __attribute__((ext_vector_type(8)));
typedef unsigned u32x4 __attribute__((ext_vector_type(4)));
typedef unsigned short ushort_t;

__device__ __forceinline__ float tanh_fast(float x) {
    float cx = fminf(15.f, fmaxf(-15.f, x));
    float e = __expf(2.f * cx);
    return (e - 1.f) * __builtin_amdgcn_rcpf(e + 1.f);
}
__device__ __forceinline__ unsigned f2bf(float f) {   // RNE fp32->bf16
    unsigned u = __float_as_uint(f);
    return (u + 0x7FFFu + ((u >> 16) & 1u)) >> 16;
}
__device__ __forceinline__ float bf2f(unsigned h) { return __uint_as_float(h << 16); }
__device__ __forceinline__ void unp8(u32x4 v, f4& a, f4& b) {  // 8 bf16 -> 2xf4
    a[0] = bf2f(v[0] & 0xFFFFu); a[1] = bf2f(v[0] >> 16);
    a[2] = bf2f(v[1] & 0xFFFFu); a[3] = bf2f(v[1] >> 16);
    b[0] = bf2f(v[2] & 0xFFFFu); b[1] = bf2f(v[2] >> 16);
    b[2] = bf2f(v[3] & 0xFFFFu); b[3] = bf2f(v[3] >> 16);
}
// bijective XCD swizzle (m204 form)
__device__ __forceinline__ int xcd_swz(int bid, int nwg) {
    int xcd = bid & 7, loc = bid >> 3;
    int q = nwg >> 3, r = nwg & 7;
    return (xcd < r ? xcd * (q + 1) : r * (q + 1) + (xcd - r) * q) + loc;
}

// ---------------- CSR build ---------------------------------------------------
__global__ void k_csr_count(const int* __restrict__ edges, int* __restrict__ cnt) {
    int p = blockIdx.x * 256 + threadIdx.x;
    if (p >= N_PAIRS) return;
    atomicAdd(&cnt[edges[N_EDGES + 2 * p]], 1);
}
__global__ __launch_bounds__(512) void k_csr_scan(const int* __restrict__ cnt,
                                                  int* __restrict__ offs) {
    __shared__ int s[512];
    int g = blockIdx.x, t = threadIdx.x;
    int v = (t < 500) ? cnt[g * 500 + t] : 0;
    s[t] = v; __syncthreads();
    for (int off = 1; off < 512; off <<= 1) {
        int a = (t >= off) ? s[t - off] : 0;
        __syncthreads();
        s[t] += a; __syncthreads();
    }
    if (t < 500) offs[g * 500 + t] = g * PPG + s[t] - v;
}
__global__ void k_csr_fill(const int* __restrict__ edges, const float* __restrict__ ea,
                           const int* __restrict__ offs, int* __restrict__ fillc,
                           int* __restrict__ esrc, float* __restrict__ ew) {
    int p = blockIdx.x * 256 + threadIdx.x;
    if (p >= N_PAIRS) return;
    int d = edges[N_EDGES + 2 * p];
    int pos = offs[d] + atomicAdd(&fillc[d], 1);
    esrc[pos] = edges[2 * p];
    ew[pos] = ea[4 * p] + ea[4 * p + 2];
}

// ---------------- gathers -----------------------------------------------------
__global__ __launch_bounds__(256) void k_gath5(
    const int* __restrict__ cnt, const int* __restrict__ offs,
    const int* __restrict__ esrc, const float* __restrict__ ew,
    const float* __restrict__ x, float* __restrict__ agg) {
    int t = blockIdx.x * 256 + threadIdx.x;
    int n = t >> 3, k = t & 7;
    if (n >= N_NODES || k >= 5) return;
    int o0 = offs[n], c = cnt[n];
    float acc = 0.f;
    for (int i = o0; i < o0 + c; ++i) acc += x[esrc[i] * 5 + k] * ew[i];
    agg[n * 5 + k] = acc;
}
__global__ __launch_bounds__(256) void k_gath32(
    const int* __restrict__ cnt, const int* __restrict__ offs,
    const int* __restrict__ esrc, const float* __restrict__ ew,
    const float* __restrict__ x1, ushort_t* __restrict__ c2h, ushort_t* __restrict__ c2l) {
    int vb = xcd_swz(blockIdx.x, gridDim.x);
    int n = vb * 8 + (threadIdx.x >> 5), k = threadIdx.x & 31;
    if (n >= N_NODES) return;
    int o0 = offs[n], c = cnt[n];
    float acc = 0.f;
    for (int i = o0; i < o0 + c; ++i) acc += x1[esrc[i] * 32 + k] * ew[i];
    unsigned hi = f2bf(acc);
    size_t o = (size_t)n * 64 + k;
    c2h[o] = (ushort_t)hi;
    c2l[o] = (ushort_t)f2bf(acc - bf2f(hi));
}
__global__ __launch_bounds__(256) void k_gath64(
    const int* __restrict__ cnt, const int* __restrict__ offs,
    const int* __restrict__ esrc, const float* __restrict__ ew,
    const float* __restrict__ x2, ushort_t* __restrict__ ch, ushort_t* __restrict__ cl) {
    int vb = xcd_swz(blockIdx.x, gridDim.x);
    int n = vb * 4 + (threadIdx.x >> 6), k = threadIdx.x & 63;
    if (n >= N_NODES) return;
    int o0 = offs[n], c = cnt[n];
    float acc = 0.f;
    for (int i = o0; i < o0 + c; ++i) acc += x2[esrc[i] * 64 + k] * ew[i];
    unsigned hi = f2bf(acc);
    size_t o = (size_t)n * 128 + k;
    ch[o] = (ushort_t)hi;
    cl[o] = (ushort_t)f2bf(acc - bf2f(hi));
}

// ---------------- layer1 dense 5->32 ------------------------------------------
__global__ __launch_bounds__(256) void k_dense1(
    const float* __restrict__ x, const float* __restrict__ agg,
    const float* __restrict__ Wrel, const float* __restrict__ brel,
    const float* __restrict__ Wroot, float* __restrict__ x1,
    ushort_t* __restrict__ c2h, ushort_t* __restrict__ c2l) {
    __shared__ float wr[160], wt[160], bb[32];
    __shared__ float sa[8][5], sx[8][5];
    for (int i = threadIdx.x; i < 160; i += 256) { wr[i] = Wrel[i]; wt[i] = Wroot[i]; }
    if (threadIdx.x < 32) bb[threadIdx.x] = brel[threadIdx.x];
    int j = threadIdx.x & 31, nl = threadIdx.x >> 5;
    int nb = blockIdx.x * 8;
    __syncthreads();
    for (int i = threadIdx.x; i < 40; i += 256) {
        int nn = nb + i / 5, kk = i % 5;
        float av = 0.f, xv = 0.f;
        if (nn < N_NODES) { av = agg[nn * 5 + kk]; xv = x[nn * 5 + kk]; }
        sa[i / 5][kk] = av; sx[i / 5][kk] = xv;
    }
    __syncthreads();
    int n = nb + nl;
    if (n < N_NODES) {
        float acc = bb[j];
        #pragma unroll
        for (int k = 0; k < 5; ++k)
            acc += sa[nl][k] * wr[k * 32 + j] + sx[nl][k] * wt[k * 32 + j];
        float v = tanhf(acc);
        x1[n * 32 + j] = v;
        unsigned hi = f2bf(v);
        size_t o = (size_t)n * 64 + 32 + j;
        c2h[o] = (ushort_t)hi;
        c2l[o] = (ushort_t)f2bf(v - bf2f(hi));
    }
}

// ---------------- merged weight frag packer -----------------------------------
__global__ void k_packAll(const float* __restrict__ Wrel2, const float* __restrict__ Wroot2,
                          const float* __restrict__ Wd0,
                          const float* __restrict__ Wrel1, const float* __restrict__ Wroot1,
                          unsigned* __restrict__ Wcb, unsigned* __restrict__ Wpqb,
                          unsigned* __restrict__ W2b) {
    int b = blockIdx.x;
    if (b < 32) {
        int i = b * 256 + threadIdx.x;
        int t = i & 3, l = (i >> 2) & 63, kk = (i >> 8) & 3, n = i >> 10;
        int k = kk * 32 + ((l >> 4) << 3) + 2 * t;
        int j = 16 * n + (l & 15);
        float v0 = (k < 64) ? Wrel2[k * 128 + j] : Wroot2[(k - 64) * 128 + j];
        float v1 = (k + 1 < 64) ? Wrel2[(k + 1) * 128 + j] : Wroot2[(k + 1 - 64) * 128 + j];
        Wcb[i] = f2bf(v0) | (f2bf(v1) << 16);
    } else if (b < 96) {
        int i = (b - 32) * 256 + threadIdx.x;
        int t = i & 3, l = (i >> 2) & 63, kk = (i >> 8) & 3, n = i >> 10;
        int k = kk * 32 + ((l >> 4) << 3) + 2 * t;
        int j = 16 * n + (l & 15);
        float v0 = (j < 128) ? Wd0[k * 128 + j] : Wd0[(129 + k) * 128 + (j - 128)];
        float v1 = (j < 128) ? Wd0[(k + 1) * 128 + j] : Wd0[(129 + k + 1) * 128 + (j - 128)];
        Wpqb[i] = f2bf(v0) | (f2bf(v1) << 16);
    } else {
        int i = (b - 96) * 256 + threadIdx.x;
        int t = i & 3, l = (i >> 2) & 63, kk = (i >> 8) & 1, n = i >> 9;
        int k = kk * 32 + ((l >> 4) << 3) + 2 * t;
        int j = 16 * n + (l & 15);
        float v0 = (k < 32) ? Wrel1[k * 64 + j] : Wroot1[(k - 32) * 64 + j];
        float v1 = (k + 1 < 32) ? Wrel1[(k + 1) * 64 + j] : Wroot1[(k + 1 - 32) * 64 + j];
        W2b[i] = f2bf(v0) | (f2bf(v1) << 16);
    }
}

// ---------------- G1b: x2 = tanh(cat2 @ W2 + brel1) ---------------------------
__global__ __launch_bounds__(256) void k_g1b(
    const ushort_t* __restrict__ Ah, const ushort_t* __restrict__ Al,
    const unsigned* __restrict__ Wb_, const float* __restrict__ bias,
    float* __restrict__ x2, ushort_t* __restrict__ ch, ushort_t* __restrict__ cl) {
    int wave = threadIdx.x >> 6, lane = threadIdx.x & 63;
    int rl = lane & 15, gp = lane >> 4;
    int cid = blockIdx.x * 4 + wave;
    if (cid >= NCHUNK) return;
    u32x4 B[4][2];
    const u32x4* Wb = (const u32x4*)Wb_;
    #pragma unroll
    for (int n = 0; n < 4; ++n)
        #pragma unroll
        for (int kk = 0; kk < 2; ++kk)
            B[n][kk] = Wb[(n * 2 + kk) * 64 + lane];
    float bs[4];
    #pragma unroll
    for (int n = 0; n < 4; ++n) bs[n] = bias[n * 16 + rl];
    const u32x4* ph = (const u32x4*)(Ah + (size_t)(cid * 16 + rl) * 64 + gp * 8);
    const u32x4* pl = (const u32x4*)(Al + (size_t)(cid * 16 + rl) * 64 + gp * 8);
    bf8 ah[2], al4[2];
    #pragma unroll
    for (int kk = 0; kk < 2; ++kk) {
        ah[kk]  = __builtin_bit_cast(bf8, ph[kk * 4]);
        al4[kk] = __builtin_bit_cast(bf8, pl[kk * 4]);
    }
    f4 acc[4];
    #pragma unroll
    for (int n = 0; n < 4; ++n) acc[n] = (f4)0.f;
    #pragma unroll
    for (int kk = 0; kk < 2; ++kk) {
        #pragma unroll
        for (int n = 0; n < 4; ++n)
            acc[n] = __builtin_amdgcn_mfma_f32_16x16x32_bf16(
                ah[kk], __builtin_bit_cast(bf8, B[n][kk]), acc[n], 0, 0, 0);
        #pragma unroll
        for (int n = 0; n < 4; ++n)
            acc[n] = __builtin_amdgcn_mfma_f32_16x16x32_bf16(
                al4[kk], __builtin_bit_cast(bf8, B[n][kk]), acc[n], 0, 0, 0);
    }
    #pragma unroll
    for (int n = 0; n < 4; ++n)
        #pragma unroll
        for (int t = 0; t < 4; ++t) {
            float v = tanh_fast(acc[n][t] + bs[n]);
            int node = cid * 16 + gp * 4 + t;
            int col = n * 16 + rl;
            x2[(size_t)node * 64 + col] = v;
            unsigned hi = f2bf(v);
            size_t o = (size_t)node * 128 + 64 + col;
            ch[o] = (ushort_t)hi;
            cl[o] = (ushort_t)f2bf(v - bf2f(hi));
        }
}

// ---------------- G1: x3 = tanh(cat @ Wc + brel2) -----------------------------
__global__ __launch_bounds__(256) void k_g1(
    const ushort_t* __restrict__ Ah, const ushort_t* __restrict__ Al,
    const unsigned* __restrict__ Wb_, const float* __restrict__ bias,
    ushort_t* __restrict__ Oh, ushort_t* __restrict__ Ol) {
    int wave = threadIdx.x >> 6, lane = threadIdx.x & 63;
    int cg = wave & 1, mg = wave >> 1;
    int rl = lane & 15, gp = lane >> 4;
    u32x4 B[4][4];
    const u32x4* Wb = (const u32x4*)Wb_;
    #pragma unroll
    for (int n = 0; n < 4; ++n)
        #pragma unroll
        for (int kk = 0; kk < 4; ++kk)
            B[n][kk] = Wb[((cg * 4 + n) * 4 + kk) * 64 + lane];
    float bs[4];
    #pragma unroll
    for (int n = 0; n < 4; ++n) bs[n] = bias[cg * 64 + n * 16 + rl];
    for (int it = 0; it < 2; ++it) {
        int cid = (blockIdx.x * 2 + it) * 2 + mg;
        if (cid >= NCHUNK) continue;
        const u32x4* ph = (const u32x4*)(Ah + (size_t)(cid * 16 + rl) * 128 + gp * 8);
        const u32x4* pl = (const u32x4*)(Al + (size_t)(cid * 16 + rl) * 128 + gp * 8);
        bf8 ah[4], al4[4];
        #pragma unroll
        for (int kk = 0; kk < 4; ++kk) {
            ah[kk]  = __builtin_bit_cast(bf8, ph[kk * 4]);
            al4[kk] = __builtin_bit_cast(bf8, pl[kk * 4]);
        }
        f4 acc[4];
        #pragma unroll
        for (int n = 0; n < 4; ++n) acc[n] = (f4)0.f;
        #pragma unroll
        for (int kk = 0; kk < 4; ++kk) {
            #pragma unroll
            for (int n = 0; n < 4; ++n)
                acc[n] = __builtin_amdgcn_mfma_f32_16x16x32_bf16(
                    ah[kk], __builtin_bit_cast(bf8, B[n][kk]), acc[n], 0, 0, 0);
            #pragma unroll
            for (int n = 0; n < 4; ++n)
                acc[n] = __builtin_amdgcn_mfma_f32_16x16x32_bf16(
                    al4[kk], __builtin_bit_cast(bf8, B[n][kk]), acc[n], 0, 0, 0);
        }
        #pragma unroll
        for (int n = 0; n < 4; ++n)
            #pragma unroll
            for (int t = 0; t < 4; ++t) {
                float v = tanh_fast(acc[n][t] + bs[n]);
                unsigned hi = f2bf(v);
                int node = cid * 16 + gp * 4 + t;
                int col = cg * 64 + n * 16 + rl;
                Oh[(size_t)node * 128 + col] = (ushort_t)hi;
                Ol[(size_t)node * 128 + col] = (ushort_t)f2bf(v - bf2f(hi));
            }
    }
}

// ---------------- G2: [P|Q] = x3 @ Wpq (+bd0), bf16 out -----------------------
__global__ __launch_bounds__(256) void k_g2(
    const ushort_t* __restrict__ Ah, const ushort_t* __restrict__ Al,
    const unsigned* __restrict__ Wb_, const float* __restrict__ bd0,
    ushort_t* __restrict__ P16, ushort_t* __restrict__ Q16) {
    int cg = threadIdx.x >> 6, lane = threadIdx.x & 63;
    int rl = lane & 15, gp = lane >> 4;
    u32x4 B[4][4];
    const u32x4* Wb = (const u32x4*)Wb_;
    #pragma unroll
    for (int n = 0; n < 4; ++n)
        #pragma unroll
        for (int kk = 0; kk < 4; ++kk)
            B[n][kk] = Wb[((cg * 4 + n) * 4 + kk) * 64 + lane];
    float bs[4];
    #pragma unroll
    for (int n = 0; n < 4; ++n) {
        int j = cg * 64 + n * 16 + rl;
        bs[n] = (j < 128) ? bd0[j] : 0.f;
    }
    for (int it = 0; it < 2; ++it) {
        int cid = blockIdx.x * 2 + it;
        if (cid >= NCHUNK) continue;
        const u32x4* ph = (const u32x4*)(Ah + (size_t)(cid * 16 + rl) * 128 + gp * 8);
        const u32x4* pl = (const u32x4*)(Al + (size_t)(cid * 16 + rl) * 128 + gp * 8);
        bf8 ah[4], al4[4];
        #pragma unroll
        for (int kk = 0; kk < 4; ++kk) {
            ah[kk]  = __builtin_bit_cast(bf8, ph[kk * 4]);
            al4[kk] = __builtin_bit_cast(bf8, pl[kk * 4]);
        }
        f4 acc[4];
        #pragma unroll
        for (int n = 0; n < 4; ++n) acc[n] = (f4)0.f;
        #pragma unroll
        for (int kk = 0; kk < 4; ++kk) {
            #pragma unroll
            for (int n = 0; n < 4; ++n)
                acc[n] = __builtin_amdgcn_mfma_f32_16x16x32_bf16(
                    ah[kk], __builtin_bit_cast(bf8, B[n][kk]), acc[n], 0, 0, 0);
            #pragma unroll
            for (int n = 0; n < 4; ++n)
                acc[n] = __builtin_amdgcn_mfma_f32_16x16x32_bf16(
                    al4[kk], __builtin_bit_cast(bf8, B[n][kk]), acc[n], 0, 0, 0);
        }
        #pragma unroll
        for (int n = 0; n < 4; ++n) {
            int j = cg * 64 + n * 16 + rl;
            #pragma unroll
            for (int t = 0; t < 4; ++t) {
                float v = acc[n][t] + bs[n];
                int node = cid * 16 + gp * 4 + t;
                if (j < 128) P16[(size_t)node * 128 + j] = (ushort_t)f2bf(v);
                else         Q16[(size_t)node * 128 + (j - 128)] = (ushort_t)f2bf(v);
            }
        }
    }
}

// ---------------- h0 stats: N_G*16, unrolled j, edge prefetch -----------------
__global__ __launch_bounds__(256, 1) void k_h0s(
    const int* __restrict__ edges, const float* __restrict__ ea,
    const ushort_t* __restrict__ P16, const ushort_t* __restrict__ Q16,
    const float* __restrict__ Wd0, float* __restrict__ part0) {
    __shared__ float ls[2][4][128];
    int vb = xcd_swz(blockIdx.x, gridDim.x);
    int g = vb >> 4, tb = vb & 15;
    int wave = threadIdx.x >> 6, lane = threadIdx.x & 63;
    int row = lane & 15, grp = lane >> 4;
    int slot = tb * 4 + wave;
    // prefetch edge indices for both tiles (static idx, issued up front)
    int sn2[2][2], dn2[2][2]; float wv2[2][2];
    #pragma unroll
    for (int j = 0; j < 2; ++j) {
        int tile = slot + 64 * j;
        if (tile < 125) {
            int eg0 = g * EPG + tile * 32;
            #pragma unroll
            for (int m = 0; m < 2; ++m) {
                int e = eg0 + 16 * m + row;
                sn2[j][m] = edges[e]; dn2[j][m] = edges[N_EDGES + e]; wv2[j][m] = ea[2 * e];
            }
        } else {
            sn2[j][0] = sn2[j][1] = dn2[j][0] = dn2[j][1] = 0;
            wv2[j][0] = wv2[j][1] = 0.f;
        }
    }
    f4 wmr[4][2];
    #pragma unroll
    for (int kk = 0; kk < 4; ++kk) {
        const f4* wmp = (const f4*)(Wd0 + 16384 + kk * 32 + grp * 8);
        wmr[kk][0] = wmp[0]; wmr[kk][1] = wmp[1];
    }
    f4 s[4][2], q[4][2];
    #pragma unroll
    for (int kk = 0; kk < 4; ++kk)
        #pragma unroll
        for (int h = 0; h < 2; ++h) { s[kk][h] = (f4)0.f; q[kk][h] = (f4)0.f; }

    #pragma unroll
    for (int j = 0; j < 2; ++j) {
        int tile = slot + 64 * j;
        if (tile < 125) {
            #pragma unroll
            for (int m = 0; m < 2; ++m) {
                float w = wv2[j][m];
                const u32x4* Pr = (const u32x4*)(P16 + (size_t)sn2[j][m] * 128);
                const u32x4* Qr = (const u32x4*)(Q16 + (size_t)dn2[j][m] * 128);
                #pragma unroll
                for (int kk = 0; kk < 4; ++kk) {
                    f4 p0, p1, q0, q1;
                    unp8(Pr[kk * 4 + grp], p0, p1);
                    unp8(Qr[kk * 4 + grp], q0, q1);
                    #pragma unroll
                    for (int r = 0; r < 4; ++r) {
                        float h0 = tanh_fast(p0[r] + q0[r] + w * wmr[kk][0][r]);
                        float h1 = tanh_fast(p1[r] + q1[r] + w * wmr[kk][1][r]);
                        s[kk][0][r] += h0; q[kk][0][r] += h0 * h0;
                        s[kk][1][r] += h1; q[kk][1][r] += h1 * h1;
                    }
                }
            }
        }
    }
    #pragma unroll
    for (int kk = 0; kk < 4; ++kk)
        #pragma unroll
        for (int h = 0; h < 2; ++h)
            #pragma unroll
            for (int r = 0; r < 4; ++r) {
                float sv = s[kk][h][r], qv = q[kk][h][r];
                sv += __shfl_xor(sv, 1); sv += __shfl_xor(sv, 2);
                sv += __shfl_xor(sv, 4); sv += __shfl_xor(sv, 8);
                qv += __shfl_xor(qv, 1); qv += __shfl_xor(qv, 2);
                qv += __shfl_xor(qv, 4); qv += __shfl_xor(qv, 8);
                if (row == 0) {
                    int k = kk * 32 + grp * 8 + h * 4 + r;
                    ls[0][wave][k] = sv;
                    ls[1][wave][k] = qv;
                }
            }
    __syncthreads();
    int st = threadIdx.x >> 7, k = threadIdx.x & 127;
    float v = ls[st][0][k] + ls[st][1][k] + ls[st][2][k] + ls[st][3][k];
    part0[((size_t)(g * 16 + tb) * 2 + st) * 128 + k] = v;
}

// ---------------- fold gnorm0 (sums 16 partials) -> W1b + gam -----------------
__global__ __launch_bounds__(256) void k_fin0(
    const float* __restrict__ part0,
    const float* __restrict__ gnw, const float* __restrict__ gnb, const float* __restrict__ gnms,
    const float* __restrict__ Wd1, const float* __restrict__ bd1,
    unsigned* __restrict__ W1b, float* __restrict__ gam) {
    int g = blockIdx.x;
    __shared__ float al[128], be[128];
    if (threadIdx.x < 128) {
        int k = threadIdx.x;
        float S = 0.f, Q = 0.f;
        #pragma unroll
        for (int tb = 0; tb < 16; ++tb) {
            S += part0[((size_t)(g * 16 + tb) * 2 + 0) * 128 + k];
            Q += part0[((size_t)(g * 16 + tb) * 2 + 1) * 128 + k];
        }
        float mean = S * (1.f / EPG);
        float t = mean * gnms[k];
        float var = (Q - 2.f * t * S) * (1.f / EPG) + t * t;
        float a = gnw[k] * rsqrtf(var + 1e-5f);
        al[k] = a;
        be[k] = gnb[k] - a * t;
    }
    __syncthreads();
    unsigned* Wb = W1b + (size_t)g * 4096;
    for (int i = threadIdx.x; i < 4096; i += 256) {
        int t = i & 3, l = (i >> 2) & 63, kk = (i >> 8) & 3, n = i >> 10;
        int k = kk * 32 + ((l >> 4) << 3) + 2 * t;
        int j = 16 * n + (l & 15);
        unsigned lo = f2bf(al[k] * Wd1[k * 64 + j]);
        unsigned hi = f2bf(al[k + 1] * Wd1[(k + 1) * 64 + j]);
        Wb[i] = lo | (hi << 16);
    }
    if (threadIdx.x < 64) {
        int j = threadIdx.x;
        float acc = bd1[j];
        #pragma unroll 8
        for (int k = 0; k < 128; ++k) acc += be[k] * Wd1[k * 64 + j];
        gam[g * 64 + j] = acc;
    }
}

// ---------------- h1 pass: W1b in LDS, nt h1ff stores, edge prefetch ----------
template<int DO_VALS, int STORE>
__global__ __launch_bounds__(256, 1) void k_h1m(
    const int* __restrict__ edges, const float* __restrict__ ea,
    const ushort_t* __restrict__ P16, const ushort_t* __restrict__ Q16,
    const float* __restrict__ Wd0,
    const unsigned* __restrict__ W1b, const float* __restrict__ gam,
    const float* __restrict__ ug, const float* __restrict__ cg,
    float* __restrict__ part1,
    float* __restrict__ vals, float* __restrict__ outp, unsigned* __restrict__ h1ff) {
    __shared__ u32x4 bsh[16][64];     // 16KB: W1b frags (block-uniform graph)
    __shared__ float ls[2][4][64];
    int vb = xcd_swz(blockIdx.x, gridDim.x);
    int g = vb >> 4, tb = vb & 15;
    int wave = threadIdx.x >> 6, lane = threadIdx.x & 63;
    int col = lane & 15, grp = lane >> 4;
    int slot = tb * 4 + wave;

    {   // cooperative load of per-graph weight frags
        const u32x4* Wb = (const u32x4*)(W1b + (size_t)g * 4096);
        u32x4* d = (u32x4*)bsh;
        for (int i = threadIdx.x; i < 1024; i += 256) d[i] = Wb[i];
    }
    // prefetch edge indices for both tiles
    int sn2[2][2], dn2[2][2]; float wv2[2][2];
    #pragma unroll
    for (int j = 0; j < 2; ++j) {
        int tile = slot + 64 * j;
        if (tile < 125) {
            int eg0 = g * EPG + tile * 32;
            #pragma unroll
            for (int m = 0; m < 2; ++m) {
                int e = eg0 + 16 * m + col;
                sn2[j][m] = edges[e]; dn2[j][m] = edges[N_EDGES + e]; wv2[j][m] = ea[2 * e];
            }
        } else {
            sn2[j][0] = sn2[j][1] = dn2[j][0] = dn2[j][1] = 0;
            wv2[j][0] = wv2[j][1] = 0.f;
        }
    }
    f4 wmr[4][2];
    #pragma unroll
    for (int kk = 0; kk < 4; ++kk) {
        const f4* wmp = (const f4*)(Wd0 + 16384 + kk * 32 + grp * 8);
        wmr[kk][0] = wmp[0]; wmr[kk][1] = wmp[1];
    }
    float gamn[4], un[4] = {0.f, 0.f, 0.f, 0.f};
    #pragma unroll
    for (int n = 0; n < 4; ++n) gamn[n] = gam[g * 64 + 16 * n + col];
    float cgv = 0.f;
    if (DO_VALS) {
        #pragma unroll
        for (int n = 0; n < 4; ++n) un[n] = ug[g * 64 + 16 * n + col];
        cgv = cg[g];
    }
    float sacc[4] = {0.f, 0.f, 0.f, 0.f}, qacc[4] = {0.f, 0.f, 0.f, 0.f};
    __syncthreads();   // bsh ready

    #pragma unroll
    for (int j = 0; j < 2; ++j) {
        int tile = slot + 64 * j;
        if (tile < 125) {
            int eg0 = g * EPG + tile * 32;
            bf8 af[2][4];
            #pragma unroll
            for (int m = 0; m < 2; ++m) {
                float w = wv2[j][m];
                const u32x4* Pr = (const u32x4*)(P16 + (size_t)sn2[j][m] * 128);
                const u32x4* Qr = (const u32x4*)(Q16 + (size_t)dn2[j][m] * 128);
                #pragma unroll
                for (int kk = 0; kk < 4; ++kk) {
                    f4 p0, p1, q0, q1;
                    unp8(Pr[kk * 4 + grp], p0, p1);
                    unp8(Qr[kk * 4 + grp], q0, q1);
                    bf8 a;
                    #pragma unroll
                    for (int r = 0; r < 4; ++r) {
                        float h0 = tanh_fast(p0[r] + q0[r] + w * wmr[kk][0][r]);
                        float h1 = tanh_fast(p1[r] + q1[r] + w * wmr[kk][1][r]);
                        a[r]     = (short)f2bf(h0);
                        a[4 + r] = (short)f2bf(h1);
                    }
                    af[m][kk] = a;
                }
            }
            f4 acc[2][4];
            #pragma unroll
            for (int m = 0; m < 2; ++m)
                #pragma unroll
                for (int n = 0; n < 4; ++n) acc[m][n] = (f4)0.f;
            #pragma unroll
            for (int kk = 0; kk < 4; ++kk) {
                bf8 bn[4];
                #pragma unroll
                for (int n = 0; n < 4; ++n)
                    bn[n] = __builtin_bit_cast(bf8, bsh[n * 4 + kk][lane]);
                #pragma unroll
                for (int m = 0; m < 2; ++m)
                    #pragma unroll
                    for (int n = 0; n < 4; ++n)
                        acc[m][n] = __builtin_amdgcn_mfma_f32_16x16x32_bf16(
                            af[m][kk], bn[n], acc[m][n], 0, 0, 0);
            }

            if (DO_VALS) {
                float rp[2][4];
                #pragma unroll
                for (int m = 0; m < 2; ++m)
                    #pragma unroll
                    for (int t = 0; t < 4; ++t) {
                        float v = 0.f;
                        #pragma unroll
                        for (int n = 0; n < 4; ++n)
                            v += un[n] * tanh_fast(acc[m][n][t] + gamn[n]);
                        v += __shfl_xor(v, 1); v += __shfl_xor(v, 2);
                        v += __shfl_xor(v, 4); v += __shfl_xor(v, 8);
                        rp[m][t] = v + cgv;
                    }
                if (col == 0) {
                    #pragma unroll
                    for (int m = 0; m < 2; ++m)
                        #pragma unroll
                        for (int pr = 0; pr < 2; ++pr) {
                            float va = rp[m][2 * pr], vb2 = rp[m][2 * pr + 1];
                            int p = ((eg0 + 16 * m + grp * 4) >> 1) + pr;
                            vals[p] = fminf(va, vb2);
                            outp[600000 + p] = (vb2 < va) ? 1.f : 0.f;
                            int e = 2 * p;
                            outp[p]          = (float)edges[e];
                            outp[200000 + p] = (float)edges[N_EDGES + e];
                        }
                }
            } else {
                int tileG = g * 125 + tile;
                #pragma unroll
                for (int m = 0; m < 2; ++m)
                    #pragma unroll
                    for (int n = 0; n < 4; ++n) {
                        float h[4];
                        #pragma unroll
                        for (int t = 0; t < 4; ++t) {
                            h[t] = tanh_fast(acc[m][n][t] + gamn[n]);
                            sacc[n] += h[t]; qacc[n] += h[t] * h[t];
                        }
                        if (STORE) {
                            unsigned w0 = f2bf(h[0]) | (f2bf(h[1]) << 16);
                            unsigned w1 = f2bf(h[2]) | (f2bf(h[3]) << 16);
                            size_t base = ((size_t)(tileG * 2 + m) * 4 + n) * 2;
                            __builtin_nontemporal_store(w0, &h1ff[(base + 0) * 64 + lane]);
                            __builtin_nontemporal_store(w1, &h1ff[(base + 1) * 64 + lane]);
                        }
                    }
            }
        }
    }
    if (!DO_VALS) {
        #pragma unroll
        for (int n = 0; n < 4; ++n) {
            float s = sacc[n], q = qacc[n];
            s += __shfl_xor(s, 16); s += __shfl_xor(s, 32);
            q += __shfl_xor(q, 16); q += __shfl_xor(q, 32);
            if (lane < 16) {
                ls[0][wave][n * 16 + col] = s;
                ls[1][wave][n * 16 + col] = q;
            }
        }
        __syncthreads();
        if (threadIdx.x < 128) {
            int st = threadIdx.x >> 6, k = threadIdx.x & 63;
            float v = ls[st][0][k] + ls[st][1][k] + ls[st][2][k] + ls[st][3][k];
            part1[((size_t)(g * 16 + tb) * 2 + st) * 64 + k] = v;
        }
    }
}

// ---------------- vals pass: nt-read h1ff, dot, pair-min ----------------------
__global__ __launch_bounds__(256) void k_vals(
    const int* __restrict__ edges, const unsigned* __restrict__ h1ff,
    const float* __restrict__ ug, const float* __restrict__ cg,
    float* __restrict__ vals, float* __restrict__ outp) {
    int g = blockIdx.x >> 4, tb = blockIdx.x & 15;
    int wave = threadIdx.x >> 6, lane = threadIdx.x & 63;
    int col = lane & 15, grp = lane >> 4;
    int slot = tb * 4 + wave;
    float un[4];
    #pragma unroll
    for (int n = 0; n < 4; ++n) un[n] = ug[g * 64 + 16 * n + col];
    float cgv = cg[g];
    for (int j = 0; j < 2; ++j) {
        int tile = slot + 64 * j;
        if (tile >= 125) break;
        int tileG = g * 125 + tile;
        int eg0 = g * EPG + tile * 32;
        #pragma unroll
        for (int m = 0; m < 2; ++m) {
            float v[4] = {0.f, 0.f, 0.f, 0.f};
            #pragma unroll
            for (int n = 0; n < 4; ++n) {
                size_t base = ((size_t)(tileG * 2 + m) * 4 + n) * 2;
                unsigned w0 = __builtin_nontemporal_load(&h1ff[(base + 0) * 64 + lane]);
                unsigned w1 = __builtin_nontemporal_load(&h1ff[(base + 1) * 64 + lane]);
                v[0] += un[n] * bf2f(w0 & 0xFFFFu);
                v[1] += un[n] * bf2f(w0 >> 16);
                v[2] += un[n] * bf2f(w1 & 0xFFFFu);
                v[3] += un[n] * bf2f(w1 >> 16);
            }
            float rp[4];
            #pragma unroll
            for (int t = 0; t < 4; ++t) {
                float vv = v[t];
                vv += __shfl_xor(vv, 1); vv += __shfl_xor(vv, 2);
                vv += __shfl_xor(vv, 4); vv += __shfl_xor(vv, 8);
                rp[t] = vv + cgv;
            }
            if (col == 0) {
                #pragma unroll
                for (int pr = 0; pr < 2; ++pr) {
                    float va = rp[2 * pr], vb = rp[2 * pr + 1];
                    int p = ((eg0 + 16 * m + grp * 4) >> 1) + pr;
                    vals[p] = fminf(va, vb);
                    outp[600000 + p] = (vb < va) ? 1.f : 0.f;
                    int e = 2 * p;
                    outp[p]          = (float)edges[e];
                    outp[200000 + p] = (float)edges[N_EDGES + e];
                }
            }
        }
    }
}

// ---------------- fold gnorm1 (sums 16 partials) into Wout --------------------
__global__ void k_fin1(const float* __restrict__ part1,
                       const float* __restrict__ gnw, const float* __restrict__ gnb,
                       const float* __restrict__ gnms,
                       const float* __restrict__ Wout, const float* __restrict__ bout,
                       float* __restrict__ ug, float* __restrict__ cg) {
    int g = blockIdx.x; int j = threadIdx.x;  // 64 threads
    float S = 0.f, Q = 0.f;
    #pragma unroll
    for (int tb = 0; tb < 16; ++tb) {
        S += part1[((size_t)(g * 16 + tb) * 2 + 0) * 64 + j];
        Q += part1[((size_t)(g * 16 + tb) * 2 + 1) * 64 + j];
    }
    float mean = S * (1.f / EPG);
    float t = mean * gnms[j];
    float var = (Q - 2.f * t * S) * (1.f / EPG) + t * t;
    float a = gnw[j] * rsqrtf(var + 1e-5f);
    float b = gnb[j] - a * t;
    ug[g * 64 + j] = a * Wout[j];
    float c = b * Wout[j];
    #pragma unroll
    for (int off = 32; off; off >>= 1) c += __shfl_xor(c, off);
    if (j == 0) cg[g] = c + bout[0];
}

// ---------------- per-graph softmax -------------------------------------------
__global__ __launch_bounds__(256) void k_softmax(const float* __restrict__ vals,
                                                 float* __restrict__ outp) {
    int g = blockIdx.x;
    __shared__ float rbuf[4], rbuf2[4];
    int t = threadIdx.x;
    const float* v = vals + g * PPG;
    float mx = -1e30f;
    for (int i = t; i < PPG; i += 256) mx = fmaxf(mx, v[i]);
    #pragma unroll
    for (int off = 32; off; off >>= 1) mx = fmaxf(mx, __shfl_xor(mx, off));
    if ((t & 63) == 0) rbuf[t >> 6] = mx;
    __syncthreads();
    mx = fmaxf(fmaxf(rbuf[0], rbuf[1]), fmaxf(rbuf[2], rbuf[3]));
    float sm = 0.f;
    for (int i = t; i < PPG; i += 256) sm += expf(v[i] - mx);
    #pragma unroll
    for (int off = 32; off; off >>= 1) sm += __shfl_xor(sm, off);
    if ((t & 63) == 0) rbuf2[t >> 6] = sm;
    __syncthreads();
    sm = rbuf2[0] + rbuf2[1] + rbuf2[2] + rbuf2[3];
    for (int i = t; i < PPG; i += 256)
        outp[400000 + g * PPG + i] = expf(v[i] - mx) / (sm + 1e-16f);
}

extern "C" void kernel_launch(void* const* d_in, const int* in_sizes, int n_in,
                              void* d_out, int out_size, void* d_ws, size_t ws_size,
                              hipStream_t stream) {
    const float* x     = (const float*)d_in[0];
    const int*   edges = (const int*)d_in[1];
    const float* ea    = (const float*)d_in[2];
    const float* Wrel0 = (const float*)d_in[6],  *brel0 = (const float*)d_in[7],  *Wroot0 = (const float*)d_in[8];
    const float* Wrel1 = (const float*)d_in[9],  *brel1 = (const float*)d_in[10], *Wroot1 = (const float*)d_in[11];
    const float* Wrel2 = (const float*)d_in[12], *brel2 = (const float*)d_in[13], *Wroot2 = (const float*)d_in[14];
    const float* Wd0 = (const float*)d_in[15],  *bd0 = (const float*)d_in[16];
    const float* gnw0 = (const float*)d_in[17], *gnb0 = (const float*)d_in[18], *gnms0 = (const float*)d_in[19];
    const float* Wd1 = (const float*)d_in[20],  *bd1 = (const float*)d_in[21];
    const float* gnw1 = (const float*)d_in[22], *gnb1 = (const float*)d_in[23], *gnms1 = (const float*)d_in[24];
    const float* Wout = (const float*)d_in[25], *bout = (const float*)d_in[26];
    float* o = (float*)d_out;
    float* w = (float*)d_ws;

    float* agg5 = w;
    float* x1   = w + 250000;
    float* x2   = w + 1850000;
    ushort_t* c2h = (ushort_t*)(w + 5050000);
    ushort_t* c2l = (ushort_t*)(w + 6650000);
    ushort_t* x3h = (ushort_t*)(w + 0);
    ushort_t* x3l = (ushort_t*)(w + 3200000);
    ushort_t* cath = (ushort_t*)(w + 8250000);
    ushort_t* catl = (ushort_t*)(w + 11450000);
    ushort_t* P16  = (ushort_t*)(w + 8250000);
    ushort_t* Q16  = (ushort_t*)(w + 11450000);
    float* tail = w + 21050000;
    unsigned* Wcb  = (unsigned*)tail;
    unsigned* Wpqb = Wcb + 8192;
    unsigned* W2b  = Wpqb + 16384;
    int* cnt   = (int*)(W2b + 2048);
    int* fillc = cnt + 50000;
    int* offs  = fillc + 50000;
    int* esrc  = offs + 50000;
    float* ew  = (float*)(esrc + 200000);
    unsigned* W1b = (unsigned*)(ew + 200000);
    float* gam = (float*)(W1b + 409600);
    float* ug  = gam + 6400;
    float* cg  = ug + 6400;
    float* vals = cg + 100;
    float* part0 = vals + 200000;
    float* part1 = part0 + 409600;
    unsigned* h1ff = (unsigned*)(w + 25600000);
    const bool haveH1 = ws_size >= 155000000ULL;

    hipMemsetAsync(cnt, 0, 100000 * sizeof(int), stream);

    k_packAll<<<104, 256, 0, stream>>>(Wrel2, Wroot2, Wd0, Wrel1, Wroot1, Wcb, Wpqb, W2b);

    k_csr_count<<<782, 256, 0, stream>>>(edges, cnt);
    k_csr_scan<<<N_G, 512, 0, stream>>>(cnt, offs);
    k_csr_fill<<<782, 256, 0, stream>>>(edges, ea, offs, fillc, esrc, ew);

    k_gath5<<<1563, 256, 0, stream>>>(cnt, offs, esrc, ew, x, agg5);
    k_dense1<<<6250, 256, 0, stream>>>(x, agg5, Wrel0, brel0, Wroot0, x1, c2h, c2l);
    k_gath32<<<6250, 256, 0, stream>>>(cnt, offs, esrc, ew, x1, c2h, c2l);
    k_g1b<<<782, 256, 0, stream>>>(c2h, c2l, W2b, brel1, x2, cath, catl);
    k_gath64<<<12500, 256, 0, stream>>>(cnt, offs, esrc, ew, x2, cath, catl);

    k_g1<<<(NCHUNK + 3) / 4, 256, 0, stream>>>(cath, catl, Wcb, brel2, x3h, x3l);
    k_g2<<<(NCHUNK + 1) / 2, 256, 0, stream>>>(x3h, x3l, Wpqb, bd0, P16, Q16);

    k_h0s<<<N_G * 16, 256, 0, stream>>>(edges, ea, P16, Q16, Wd0, part0);
    k_fin0<<<N_G, 256, 0, stream>>>(part0, gnw0, gnb0, gnms0, Wd1, bd1, W1b, gam);

    if (haveH1) {
        k_h1m<0, 1><<<N_G * 16, 256, 0, stream>>>(edges, ea, P16, Q16, Wd0, W1b, gam,
                                                  ug, cg, part1, vals, o, h1ff);
        k_fin1<<<N_G, 64, 0, stream>>>(part1, gnw1, gnb1, gnms1, Wout, bout, ug, cg);
        k_vals<<<N_G * 16, 256, 0, stream>>>(edges, h1ff, ug, cg, vals, o);
    } else {
        k_h1m<0, 0><<<N_G * 16, 256, 0, stream>>>(edges, ea, P16, Q16, Wd0, W1b, gam,
                                                  ug, cg, part1, vals, o, h1ff);
        k_fin1<<<N_G, 64, 0, stream>>>(part1, gnw1, gnb1, gnms1, Wout, bout, ug, cg);
        k_h1m<1, 0><<<N_G * 16, 256, 0, stream>>>(edges, ea, P16, Q16, Wd0, W1b, gam,
                                                  ug, cg, part1, vals, o, h1ff);
    }

    k_softmax<<<N_G, 256, 0, stream>>>(vals, o);
}